// Round 1
// baseline (6483.747 us; speedup 1.0000x reference)
//
#include <hip/hip_runtime.h>
#include <math.h>

// ---------------- utility ----------------
__device__ __forceinline__ float wave_sum(float v) {
    #pragma unroll
    for (int off = 32; off > 0; off >>= 1) v += __shfl_xor(v, off, 64);
    return v;
}
__device__ __forceinline__ float wave_max(float v) {
    #pragma unroll
    for (int off = 32; off > 0; off >>= 1) v = fmaxf(v, __shfl_xor(v, off, 64));
    return v;
}

// ---------------- generic tiled fp32 GEMM ----------------
// C[M,N] = act( A[M,K] (optionally row-scaled) @ op(B) + bias )
// BT=true : B is [N,K] (we compute A @ B^T)
// BT=false: B is [K,N] (we compute A @ B)
// act: 0=none 1=relu 2=elu
#define BM 64
#define BN 64
#define BKK 32

template<bool BT>
__global__ __launch_bounds__(256) void gemm_kernel(
    const float* __restrict__ A, const float* __restrict__ B,
    const float* __restrict__ bias, const float* __restrict__ rowscale,
    float* __restrict__ C,
    int M, int N, int K, int lda, int ldb, int ldc, int coff, int act)
{
    __shared__ float As[BKK][BM + 4];   // [kk][row]
    __shared__ float Bs[BKK][BN + 4];   // [kk][col]
    const int tid = threadIdx.x;
    const int m0 = blockIdx.y * BM;
    const int n0 = blockIdx.x * BN;
    const int ty = tid >> 4;   // 0..15
    const int tx = tid & 15;   // 0..15

    float acc[4][4] = {};

    for (int k0 = 0; k0 < K; k0 += BKK) {
        // ---- load A tile: 64 rows x 32 k = 512 float4 (along k), 2 per thread
        #pragma unroll
        for (int r = 0; r < 2; ++r) {
            int f4 = tid + r * 256;
            int ar = f4 >> 3;            // row in tile 0..63
            int af = (f4 & 7) << 2;      // k offset 0..28
            float4 v = make_float4(0.f, 0.f, 0.f, 0.f);
            int grow = m0 + ar;
            if (grow < M) {
                v = *(const float4*)(A + (size_t)grow * lda + k0 + af);
                if (rowscale) { float s = rowscale[grow]; v.x *= s; v.y *= s; v.z *= s; v.w *= s; }
            }
            As[af + 0][ar] = v.x; As[af + 1][ar] = v.y; As[af + 2][ar] = v.z; As[af + 3][ar] = v.w;
        }
        // ---- load B tile
        #pragma unroll
        for (int r = 0; r < 2; ++r) {
            int f4 = tid + r * 256;
            if (BT) {
                int col = f4 >> 3;       // 0..63
                int kf = (f4 & 7) << 2;  // 0..28
                float4 v = make_float4(0.f, 0.f, 0.f, 0.f);
                if (n0 + col < N) v = *(const float4*)(B + (size_t)(n0 + col) * ldb + k0 + kf);
                Bs[kf + 0][col] = v.x; Bs[kf + 1][col] = v.y; Bs[kf + 2][col] = v.z; Bs[kf + 3][col] = v.w;
            } else {
                int kk = f4 >> 4;        // 0..31
                int cf = (f4 & 15) << 2; // 0..60
                float4 v = make_float4(0.f, 0.f, 0.f, 0.f);
                if (n0 + cf < N) v = *(const float4*)(B + (size_t)(k0 + kk) * ldb + n0 + cf);
                *(float4*)&Bs[kk][cf] = v;
            }
        }
        __syncthreads();
        #pragma unroll
        for (int kk = 0; kk < BKK; ++kk) {
            float4 a4 = *(const float4*)&As[kk][ty << 2];
            float4 b4 = *(const float4*)&Bs[kk][tx << 2];
            float a[4] = {a4.x, a4.y, a4.z, a4.w};
            float b[4] = {b4.x, b4.y, b4.z, b4.w};
            #pragma unroll
            for (int i = 0; i < 4; ++i)
                #pragma unroll
                for (int j = 0; j < 4; ++j)
                    acc[i][j] = fmaf(a[i], b[j], acc[i][j]);
        }
        __syncthreads();
    }

    #pragma unroll
    for (int i = 0; i < 4; ++i) {
        int row = m0 + (ty << 2) + i;
        if (row >= M) continue;
        #pragma unroll
        for (int j = 0; j < 4; ++j) {
            int col = n0 + (tx << 2) + j;
            if (col >= N) continue;
            float v = acc[i][j];
            if (bias) v += bias[col];
            if (act == 1) v = fmaxf(v, 0.f);
            else if (act == 2) v = (v > 0.f) ? v : expm1f(v);
            C[(size_t)row * ldc + coff + col] = v;
        }
    }
}

// ---------------- degree kernels ----------------
__global__ __launch_bounds__(256) void deg_count_kernel(const int* __restrict__ idx, float* __restrict__ deg, int n) {
    int i = blockIdx.x * 256 + threadIdx.x;
    if (i < n) atomicAdd(&deg[idx[i]], 1.0f);
}
__global__ __launch_bounds__(256) void deg_fin_kernel(float* __restrict__ deg, int n) {
    int i = blockIdx.x * 256 + threadIdx.x;
    if (i < n) deg[i] = rsqrtf(fmaxf(deg[i], 1.0f));
}

// ---------------- edge aggregation (segment_sum of x[src] into out[dst]) ----------------
__global__ __launch_bounds__(256) void edge_agg_kernel(
    const float* __restrict__ x, const int* __restrict__ src,
    const int* __restrict__ dst, float* __restrict__ out, int ne)
{
    int e = blockIdx.x * 4 + (threadIdx.x >> 6);
    if (e >= ne) return;
    int lane = threadIdx.x & 63;
    int s = src[e], d = dst[e];
    float4 v = *(const float4*)(x + (size_t)s * 256 + (lane << 2));
    float* o = out + (size_t)d * 256 + (lane << 2);
    atomicAdd(o + 0, v.x); atomicAdd(o + 1, v.y); atomicAdd(o + 2, v.z); atomicAdd(o + 3, v.w);
}

// gh = relu(gh * deg_in^-0.5) rowwise
__global__ __launch_bounds__(256) void relu_scale_kernel(float* __restrict__ gh, const float* __restrict__ dinv, int nrows) {
    int idx = blockIdx.x * 256 + threadIdx.x;
    int row = idx >> 6, c4 = (idx & 63) << 2;
    if (row >= nrows) return;
    float s = dinv[row];
    float4 v = *(float4*)(gh + (size_t)row * 256 + c4);
    v.x = fmaxf(v.x * s, 0.f); v.y = fmaxf(v.y * s, 0.f);
    v.z = fmaxf(v.z * s, 0.f); v.w = fmaxf(v.w * s, 0.f);
    *(float4*)(gh + (size_t)row * 256 + c4) = v;
}

// ---------------- gather rows: h[r,:] = gh[seqs[r],:] ----------------
__global__ __launch_bounds__(256) void gather_kernel(
    const float* __restrict__ gh, const int* __restrict__ seqs,
    float* __restrict__ h, int nrows)
{
    int idx = blockIdx.x * 256 + threadIdx.x;
    int row = idx >> 6, c4 = (idx & 63) << 2;
    if (row >= nrows) return;
    int node = seqs[row];
    *(float4*)(h + (size_t)row * 256 + c4) = *(const float4*)(gh + (size_t)node * 256 + c4);
}

// ---------------- attention: sr -> softmax -> ctx (score independent of i!) ----------------
// fr: [1024*64, 256] with head h occupying cols [h*128, h*128+128)
// hsa: [1024, 256]
__global__ __launch_bounds__(64) void attn_kernel(
    const float* __restrict__ fr, const float* __restrict__ ar,
    float* __restrict__ hsa)
{
    int b = blockIdx.x;
    int h = blockIdx.y;
    int j = threadIdx.x;   // 0..63
    const float* frb = fr + (size_t)b * 64 * 256 + h * 128;
    // sr_j = sum_d leaky(fr[b,h,j,d]) * ar[d]
    const float* rowp = frb + (size_t)j * 256;
    float s = 0.f;
    #pragma unroll 8
    for (int d = 0; d < 128; d += 4) {
        float4 v = *(const float4*)(rowp + d);
        float4 a = *(const float4*)(ar + d);
        float x;
        x = v.x; s += (x >= 0.f ? x : 0.01f * x) * a.x;
        x = v.y; s += (x >= 0.f ? x : 0.01f * x) * a.y;
        x = v.z; s += (x >= 0.f ? x : 0.01f * x) * a.z;
        x = v.w; s += (x >= 0.f ? x : 0.01f * x) * a.w;
    }
    float mx = wave_max(s);
    float e = expf(s - mx);
    float sum = wave_sum(e);
    __shared__ float ps[64];
    ps[j] = e / sum;
    __syncthreads();
    // ctx[d] = sum_j p_j * fr[b,h,j,d]; lane handles d=j and d=j+64 (coalesced)
    float c0 = 0.f, c1 = 0.f;
    for (int jj = 0; jj < 64; ++jj) {
        float pj = ps[jj];
        c0 = fmaf(pj, frb[(size_t)jj * 256 + j], c0);
        c1 = fmaf(pj, frb[(size_t)jj * 256 + 64 + j], c1);
    }
    hsa[(size_t)b * 256 + h * 128 + j] = c0;
    hsa[(size_t)b * 256 + h * 128 + 64 + j] = c1;
}

// ---------------- h = LN(h + broadcast u) * g + b ----------------
__global__ __launch_bounds__(256) void add_ln_kernel(
    float* __restrict__ h, const float* __restrict__ u,
    const float* __restrict__ g, const float* __restrict__ beta, int nrows)
{
    int row = blockIdx.x * 4 + (threadIdx.x >> 6);
    int lane = threadIdx.x & 63;
    if (row >= nrows) return;
    int b = row >> 6;
    float4 hv = *(float4*)(h + (size_t)row * 256 + (lane << 2));
    float4 uv = *(const float4*)(u + (size_t)b * 256 + (lane << 2));
    float y0 = hv.x + uv.x, y1 = hv.y + uv.y, y2 = hv.z + uv.z, y3 = hv.w + uv.w;
    float s = y0 + y1 + y2 + y3;
    float q = y0 * y0 + y1 * y1 + y2 * y2 + y3 * y3;
    s = wave_sum(s); q = wave_sum(q);
    float mean = s * (1.f / 256.f);
    float var = q * (1.f / 256.f) - mean * mean;
    float inv = rsqrtf(var + 1e-5f);
    float4 gv = *(const float4*)(g + (lane << 2));
    float4 bv = *(const float4*)(beta + (lane << 2));
    float4 o;
    o.x = (y0 - mean) * inv * gv.x + bv.x;
    o.y = (y1 - mean) * inv * gv.y + bv.y;
    o.z = (y2 - mean) * inv * gv.z + bv.z;
    o.w = (y3 - mean) * inv * gv.w + bv.w;
    *(float4*)(h + (size_t)row * 256 + (lane << 2)) = o;
}

// ---------------- final: out[row] = sigmoid(m2[row,:] . w3 + b3) ----------------
__global__ __launch_bounds__(256) void final_kernel(
    const float* __restrict__ m2, const float* __restrict__ w3,
    const float* __restrict__ b3, float* __restrict__ out, int nrows)
{
    int row = blockIdx.x * 4 + (threadIdx.x >> 6);
    int lane = threadIdx.x & 63;
    if (row >= nrows) return;
    float s = m2[(size_t)row * 128 + lane] * w3[lane]
            + m2[(size_t)row * 128 + 64 + lane] * w3[64 + lane];
    s = wave_sum(s);
    if (lane == 0) out[row] = 1.f / (1.f + expf(-(s + b3[0])));
}

static inline int cdiv(int a, int b) { return (a + b - 1) / b; }

extern "C" void kernel_launch(void* const* d_in, const int* in_sizes, int n_in,
                              void* d_out, int out_size, void* d_ws, size_t ws_size,
                              hipStream_t stream)
{
    const float* feat0   = (const float*)d_in[0];
    const float* feat1   = (const float*)d_in[1];
    const float* fc_w0   = (const float*)d_in[2];
    const float* fc_b0   = (const float*)d_in[3];
    const float* fc_w1   = (const float*)d_in[4];
    const float* fc_b1   = (const float*)d_in[5];
    const float* gcn_w   = (const float*)d_in[6];
    const int*   edge_src= (const int*)d_in[7];
    const int*   edge_dst= (const int*)d_in[8];
    const int*   dg_seqs = (const int*)d_in[9];
    const int*   pt_seqs = (const int*)d_in[10];
    // 11 type_emb, 12 node_type: dead in the reference
    // 13 gt_wl, 15 gt_al: dead (softmax row-constant cancellation)
    const float* gt_wr   = (const float*)d_in[14];
    const float* gt_ar   = (const float*)d_in[16];
    const float* gt_wf   = (const float*)d_in[17];
    const float* ln_g    = (const float*)d_in[18];
    const float* ln_b    = (const float*)d_in[19];
    const float* proj_d_w= (const float*)d_in[20];
    const float* proj_d_b= (const float*)d_in[21];
    const float* proj_p_w= (const float*)d_in[22];
    const float* proj_p_b= (const float*)d_in[23];
    const float* ml_w1   = (const float*)d_in[24];
    const float* ml_b1   = (const float*)d_in[25];
    const float* ml_w2   = (const float*)d_in[26];
    const float* ml_b2   = (const float*)d_in[27];
    const float* ml_w3   = (const float*)d_in[28];
    const float* ml_b3   = (const float*)d_in[29];
    float* out = (float*)d_out;

    // ---- workspace layout (floats) ----
    float* base = (float*)d_ws;
    float* gh   = base;                    // 40000*256 = 10,240,000
    float* tmp  = gh  + 10240000;          // 10,240,000
    float* h    = tmp + 10240000;          // 65536*256 = 16,777,216
    float* fr   = h   + 16777216;          // 16,777,216
    float* dego = fr  + 16777216;          // 40,000
    float* degi = dego + 40000;            // 40,000
    float* hsa  = degi + 40000;            // 262,144
    float* u    = hsa + 262144;            // 262,144
    float* t1   = u   + 262144;            // 262,144
    float* mx   = t1  + 262144;            // 1024*512 = 524,288
    float* m1   = mx  + 524288;            // 262,144
    float* m2   = m1  + 262144;            // 131,072

    // ---- FC projections into gh ----
    gemm_kernel<true><<<dim3(4, cdiv(20000, 64)), 256, 0, stream>>>(
        feat0, fc_w0, fc_b0, nullptr, gh, 20000, 256, 512, 512, 512, 256, 0, 0);
    gemm_kernel<true><<<dim3(4, cdiv(20000, 64)), 256, 0, stream>>>(
        feat1, fc_w1, fc_b1, nullptr, gh + (size_t)20000 * 256, 20000, 256, 512, 512, 512, 256, 0, 0);

    // ---- degrees ----
    hipMemsetAsync(dego, 0, 80000 * sizeof(float), stream);
    deg_count_kernel<<<2500, 256, 0, stream>>>(edge_src, dego, 640000);
    deg_count_kernel<<<2500, 256, 0, stream>>>(edge_dst, degi, 640000);
    deg_fin_kernel<<<cdiv(80000, 256), 256, 0, stream>>>(dego, 80000);

    // ---- 2x GCN ----
    for (int l = 0; l < 2; ++l) {
        gemm_kernel<false><<<dim3(4, 625), 256, 0, stream>>>(
            gh, gcn_w + (size_t)l * 65536, nullptr, dego, tmp, 40000, 256, 256, 256, 256, 256, 0, 0);
        hipMemsetAsync(gh, 0, (size_t)10240000 * sizeof(float), stream);
        edge_agg_kernel<<<160000, 256, 0, stream>>>(tmp, edge_src, edge_dst, gh, 640000);
        relu_scale_kernel<<<10000, 256, 0, stream>>>(gh, degi, 40000);
    }

    // ---- graph transformer per node type ----
    const int* seqs[2] = {dg_seqs, pt_seqs};
    const float* pw[2] = {proj_d_w, proj_p_w};
    const float* pb[2] = {proj_d_b, proj_p_b};
    for (int t = 0; t < 2; ++t) {
        gather_kernel<<<16384, 256, 0, stream>>>(gh, seqs[t], h, 65536);
        for (int l = 0; l < 4; ++l) {
            int i = t * 4 + l;
            gemm_kernel<true><<<dim3(4, 1024), 256, 0, stream>>>(
                h, gt_wr + (size_t)i * 65536, nullptr, nullptr, fr, 65536, 256, 256, 256, 256, 256, 0, 0);
            attn_kernel<<<dim3(1024, 2), 64, 0, stream>>>(fr, gt_ar + (size_t)i * 128, hsa);
            gemm_kernel<true><<<dim3(4, 16), 256, 0, stream>>>(
                hsa, gt_wf + (size_t)i * 65536, nullptr, nullptr, u, 1024, 256, 256, 256, 256, 256, 0, 0);
            add_ln_kernel<<<16384, 256, 0, stream>>>(h, u, ln_g + i * 256, ln_b + i * 256, 65536);
        }
        // proj head: elu(emb @ w0^T + b0) @ w1^T + b1, written into mx[:, t*256:...]
        gemm_kernel<true><<<dim3(4, 16), 256, 0, stream>>>(
            h, pw[t], pb[t], nullptr, t1, 1024, 256, 256, 64 * 256, 256, 256, 0, 2);
        gemm_kernel<true><<<dim3(4, 16), 256, 0, stream>>>(
            t1, pw[t] + 65536, pb[t] + 256, nullptr, mx, 1024, 256, 256, 256, 256, 512, t * 256, 0);
    }

    // ---- predict MLP ----
    gemm_kernel<true><<<dim3(4, 16), 256, 0, stream>>>(
        mx, ml_w1, ml_b1, nullptr, m1, 1024, 256, 512, 512, 512, 256, 0, 1);
    gemm_kernel<true><<<dim3(2, 16), 256, 0, stream>>>(
        m1, ml_w2, ml_b2, nullptr, m2, 1024, 128, 256, 256, 256, 128, 0, 1);
    final_kernel<<<256, 256, 0, stream>>>(m2, ml_w3, ml_b3, out, 1024);
}

// Round 2
// 2286.322 us; speedup vs baseline: 2.8359x; 2.8359x over previous
//
#include <hip/hip_runtime.h>
#include <math.h>

// ---------------- utility ----------------
__device__ __forceinline__ float wave_sum(float v) {
    #pragma unroll
    for (int off = 32; off > 0; off >>= 1) v += __shfl_xor(v, off, 64);
    return v;
}
__device__ __forceinline__ float wave_max(float v) {
    #pragma unroll
    for (int off = 32; off > 0; off >>= 1) v = fmaxf(v, __shfl_xor(v, off, 64));
    return v;
}

// ---------------- generic tiled fp32 GEMM ----------------
// C[M,N] = act( A[M,K] (optionally row-scaled) @ op(B) + bias )
// BT=true : B is [N,K] (we compute A @ B^T)
// BT=false: B is [K,N] (we compute A @ B)
// act: 0=none 1=relu 2=elu
#define BM 64
#define BN 64
#define BKK 32

template<bool BT>
__global__ __launch_bounds__(256) void gemm_kernel(
    const float* __restrict__ A, const float* __restrict__ B,
    const float* __restrict__ bias, const float* __restrict__ rowscale,
    float* __restrict__ C,
    int M, int N, int K, int lda, int ldb, int ldc, int coff, int act)
{
    __shared__ float As[BKK][BM + 4];   // [kk][row]
    __shared__ float Bs[BKK][BN + 4];   // [kk][col]
    const int tid = threadIdx.x;
    const int m0 = blockIdx.y * BM;
    const int n0 = blockIdx.x * BN;
    const int ty = tid >> 4;   // 0..15
    const int tx = tid & 15;   // 0..15

    float acc[4][4] = {};

    for (int k0 = 0; k0 < K; k0 += BKK) {
        // ---- load A tile: 64 rows x 32 k = 512 float4 (along k), 2 per thread
        #pragma unroll
        for (int r = 0; r < 2; ++r) {
            int f4 = tid + r * 256;
            int ar = f4 >> 3;            // row in tile 0..63
            int af = (f4 & 7) << 2;      // k offset 0..28
            float4 v = make_float4(0.f, 0.f, 0.f, 0.f);
            int grow = m0 + ar;
            if (grow < M) {
                v = *(const float4*)(A + (size_t)grow * lda + k0 + af);
                if (rowscale) { float s = rowscale[grow]; v.x *= s; v.y *= s; v.z *= s; v.w *= s; }
            }
            As[af + 0][ar] = v.x; As[af + 1][ar] = v.y; As[af + 2][ar] = v.z; As[af + 3][ar] = v.w;
        }
        // ---- load B tile
        #pragma unroll
        for (int r = 0; r < 2; ++r) {
            int f4 = tid + r * 256;
            if (BT) {
                int col = f4 >> 3;       // 0..63
                int kf = (f4 & 7) << 2;  // 0..28
                float4 v = make_float4(0.f, 0.f, 0.f, 0.f);
                if (n0 + col < N) v = *(const float4*)(B + (size_t)(n0 + col) * ldb + k0 + kf);
                Bs[kf + 0][col] = v.x; Bs[kf + 1][col] = v.y; Bs[kf + 2][col] = v.z; Bs[kf + 3][col] = v.w;
            } else {
                int kk = f4 >> 4;        // 0..31
                int cf = (f4 & 15) << 2; // 0..60
                float4 v = make_float4(0.f, 0.f, 0.f, 0.f);
                if (n0 + cf < N) v = *(const float4*)(B + (size_t)(k0 + kk) * ldb + n0 + cf);
                *(float4*)&Bs[kk][cf] = v;
            }
        }
        __syncthreads();
        #pragma unroll
        for (int kk = 0; kk < BKK; ++kk) {
            float4 a4 = *(const float4*)&As[kk][ty << 2];
            float4 b4 = *(const float4*)&Bs[kk][tx << 2];
            float a[4] = {a4.x, a4.y, a4.z, a4.w};
            float b[4] = {b4.x, b4.y, b4.z, b4.w};
            #pragma unroll
            for (int i = 0; i < 4; ++i)
                #pragma unroll
                for (int j = 0; j < 4; ++j)
                    acc[i][j] = fmaf(a[i], b[j], acc[i][j]);
        }
        __syncthreads();
    }

    #pragma unroll
    for (int i = 0; i < 4; ++i) {
        int row = m0 + (ty << 2) + i;
        if (row >= M) continue;
        #pragma unroll
        for (int j = 0; j < 4; ++j) {
            int col = n0 + (tx << 2) + j;
            if (col >= N) continue;
            float v = acc[i][j];
            if (bias) v += bias[col];
            if (act == 1) v = fmaxf(v, 0.f);
            else if (act == 2) v = (v > 0.f) ? v : expm1f(v);
            C[(size_t)row * ldc + coff + col] = v;
        }
    }
}

// ---------------- CSR-by-dst build ----------------
#define EDGE_CAP 128

// one int atomic per edge; also count out-degrees
__global__ __launch_bounds__(256) void bucket_fill_kernel(
    const int* __restrict__ src, const int* __restrict__ dst,
    int* __restrict__ ebuf, int* __restrict__ cursor, int* __restrict__ cnt_out, int ne)
{
    int e = blockIdx.x * 256 + threadIdx.x;
    if (e >= ne) return;
    int s = src[e], d = dst[e];
    atomicAdd(&cnt_out[s], 1);
    int pos = atomicAdd(&cursor[d], 1);
    if (pos < EDGE_CAP) ebuf[(size_t)d * EDGE_CAP + pos] = s;
}

// dego[i] = (max(cnt_out[i],1))^-0.5
__global__ __launch_bounds__(256) void deg_fin_kernel(const int* __restrict__ cnt, float* __restrict__ dinv, int n) {
    int i = blockIdx.x * 256 + threadIdx.x;
    if (i < n) dinv[i] = rsqrtf(fmaxf((float)cnt[i], 1.0f));
}

// ---------------- CSR gather-aggregate: out[n] = relu( (sum_{e in in(n)} x[src_e]) * deg_in^-0.5 )
__global__ __launch_bounds__(256) void csr_agg_kernel(
    const float* __restrict__ x, const int* __restrict__ ebuf,
    const int* __restrict__ deg, float* __restrict__ out, int nnodes)
{
    int n = blockIdx.x * 4 + (threadIdx.x >> 6);
    if (n >= nnodes) return;
    int lane = threadIdx.x & 63;
    int d = deg[n];
    float dinv = rsqrtf(fmaxf((float)d, 1.0f));
    if (d > EDGE_CAP) d = EDGE_CAP;
    const int* eb = ebuf + (size_t)n * EDGE_CAP;
    float ax = 0.f, ay = 0.f, az = 0.f, aw = 0.f;
    for (int k = 0; k < d; ++k) {
        int s = eb[k];
        float4 v = *(const float4*)(x + (size_t)s * 256 + (lane << 2));
        ax += v.x; ay += v.y; az += v.z; aw += v.w;
    }
    float4 o;
    o.x = fmaxf(ax * dinv, 0.f);
    o.y = fmaxf(ay * dinv, 0.f);
    o.z = fmaxf(az * dinv, 0.f);
    o.w = fmaxf(aw * dinv, 0.f);
    *(float4*)(out + (size_t)n * 256 + (lane << 2)) = o;
}

// ---------------- gather rows: h[r,:] = gh[seqs[r],:] ----------------
__global__ __launch_bounds__(256) void gather_kernel(
    const float* __restrict__ gh, const int* __restrict__ seqs,
    float* __restrict__ h, int nrows)
{
    int idx = blockIdx.x * 256 + threadIdx.x;
    int row = idx >> 6, c4 = (idx & 63) << 2;
    if (row >= nrows) return;
    int node = seqs[row];
    *(float4*)(h + (size_t)row * 256 + c4) = *(const float4*)(gh + (size_t)node * 256 + c4);
}

// ---------------- attention: sr -> softmax -> ctx (score independent of i!) ----------------
// fr: [1024*64, 256] with head h occupying cols [h*128, h*128+128)
// hsa: [1024, 256]
__global__ __launch_bounds__(64) void attn_kernel(
    const float* __restrict__ fr, const float* __restrict__ ar,
    float* __restrict__ hsa)
{
    int b = blockIdx.x;
    int h = blockIdx.y;
    int j = threadIdx.x;   // 0..63
    const float* frb = fr + (size_t)b * 64 * 256 + h * 128;
    // sr_j = sum_d leaky(fr[b,h,j,d]) * ar[d]
    const float* rowp = frb + (size_t)j * 256;
    float s = 0.f;
    #pragma unroll 8
    for (int d = 0; d < 128; d += 4) {
        float4 v = *(const float4*)(rowp + d);
        float4 a = *(const float4*)(ar + d);
        float x;
        x = v.x; s += (x >= 0.f ? x : 0.01f * x) * a.x;
        x = v.y; s += (x >= 0.f ? x : 0.01f * x) * a.y;
        x = v.z; s += (x >= 0.f ? x : 0.01f * x) * a.z;
        x = v.w; s += (x >= 0.f ? x : 0.01f * x) * a.w;
    }
    float mx = wave_max(s);
    float e = expf(s - mx);
    float sum = wave_sum(e);
    __shared__ float ps[64];
    ps[j] = e / sum;
    __syncthreads();
    // ctx[d] = sum_j p_j * fr[b,h,j,d]; lane handles d=j and d=j+64 (coalesced)
    float c0 = 0.f, c1 = 0.f;
    for (int jj = 0; jj < 64; ++jj) {
        float pj = ps[jj];
        c0 = fmaf(pj, frb[(size_t)jj * 256 + j], c0);
        c1 = fmaf(pj, frb[(size_t)jj * 256 + 64 + j], c1);
    }
    hsa[(size_t)b * 256 + h * 128 + j] = c0;
    hsa[(size_t)b * 256 + h * 128 + 64 + j] = c1;
}

// ---------------- h = LN(h + broadcast u) * g + b ----------------
__global__ __launch_bounds__(256) void add_ln_kernel(
    float* __restrict__ h, const float* __restrict__ u,
    const float* __restrict__ g, const float* __restrict__ beta, int nrows)
{
    int row = blockIdx.x * 4 + (threadIdx.x >> 6);
    int lane = threadIdx.x & 63;
    if (row >= nrows) return;
    int b = row >> 6;
    float4 hv = *(float4*)(h + (size_t)row * 256 + (lane << 2));
    float4 uv = *(const float4*)(u + (size_t)b * 256 + (lane << 2));
    float y0 = hv.x + uv.x, y1 = hv.y + uv.y, y2 = hv.z + uv.z, y3 = hv.w + uv.w;
    float s = y0 + y1 + y2 + y3;
    float q = y0 * y0 + y1 * y1 + y2 * y2 + y3 * y3;
    s = wave_sum(s); q = wave_sum(q);
    float mean = s * (1.f / 256.f);
    float var = q * (1.f / 256.f) - mean * mean;
    float inv = rsqrtf(var + 1e-5f);
    float4 gv = *(const float4*)(g + (lane << 2));
    float4 bv = *(const float4*)(beta + (lane << 2));
    float4 o;
    o.x = (y0 - mean) * inv * gv.x + bv.x;
    o.y = (y1 - mean) * inv * gv.y + bv.y;
    o.z = (y2 - mean) * inv * gv.z + bv.z;
    o.w = (y3 - mean) * inv * gv.w + bv.w;
    *(float4*)(h + (size_t)row * 256 + (lane << 2)) = o;
}

// ---------------- final: out[row] = sigmoid(m2[row,:] . w3 + b3) ----------------
__global__ __launch_bounds__(256) void final_kernel(
    const float* __restrict__ m2, const float* __restrict__ w3,
    const float* __restrict__ b3, float* __restrict__ out, int nrows)
{
    int row = blockIdx.x * 4 + (threadIdx.x >> 6);
    int lane = threadIdx.x & 63;
    if (row >= nrows) return;
    float s = m2[(size_t)row * 128 + lane] * w3[lane]
            + m2[(size_t)row * 128 + 64 + lane] * w3[64 + lane];
    s = wave_sum(s);
    if (lane == 0) out[row] = 1.f / (1.f + expf(-(s + b3[0])));
}

static inline int cdiv(int a, int b) { return (a + b - 1) / b; }

extern "C" void kernel_launch(void* const* d_in, const int* in_sizes, int n_in,
                              void* d_out, int out_size, void* d_ws, size_t ws_size,
                              hipStream_t stream)
{
    const float* feat0   = (const float*)d_in[0];
    const float* feat1   = (const float*)d_in[1];
    const float* fc_w0   = (const float*)d_in[2];
    const float* fc_b0   = (const float*)d_in[3];
    const float* fc_w1   = (const float*)d_in[4];
    const float* fc_b1   = (const float*)d_in[5];
    const float* gcn_w   = (const float*)d_in[6];
    const int*   edge_src= (const int*)d_in[7];
    const int*   edge_dst= (const int*)d_in[8];
    const int*   dg_seqs = (const int*)d_in[9];
    const int*   pt_seqs = (const int*)d_in[10];
    // 11 type_emb, 12 node_type: dead in the reference
    // 13 gt_wl, 15 gt_al: dead (softmax row-constant cancellation)
    const float* gt_wr   = (const float*)d_in[14];
    const float* gt_ar   = (const float*)d_in[16];
    const float* gt_wf   = (const float*)d_in[17];
    const float* ln_g    = (const float*)d_in[18];
    const float* ln_b    = (const float*)d_in[19];
    const float* proj_d_w= (const float*)d_in[20];
    const float* proj_d_b= (const float*)d_in[21];
    const float* proj_p_w= (const float*)d_in[22];
    const float* proj_p_b= (const float*)d_in[23];
    const float* ml_w1   = (const float*)d_in[24];
    const float* ml_b1   = (const float*)d_in[25];
    const float* ml_w2   = (const float*)d_in[26];
    const float* ml_b2   = (const float*)d_in[27];
    const float* ml_w3   = (const float*)d_in[28];
    const float* ml_b3   = (const float*)d_in[29];
    float* out = (float*)d_out;

    // ---- workspace layout (floats) ----
    float* base = (float*)d_ws;
    float* gh   = base;                    // 40000*256 = 10,240,000
    float* tmp  = gh  + 10240000;          // 10,240,000
    float* h    = tmp + 10240000;          // 65536*256 = 16,777,216
    float* fr   = h   + 16777216;          // 16,777,216
    float* dego = fr  + 16777216;          // 40,000
    float* hsa  = dego + 40000;            // 262,144
    float* u    = hsa + 262144;            // 262,144
    float* t1   = u   + 262144;            // 262,144
    float* mx   = t1  + 262144;            // 1024*512 = 524,288
    float* m1   = mx  + 524288;            // 262,144
    float* m2   = m1  + 262144;            // 131,072

    // int scratch aliased onto fr (fr used only in transformer phase; CSR only in GCN phase)
    int* ebuf    = (int*)fr;               // 40000*128 = 5,120,000 ints
    int* cursor  = ebuf + (size_t)40000 * EDGE_CAP;  // 40,000 (in-degree counts)
    int* cnt_out = cursor + 40000;         // 40,000

    // ---- FC projections into gh ----
    gemm_kernel<true><<<dim3(4, cdiv(20000, 64)), 256, 0, stream>>>(
        feat0, fc_w0, fc_b0, nullptr, gh, 20000, 256, 512, 512, 512, 256, 0, 0);
    gemm_kernel<true><<<dim3(4, cdiv(20000, 64)), 256, 0, stream>>>(
        feat1, fc_w1, fc_b1, nullptr, gh + (size_t)20000 * 256, 20000, 256, 512, 512, 512, 256, 0, 0);

    // ---- CSR build (once; reused by both GCN layers) ----
    hipMemsetAsync(cursor, 0, 80000 * sizeof(int), stream);
    bucket_fill_kernel<<<2500, 256, 0, stream>>>(edge_src, edge_dst, ebuf, cursor, cnt_out, 640000);
    deg_fin_kernel<<<cdiv(40000, 256), 256, 0, stream>>>(cnt_out, dego, 40000);

    // ---- 2x GCN: gemm (rowscaled by dego) -> gather-aggregate (scale+relu fused) ----
    for (int l = 0; l < 2; ++l) {
        gemm_kernel<false><<<dim3(4, 625), 256, 0, stream>>>(
            gh, gcn_w + (size_t)l * 65536, nullptr, dego, tmp, 40000, 256, 256, 256, 256, 256, 0, 0);
        csr_agg_kernel<<<10000, 256, 0, stream>>>(tmp, ebuf, cursor, gh, 40000);
    }

    // ---- graph transformer per node type ----
    const int* seqs[2] = {dg_seqs, pt_seqs};
    const float* pw[2] = {proj_d_w, proj_p_w};
    const float* pb[2] = {proj_d_b, proj_p_b};
    for (int t = 0; t < 2; ++t) {
        gather_kernel<<<16384, 256, 0, stream>>>(gh, seqs[t], h, 65536);
        for (int l = 0; l < 4; ++l) {
            int i = t * 4 + l;
            gemm_kernel<true><<<dim3(4, 1024), 256, 0, stream>>>(
                h, gt_wr + (size_t)i * 65536, nullptr, nullptr, fr, 65536, 256, 256, 256, 256, 256, 0, 0);
            attn_kernel<<<dim3(1024, 2), 64, 0, stream>>>(fr, gt_ar + (size_t)i * 128, hsa);
            gemm_kernel<true><<<dim3(4, 16), 256, 0, stream>>>(
                hsa, gt_wf + (size_t)i * 65536, nullptr, nullptr, u, 1024, 256, 256, 256, 256, 256, 0, 0);
            add_ln_kernel<<<16384, 256, 0, stream>>>(h, u, ln_g + i * 256, ln_b + i * 256, 65536);
        }
        // proj head: elu(emb @ w0^T + b0) @ w1^T + b1, written into mx[:, t*256:...]
        gemm_kernel<true><<<dim3(4, 16), 256, 0, stream>>>(
            h, pw[t], pb[t], nullptr, t1, 1024, 256, 256, 64 * 256, 256, 256, 0, 2);
        gemm_kernel<true><<<dim3(4, 16), 256, 0, stream>>>(
            t1, pw[t] + 65536, pb[t] + 256, nullptr, mx, 1024, 256, 256, 256, 256, 512, t * 256, 0);
    }

    // ---- predict MLP ----
    gemm_kernel<true><<<dim3(4, 16), 256, 0, stream>>>(
        mx, ml_w1, ml_b1, nullptr, m1, 1024, 256, 512, 512, 512, 256, 0, 1);
    gemm_kernel<true><<<dim3(2, 16), 256, 0, stream>>>(
        m1, ml_w2, ml_b2, nullptr, m2, 1024, 128, 256, 256, 256, 128, 0, 1);
    final_kernel<<<256, 256, 0, stream>>>(m2, ml_w3, ml_b3, out, 1024);
}

// Round 3
// 1329.932 us; speedup vs baseline: 4.8752x; 1.7191x over previous
//
#include <hip/hip_runtime.h>
#include <hip/hip_bf16.h>
#include <math.h>

typedef unsigned int u32;
typedef unsigned short u16;
typedef __attribute__((ext_vector_type(8))) short bf16x8;
typedef __attribute__((ext_vector_type(4))) float f32x4;

__device__ __forceinline__ float b2f(u16 u) { union { u32 i; float f; } c; c.i = ((u32)u) << 16; return c.f; }
__device__ __forceinline__ u16 f2b(float f) { __hip_bfloat16 h = __float2bfloat16(f); u16 r; __builtin_memcpy(&r, &h, 2); return r; }
__device__ __forceinline__ float b2f_lo(u32 w) { union { u32 i; float f; } c; c.i = w << 16; return c.f; }
__device__ __forceinline__ float b2f_hi(u32 w) { union { u32 i; float f; } c; c.i = w & 0xffff0000u; return c.f; }

__device__ __forceinline__ float wave_sum(float v) {
    #pragma unroll
    for (int off = 32; off > 0; off >>= 1) v += __shfl_xor(v, off, 64);
    return v;
}
__device__ __forceinline__ float wave_max(float v) {
    #pragma unroll
    for (int off = 32; off > 0; off >>= 1) v = fmaxf(v, __shfl_xor(v, off, 64));
    return v;
}

// ================= bf16 MFMA GEMM =================
// C[M,N] = (A[M,K] @ B[N,K]^T) (+bias[col]) (*rowscale[row]) -> bf16 out
// 128x128 block tile, 4 waves (2x2), each wave 64x64 = 4x4 frags of 16x16x32.
// LDS: A tile [128][64] bf16 + B tile [128][64] bf16, XOR-swizzled (T2).
__global__ __launch_bounds__(256) void mfma_gemm_kernel(
    const u16* __restrict__ A, const u16* __restrict__ B,
    const float* __restrict__ bias, const float* __restrict__ rowscale,
    u16* __restrict__ Cb, int M, int N, int K)
{
    __shared__ u16 lds[2 * 128 * 64];   // A at byte 0, B at byte 16384
    const int tid = threadIdx.x;
    const int wid = tid >> 6, lane = tid & 63;
    const int wr = wid >> 1, wc = wid & 1;
    const int m0 = blockIdx.y * 128, n0 = blockIdx.x * 128;

    f32x4 acc[4][4] = {};

    const int rsub = lane >> 3;              // 0..7 (row-within-8 for staging)
    const int cbyte = (lane & 7) << 4;       // 0..112, 16B granule
    const int swz_st = cbyte ^ (rsub << 4);  // write-side XOR swizzle

    for (int k0 = 0; k0 < K; k0 += 64) {
        // ---- stage A (chunks 0-15) and B (chunks 16-31): wave w does 8 chunks
        #pragma unroll
        for (int cc = 0; cc < 8; ++cc) {
            int c = wid * 8 + cc;
            int buf = c >> 4;                      // 0=A, 1=B
            int row_in = ((c & 15) << 3) + rsub;   // 0..127
            int lim = buf ? N : M;
            int row_g = (buf ? n0 : m0) + row_in;
            if (row_g >= lim) row_g = lim - 1;
            const u16* src = (buf ? B : A) + (size_t)row_g * K + k0 + (cbyte >> 1);
            f32x4 v = *(const f32x4*)src;          // 16 B = 8 bf16
            *(f32x4*)((char*)lds + buf * 16384 + row_in * 128 + swz_st) = v;
        }
        __syncthreads();
        // ---- 2 K-steps of 32
        #pragma unroll
        for (int ks = 0; ks < 2; ++ks) {
            const int kbyte = ks * 64 + ((lane >> 4) << 4);
            const int off = kbyte ^ ((lane & 7) << 4);   // read-side swizzle (row&7 == lane&7)
            const int ra = lane & 15;
            bf16x8 af[4], bf[4];
            #pragma unroll
            for (int i = 0; i < 4; ++i) {
                int r = wr * 64 + i * 16 + ra;
                af[i] = *(bf16x8*)((char*)lds + r * 128 + off);
            }
            #pragma unroll
            for (int j = 0; j < 4; ++j) {
                int r = wc * 64 + j * 16 + ra;
                bf[j] = *(bf16x8*)((char*)lds + 16384 + r * 128 + off);
            }
            #pragma unroll
            for (int i = 0; i < 4; ++i)
                #pragma unroll
                for (int j = 0; j < 4; ++j)
                    acc[i][j] = __builtin_amdgcn_mfma_f32_16x16x32_bf16(af[i], bf[j], acc[i][j], 0, 0, 0);
        }
        __syncthreads();
    }

    // ---- epilogue: C/D layout col=lane&15, row=(lane>>4)*4+reg (m89-verified)
    const int cr = lane >> 4, ccol = lane & 15;
    #pragma unroll
    for (int i = 0; i < 4; ++i) {
        #pragma unroll
        for (int j = 0; j < 4; ++j) {
            int colg = n0 + wc * 64 + j * 16 + ccol;
            if (colg >= N) continue;
            float badd = bias ? bias[colg] : 0.f;
            #pragma unroll
            for (int reg = 0; reg < 4; ++reg) {
                int rowg = m0 + wr * 64 + i * 16 + cr * 4 + reg;
                if (rowg >= M) continue;
                float v = acc[i][j][reg] + badd;
                if (rowscale) v *= rowscale[rowg];
                Cb[(size_t)rowg * N + colg] = f2b(v);
            }
        }
    }
}

// ================= fp32 tiled GEMM (small M only) =================
// C = act(A @ B^T + bias); act: 0=none 1=relu 2=elu
template<bool BT>
__global__ __launch_bounds__(256) void gemm_kernel(
    const float* __restrict__ A, const float* __restrict__ B,
    const float* __restrict__ bias, const float* __restrict__ rowscale,
    float* __restrict__ C,
    int M, int N, int K, int lda, int ldb, int ldc, int coff, int act)
{
    __shared__ float As[32][64 + 4];
    __shared__ float Bs[32][64 + 4];
    const int tid = threadIdx.x;
    const int m0 = blockIdx.y * 64;
    const int n0 = blockIdx.x * 64;
    const int ty = tid >> 4, tx = tid & 15;
    float acc[4][4] = {};
    for (int k0 = 0; k0 < K; k0 += 32) {
        #pragma unroll
        for (int r = 0; r < 2; ++r) {
            int f4 = tid + r * 256;
            int ar = f4 >> 3, af = (f4 & 7) << 2;
            float4 v = make_float4(0.f, 0.f, 0.f, 0.f);
            int grow = m0 + ar;
            if (grow < M) {
                v = *(const float4*)(A + (size_t)grow * lda + k0 + af);
                if (rowscale) { float s = rowscale[grow]; v.x *= s; v.y *= s; v.z *= s; v.w *= s; }
            }
            As[af + 0][ar] = v.x; As[af + 1][ar] = v.y; As[af + 2][ar] = v.z; As[af + 3][ar] = v.w;
        }
        #pragma unroll
        for (int r = 0; r < 2; ++r) {
            int f4 = tid + r * 256;
            int col = f4 >> 3, kf = (f4 & 7) << 2;
            float4 v = make_float4(0.f, 0.f, 0.f, 0.f);
            if (n0 + col < N) v = *(const float4*)(B + (size_t)(n0 + col) * ldb + k0 + kf);
            Bs[kf + 0][col] = v.x; Bs[kf + 1][col] = v.y; Bs[kf + 2][col] = v.z; Bs[kf + 3][col] = v.w;
        }
        __syncthreads();
        #pragma unroll
        for (int kk = 0; kk < 32; ++kk) {
            float4 a4 = *(const float4*)&As[kk][ty << 2];
            float4 b4 = *(const float4*)&Bs[kk][tx << 2];
            float a[4] = {a4.x, a4.y, a4.z, a4.w};
            float b[4] = {b4.x, b4.y, b4.z, b4.w};
            #pragma unroll
            for (int i = 0; i < 4; ++i)
                #pragma unroll
                for (int j = 0; j < 4; ++j)
                    acc[i][j] = fmaf(a[i], b[j], acc[i][j]);
        }
        __syncthreads();
    }
    #pragma unroll
    for (int i = 0; i < 4; ++i) {
        int row = m0 + (ty << 2) + i;
        if (row >= M) continue;
        #pragma unroll
        for (int j = 0; j < 4; ++j) {
            int col = n0 + (tx << 2) + j;
            if (col >= N) continue;
            float v = acc[i][j];
            if (bias) v += bias[col];
            if (act == 1) v = fmaxf(v, 0.f);
            else if (act == 2) v = (v > 0.f) ? v : expm1f(v);
            C[(size_t)row * ldc + coff + col] = v;
        }
    }
}

// ================= converts =================
__global__ __launch_bounds__(256) void conv_flat_kernel(const float* __restrict__ in, u16* __restrict__ out, int n) {
    int i = (blockIdx.x * 256 + threadIdx.x) * 4;
    if (i >= n) return;
    float4 v = *(const float4*)(in + i);
    u32 p0 = (u32)f2b(v.x) | ((u32)f2b(v.y) << 16);
    u32 p1 = (u32)f2b(v.z) | ((u32)f2b(v.w) << 16);
    *(uint2*)(out + i) = make_uint2(p0, p1);
}
// gcn_w [2][K=256][N=256] -> out [2][N][K] bf16 (transposed)
__global__ __launch_bounds__(256) void conv_gcnw_kernel(const float* __restrict__ w, u16* __restrict__ out) {
    int idx = blockIdx.x * 256 + threadIdx.x;   // 0..65535
    int l = blockIdx.y;
    int k = idx >> 8, n = idx & 255;
    out[(size_t)l * 65536 + n * 256 + k] = f2b(w[(size_t)l * 65536 + k * 256 + n]);
}

// ================= CSR build =================
#define EDGE_CAP 128
__global__ __launch_bounds__(256) void bucket_fill_kernel(
    const int* __restrict__ src, const int* __restrict__ dst,
    int* __restrict__ ebuf, int* __restrict__ cursor, int* __restrict__ cnt_out, int ne)
{
    int e = blockIdx.x * 256 + threadIdx.x;
    if (e >= ne) return;
    int s = src[e], d = dst[e];
    atomicAdd(&cnt_out[s], 1);
    int pos = atomicAdd(&cursor[d], 1);
    if (pos < EDGE_CAP) ebuf[(size_t)d * EDGE_CAP + pos] = s;
}
__global__ __launch_bounds__(256) void deg_fin_kernel(const int* __restrict__ cnt, float* __restrict__ dinv, int n) {
    int i = blockIdx.x * 256 + threadIdx.x;
    if (i < n) dinv[i] = rsqrtf(fmaxf((float)cnt[i], 1.0f));
}

// ================= CSR aggregate (bf16 in, fp32+bf16 out) =================
__global__ __launch_bounds__(256) void csr_agg_kernel(
    const u16* __restrict__ x, const int* __restrict__ ebuf,
    const int* __restrict__ deg, float* __restrict__ outf, u16* __restrict__ outb, int nnodes)
{
    int n = blockIdx.x * 4 + (threadIdx.x >> 6);
    if (n >= nnodes) return;
    int lane = threadIdx.x & 63;
    int d = deg[n];
    float dinv = rsqrtf(fmaxf((float)d, 1.0f));
    if (d > EDGE_CAP) d = EDGE_CAP;
    const int* eb = ebuf + (size_t)n * EDGE_CAP;
    float a0 = 0.f, a1 = 0.f, a2 = 0.f, a3 = 0.f;
    for (int k = 0; k < d; ++k) {
        int s = eb[k];
        uint2 v = *(const uint2*)(x + (size_t)s * 256 + (lane << 2));  // 4 bf16
        a0 += b2f_lo(v.x); a1 += b2f_hi(v.x);
        a2 += b2f_lo(v.y); a3 += b2f_hi(v.y);
    }
    a0 = fmaxf(a0 * dinv, 0.f); a1 = fmaxf(a1 * dinv, 0.f);
    a2 = fmaxf(a2 * dinv, 0.f); a3 = fmaxf(a3 * dinv, 0.f);
    float4 o = make_float4(a0, a1, a2, a3);
    *(float4*)(outf + (size_t)n * 256 + (lane << 2)) = o;
    u32 p0 = (u32)f2b(a0) | ((u32)f2b(a1) << 16);
    u32 p1 = (u32)f2b(a2) | ((u32)f2b(a3) << 16);
    *(uint2*)(outb + (size_t)n * 256 + (lane << 2)) = make_uint2(p0, p1);
}

// ================= gather rows (fp32 + bf16 out) =================
__global__ __launch_bounds__(256) void gather_kernel(
    const float* __restrict__ gh, const int* __restrict__ seqs,
    float* __restrict__ h, u16* __restrict__ hb, int nrows)
{
    int idx = blockIdx.x * 256 + threadIdx.x;
    int row = idx >> 6, c4 = (idx & 63) << 2;
    if (row >= nrows) return;
    int node = seqs[row];
    float4 v = *(const float4*)(gh + (size_t)node * 256 + c4);
    *(float4*)(h + (size_t)row * 256 + c4) = v;
    u32 p0 = (u32)f2b(v.x) | ((u32)f2b(v.y) << 16);
    u32 p1 = (u32)f2b(v.z) | ((u32)f2b(v.w) << 16);
    *(uint2*)(hb + (size_t)row * 256 + c4) = make_uint2(p0, p1);
}

// ================= attention (bf16 fr), score independent of query row =================
__global__ __launch_bounds__(64) void attn_kernel(
    const u16* __restrict__ fr, const float* __restrict__ ar,
    float* __restrict__ hsa)
{
    int b = blockIdx.x;
    int h = blockIdx.y;
    int j = threadIdx.x;   // 0..63
    const u16* frb = fr + (size_t)b * 64 * 256 + h * 128;
    const u16* rowp = frb + (size_t)j * 256;
    float s = 0.f;
    #pragma unroll
    for (int d0 = 0; d0 < 128; d0 += 8) {
        uint4 v = *(const uint4*)(rowp + d0);   // 8 bf16
        float x;
        x = b2f_lo(v.x); s += (x >= 0.f ? x : 0.01f * x) * ar[d0 + 0];
        x = b2f_hi(v.x); s += (x >= 0.f ? x : 0.01f * x) * ar[d0 + 1];
        x = b2f_lo(v.y); s += (x >= 0.f ? x : 0.01f * x) * ar[d0 + 2];
        x = b2f_hi(v.y); s += (x >= 0.f ? x : 0.01f * x) * ar[d0 + 3];
        x = b2f_lo(v.z); s += (x >= 0.f ? x : 0.01f * x) * ar[d0 + 4];
        x = b2f_hi(v.z); s += (x >= 0.f ? x : 0.01f * x) * ar[d0 + 5];
        x = b2f_lo(v.w); s += (x >= 0.f ? x : 0.01f * x) * ar[d0 + 6];
        x = b2f_hi(v.w); s += (x >= 0.f ? x : 0.01f * x) * ar[d0 + 7];
    }
    float mx = wave_max(s);
    float e = expf(s - mx);
    float sum = wave_sum(e);
    __shared__ float ps[64];
    ps[j] = e / sum;
    __syncthreads();
    float c0 = 0.f, c1 = 0.f;
    for (int jj = 0; jj < 64; ++jj) {
        float pj = ps[jj];
        c0 = fmaf(pj, b2f(frb[(size_t)jj * 256 + j]), c0);
        c1 = fmaf(pj, b2f(frb[(size_t)jj * 256 + 64 + j]), c1);
    }
    hsa[(size_t)b * 256 + h * 128 + j] = c0;
    hsa[(size_t)b * 256 + h * 128 + 64 + j] = c1;
}

// ================= h = LN(h + broadcast u) (fp32 + bf16 out) =================
__global__ __launch_bounds__(256) void add_ln_kernel(
    float* __restrict__ h, u16* __restrict__ hb, const float* __restrict__ u,
    const float* __restrict__ g, const float* __restrict__ beta, int nrows)
{
    int row = blockIdx.x * 4 + (threadIdx.x >> 6);
    int lane = threadIdx.x & 63;
    if (row >= nrows) return;
    int b = row >> 6;
    float4 hv = *(float4*)(h + (size_t)row * 256 + (lane << 2));
    float4 uv = *(const float4*)(u + (size_t)b * 256 + (lane << 2));
    float y0 = hv.x + uv.x, y1 = hv.y + uv.y, y2 = hv.z + uv.z, y3 = hv.w + uv.w;
    float s = y0 + y1 + y2 + y3;
    float q = y0 * y0 + y1 * y1 + y2 * y2 + y3 * y3;
    s = wave_sum(s); q = wave_sum(q);
    float mean = s * (1.f / 256.f);
    float var = q * (1.f / 256.f) - mean * mean;
    float inv = rsqrtf(var + 1e-5f);
    float4 gv = *(const float4*)(g + (lane << 2));
    float4 bv = *(const float4*)(beta + (lane << 2));
    float o0 = (y0 - mean) * inv * gv.x + bv.x;
    float o1 = (y1 - mean) * inv * gv.y + bv.y;
    float o2 = (y2 - mean) * inv * gv.z + bv.z;
    float o3 = (y3 - mean) * inv * gv.w + bv.w;
    *(float4*)(h + (size_t)row * 256 + (lane << 2)) = make_float4(o0, o1, o2, o3);
    u32 p0 = (u32)f2b(o0) | ((u32)f2b(o1) << 16);
    u32 p1 = (u32)f2b(o2) | ((u32)f2b(o3) << 16);
    *(uint2*)(hb + (size_t)row * 256 + (lane << 2)) = make_uint2(p0, p1);
}

// ================= final =================
__global__ __launch_bounds__(256) void final_kernel(
    const float* __restrict__ m2, const float* __restrict__ w3,
    const float* __restrict__ b3, float* __restrict__ out, int nrows)
{
    int row = blockIdx.x * 4 + (threadIdx.x >> 6);
    int lane = threadIdx.x & 63;
    if (row >= nrows) return;
    float s = m2[(size_t)row * 128 + lane] * w3[lane]
            + m2[(size_t)row * 128 + 64 + lane] * w3[64 + lane];
    s = wave_sum(s);
    if (lane == 0) out[row] = 1.f / (1.f + expf(-(s + b3[0])));
}

static inline int cdiv(int a, int b) { return (a + b - 1) / b; }

extern "C" void kernel_launch(void* const* d_in, const int* in_sizes, int n_in,
                              void* d_out, int out_size, void* d_ws, size_t ws_size,
                              hipStream_t stream)
{
    const float* feat0   = (const float*)d_in[0];
    const float* feat1   = (const float*)d_in[1];
    const float* fc_w0   = (const float*)d_in[2];
    const float* fc_b0   = (const float*)d_in[3];
    const float* fc_w1   = (const float*)d_in[4];
    const float* fc_b1   = (const float*)d_in[5];
    const float* gcn_w   = (const float*)d_in[6];
    const int*   edge_src= (const int*)d_in[7];
    const int*   edge_dst= (const int*)d_in[8];
    const int*   dg_seqs = (const int*)d_in[9];
    const int*   pt_seqs = (const int*)d_in[10];
    // 11 type_emb, 12 node_type: dead; 13 gt_wl, 15 gt_al: dead (softmax cancellation)
    const float* gt_wr   = (const float*)d_in[14];
    const float* gt_ar   = (const float*)d_in[16];
    const float* gt_wf   = (const float*)d_in[17];
    const float* ln_g    = (const float*)d_in[18];
    const float* ln_b    = (const float*)d_in[19];
    const float* proj_d_w= (const float*)d_in[20];
    const float* proj_d_b= (const float*)d_in[21];
    const float* proj_p_w= (const float*)d_in[22];
    const float* proj_p_b= (const float*)d_in[23];
    const float* ml_w1   = (const float*)d_in[24];
    const float* ml_b1   = (const float*)d_in[25];
    const float* ml_w2   = (const float*)d_in[26];
    const float* ml_b2   = (const float*)d_in[27];
    const float* ml_w3   = (const float*)d_in[28];
    const float* ml_b3   = (const float*)d_in[29];
    float* out = (float*)d_out;

    // ---- workspace layout (f32 units) ----
    float* base = (float*)d_ws;
    float* gh    = base;                     // 10,240,000 f32
    float* h     = gh + 10240000;            // 16,777,216 f32  (FC phase alias: feat0_b/feat1_b bf16)
    float* frR   = h + 16777216;             // 8,388,608 f32 region (fr_b bf16; GCN-phase alias: ebuf/cursor/cnt)
    float* ghbR  = frR + 8388608;            // 5,120,000 f32 region (gh_b bf16)
    float* hbR   = ghbR + 5120000;           // 8,388,608 f32 region (h_b bf16; GCN alias: tmp_b bf16)
    float* dego  = hbR + 8388608;            // 40,000
    float* hsa   = dego + 40000;             // 262,144
    float* u     = hsa + 262144;             // 262,144
    float* t1    = u + 262144;               // 262,144
    float* mx    = t1 + 262144;              // 524,288
    float* m1    = mx + 524288;              // 262,144
    float* m2    = m1 + 262144;              // 131,072
    float* wbR   = m2 + 131072;              // weights bf16: wr 262,144 + fcw 131,072 + gcnw 65,536 f32-equiv

    u16* feat0_b = (u16*)h;                  // 10,240,000 bf16
    u16* feat1_b = (u16*)h + 10240000;       // 10,240,000 bf16
    u16* fr_b    = (u16*)frR;                // 16,777,216 bf16
    int* ebuf    = (int*)frR;                // 5,120,000 int (GCN phase only)
    int* cursor  = ebuf + (size_t)40000 * EDGE_CAP;
    int* cnt_out = cursor + 40000;
    u16* gh_b    = (u16*)ghbR;               // 10,240,000 bf16
    u16* h_b     = (u16*)hbR;                // 16,777,216 bf16
    u16* tmp_b   = (u16*)hbR;                // 10,240,000 bf16 (GCN phase only)
    u16* wr_b    = (u16*)wbR;                // 524,288 bf16
    u16* fcw_b   = wr_b + 524288;            // 262,144 bf16 (fc_w0 then fc_w1)
    u16* gcnw_b  = fcw_b + 262144;           // 131,072 bf16 (transposed)

    // ---- weight/feature converts ----
    conv_flat_kernel<<<cdiv(10240000 / 4, 256), 256, 0, stream>>>(feat0, feat0_b, 10240000);
    conv_flat_kernel<<<cdiv(10240000 / 4, 256), 256, 0, stream>>>(feat1, feat1_b, 10240000);
    conv_flat_kernel<<<cdiv(524288 / 4, 256), 256, 0, stream>>>(gt_wr, wr_b, 524288);
    conv_flat_kernel<<<cdiv(131072 / 4, 256), 256, 0, stream>>>(fc_w0, fcw_b, 131072);
    conv_flat_kernel<<<cdiv(131072 / 4, 256), 256, 0, stream>>>(fc_w1, fcw_b + 131072, 131072);
    conv_gcnw_kernel<<<dim3(256, 2), 256, 0, stream>>>(gcn_w, gcnw_b);

    // ---- FC projections -> gh_b (bf16) ----
    mfma_gemm_kernel<<<dim3(2, cdiv(20000, 128)), 256, 0, stream>>>(
        feat0_b, fcw_b, fc_b0, nullptr, gh_b, 20000, 256, 512);
    mfma_gemm_kernel<<<dim3(2, cdiv(20000, 128)), 256, 0, stream>>>(
        feat1_b, fcw_b + 131072, fc_b1, nullptr, gh_b + (size_t)20000 * 256, 20000, 256, 512);

    // ---- CSR build (once) ----
    hipMemsetAsync(cursor, 0, 80000 * sizeof(int), stream);
    bucket_fill_kernel<<<2500, 256, 0, stream>>>(edge_src, edge_dst, ebuf, cursor, cnt_out, 640000);
    deg_fin_kernel<<<cdiv(40000, 256), 256, 0, stream>>>(cnt_out, dego, 40000);

    // ---- 2x GCN: MFMA gemm (rowscale in epilogue, commuted) -> CSR aggregate ----
    for (int l = 0; l < 2; ++l) {
        mfma_gemm_kernel<<<dim3(2, cdiv(40000, 128)), 256, 0, stream>>>(
            gh_b, gcnw_b + (size_t)l * 65536, nullptr, dego, tmp_b, 40000, 256, 256);
        csr_agg_kernel<<<10000, 256, 0, stream>>>(tmp_b, ebuf, cursor, gh, gh_b, 40000);
    }

    // ---- graph transformer per node type ----
    const int* seqs[2] = {dg_seqs, pt_seqs};
    const float* pw[2] = {proj_d_w, proj_p_w};
    const float* pb[2] = {proj_d_b, proj_p_b};
    for (int t = 0; t < 2; ++t) {
        gather_kernel<<<16384, 256, 0, stream>>>(gh, seqs[t], h, h_b, 65536);
        for (int l = 0; l < 4; ++l) {
            int i = t * 4 + l;
            mfma_gemm_kernel<<<dim3(2, 512), 256, 0, stream>>>(
                h_b, wr_b + (size_t)i * 65536, nullptr, nullptr, fr_b, 65536, 256, 256);
            attn_kernel<<<dim3(1024, 2), 64, 0, stream>>>(fr_b, gt_ar + (size_t)i * 128, hsa);
            gemm_kernel<true><<<dim3(4, 16), 256, 0, stream>>>(
                hsa, gt_wf + (size_t)i * 65536, nullptr, nullptr, u, 1024, 256, 256, 256, 256, 256, 0, 0);
            add_ln_kernel<<<16384, 256, 0, stream>>>(h, h_b, u, ln_g + i * 256, ln_b + i * 256, 65536);
        }
        gemm_kernel<true><<<dim3(4, 16), 256, 0, stream>>>(
            h, pw[t], pb[t], nullptr, t1, 1024, 256, 256, 64 * 256, 256, 256, 0, 2);
        gemm_kernel<true><<<dim3(4, 16), 256, 0, stream>>>(
            t1, pw[t] + 65536, pb[t] + 256, nullptr, mx, 1024, 256, 256, 256, 256, 512, t * 256, 0);
    }

    // ---- predict MLP ----
    gemm_kernel<true><<<dim3(4, 16), 256, 0, stream>>>(
        mx, ml_w1, ml_b1, nullptr, m1, 1024, 256, 512, 512, 512, 256, 0, 1);
    gemm_kernel<true><<<dim3(2, 16), 256, 0, stream>>>(
        m1, ml_w2, ml_b2, nullptr, m2, 1024, 128, 256, 256, 256, 128, 0, 1);
    final_kernel<<<256, 256, 0, stream>>>(m2, ml_w3, ml_b3, out, 1024);
}

// Round 4
// 1235.278 us; speedup vs baseline: 5.2488x; 1.0766x over previous
//
#include <hip/hip_runtime.h>
#include <hip/hip_bf16.h>
#include <math.h>

typedef unsigned int u32;
typedef unsigned short u16;
typedef __attribute__((ext_vector_type(8))) short bf16x8;
typedef __attribute__((ext_vector_type(4))) float f32x4;

__device__ __forceinline__ float b2f(u16 u) { union { u32 i; float f; } c; c.i = ((u32)u) << 16; return c.f; }
__device__ __forceinline__ u16 f2b(float f) { __hip_bfloat16 h = __float2bfloat16(f); u16 r; __builtin_memcpy(&r, &h, 2); return r; }
__device__ __forceinline__ float b2f_lo(u32 w) { union { u32 i; float f; } c; c.i = w << 16; return c.f; }
__device__ __forceinline__ float b2f_hi(u32 w) { union { u32 i; float f; } c; c.i = w & 0xffff0000u; return c.f; }

__device__ __forceinline__ float wave_sum(float v) {
    #pragma unroll
    for (int off = 32; off > 0; off >>= 1) v += __shfl_xor(v, off, 64);
    return v;
}
__device__ __forceinline__ float wave_max(float v) {
    #pragma unroll
    for (int off = 32; off > 0; off >>= 1) v = fmaxf(v, __shfl_xor(v, off, 64));
    return v;
}

// ================= generic bf16 MFMA GEMM (128x128 tile, 4 waves) =================
// C[M,N] = (A[M,K] @ B[N,K]^T) (+bias[col]) (*rowscale[row]) -> bf16 out
// AF32: A is fp32 (converted to bf16 during staging); else A is bf16.
template<bool AF32>
__global__ __launch_bounds__(256) void mfma_gemm_kernel(
    const void* __restrict__ Av, const u16* __restrict__ B,
    const float* __restrict__ bias, const float* __restrict__ rowscale,
    u16* __restrict__ Cb, int M, int N, int K)
{
    __shared__ u16 lds[2 * 128 * 64];   // A at byte 0, B at byte 16384
    const int tid = threadIdx.x;
    const int wid = tid >> 6, lane = tid & 63;
    const int wr = wid >> 1, wc = wid & 1;
    const int m0 = blockIdx.y * 128, n0 = blockIdx.x * 128;

    f32x4 acc[4][4] = {};

    const int rsub = lane >> 3;              // 0..7
    const int cbyte = (lane & 7) << 4;       // 0..112 (bf16-layout byte offset)
    const int swz_st = cbyte ^ (rsub << 4);  // write-side XOR swizzle

    for (int k0 = 0; k0 < K; k0 += 64) {
        #pragma unroll
        for (int cc = 0; cc < 8; ++cc) {
            int c = wid * 8 + cc;
            int buf = c >> 4;                      // 0=A, 1=B
            int row_in = ((c & 15) << 3) + rsub;   // 0..127
            int lim = buf ? N : M;
            int row_g = (buf ? n0 : m0) + row_in;
            if (row_g >= lim) row_g = lim - 1;
            if (buf == 0 && AF32) {
                const float* src = (const float*)Av + (size_t)row_g * K + k0 + (cbyte >> 1);
                float4 v0 = *(const float4*)src;
                float4 v1 = *(const float4*)(src + 4);
                u32 p0 = (u32)f2b(v0.x) | ((u32)f2b(v0.y) << 16);
                u32 p1 = (u32)f2b(v0.z) | ((u32)f2b(v0.w) << 16);
                u32 p2 = (u32)f2b(v1.x) | ((u32)f2b(v1.y) << 16);
                u32 p3 = (u32)f2b(v1.z) | ((u32)f2b(v1.w) << 16);
                *(uint4*)((char*)lds + row_in * 128 + swz_st) = make_uint4(p0, p1, p2, p3);
            } else {
                const u16* srcb = (buf ? B : (const u16*)Av) + (size_t)row_g * K + k0 + (cbyte >> 1);
                f32x4 v = *(const f32x4*)srcb;
                *(f32x4*)((char*)lds + buf * 16384 + row_in * 128 + swz_st) = v;
            }
        }
        __syncthreads();
        #pragma unroll
        for (int ks = 0; ks < 2; ++ks) {
            const int kbyte = ks * 64 + ((lane >> 4) << 4);
            const int off = kbyte ^ ((lane & 7) << 4);
            const int ra = lane & 15;
            bf16x8 af[4], bfr[4];
            #pragma unroll
            for (int i = 0; i < 4; ++i) {
                int r = wr * 64 + i * 16 + ra;
                af[i] = *(bf16x8*)((char*)lds + r * 128 + off);
            }
            #pragma unroll
            for (int j = 0; j < 4; ++j) {
                int r = wc * 64 + j * 16 + ra;
                bfr[j] = *(bf16x8*)((char*)lds + 16384 + r * 128 + off);
            }
            #pragma unroll
            for (int i = 0; i < 4; ++i)
                #pragma unroll
                for (int j = 0; j < 4; ++j)
                    acc[i][j] = __builtin_amdgcn_mfma_f32_16x16x32_bf16(af[i], bfr[j], acc[i][j], 0, 0, 0);
        }
        __syncthreads();
    }

    const int cr = lane >> 4, ccol = lane & 15;
    #pragma unroll
    for (int i = 0; i < 4; ++i) {
        #pragma unroll
        for (int j = 0; j < 4; ++j) {
            int colg = n0 + wc * 64 + j * 16 + ccol;
            if (colg >= N) continue;
            float badd = bias ? bias[colg] : 0.f;
            #pragma unroll
            for (int reg = 0; reg < 4; ++reg) {
                int rowg = m0 + wr * 64 + i * 16 + cr * 4 + reg;
                if (rowg >= M) continue;
                float v = acc[i][j][reg] + badd;
                if (rowscale) v *= rowscale[rowg];
                Cb[(size_t)rowg * N + colg] = f2b(v);
            }
        }
    }
}

// ================= fused fr-GEMM + attention =================
// Block = 128 rows of h (= 2 sequences) x full N=256. 8 waves (2 row x 4 col).
// Computes fr = h @ wr^T in MFMA accs, then per (seq,head) softmax over the 64
// seq rows (score independent of query row) and ctx, writing hsa[2,256] only.
__global__ __launch_bounds__(512) void fused_fr_attn_kernel(
    const u16* __restrict__ Ab,   // h_b [65536,256] bf16
    const u16* __restrict__ Bb,   // wr_b [256,256] bf16
    const float* __restrict__ ar, // [128]
    float* __restrict__ hsa)      // [1024,256]
{
    __shared__ u16 ldsA[128 * 64];
    __shared__ u16 ldsB[256 * 64];
    __shared__ float sPart[2][2][2][64];
    __shared__ float pbuf[2][2][64];

    const int tid = threadIdx.x;
    const int wid = tid >> 6, lane = tid & 63;
    const int wr = wid >> 2, wc = wid & 3;
    const int m0 = blockIdx.x * 128;

    f32x4 acc[4][4] = {};

    const int rsub = lane >> 3;
    const int cbyte = (lane & 7) << 4;
    const int swz_st = cbyte ^ (rsub << 4);

    for (int k0 = 0; k0 < 256; k0 += 64) {
        #pragma unroll
        for (int cc = 0; cc < 6; ++cc) {
            int c = wid * 6 + cc;                 // 0..47
            if (c < 16) {
                int row_in = (c << 3) + rsub;     // 0..127 (M=65536, always in-bounds)
                f32x4 v = *(const f32x4*)(Ab + (size_t)(m0 + row_in) * 256 + k0 + (cbyte >> 1));
                *(f32x4*)((char*)ldsA + row_in * 128 + swz_st) = v;
            } else {
                int row_in = ((c - 16) << 3) + rsub;  // 0..255
                f32x4 v = *(const f32x4*)(Bb + (size_t)row_in * 256 + k0 + (cbyte >> 1));
                *(f32x4*)((char*)ldsB + row_in * 128 + swz_st) = v;
            }
        }
        __syncthreads();
        #pragma unroll
        for (int ks = 0; ks < 2; ++ks) {
            const int kbyte = ks * 64 + ((lane >> 4) << 4);
            const int off = kbyte ^ ((lane & 7) << 4);
            const int ra = lane & 15;
            bf16x8 af[4], bfr[4];
            #pragma unroll
            for (int i = 0; i < 4; ++i) {
                int r = wr * 64 + i * 16 + ra;
                af[i] = *(bf16x8*)((char*)ldsA + r * 128 + off);
            }
            #pragma unroll
            for (int j = 0; j < 4; ++j) {
                int r = wc * 64 + j * 16 + ra;
                bfr[j] = *(bf16x8*)((char*)ldsB + r * 128 + off);
            }
            #pragma unroll
            for (int i = 0; i < 4; ++i)
                #pragma unroll
                for (int j = 0; j < 4; ++j)
                    acc[i][j] = __builtin_amdgcn_mfma_f32_16x16x32_bf16(af[i], bfr[j], acc[i][j], 0, 0, 0);
        }
        __syncthreads();
    }

    // ---- attention. acc[i][j][reg] = fr[row=wr*64+i*16+g4*4+reg][col=wc*64+j*16+cl]
    const int g4 = lane >> 4;     // row quarter
    const int cl = lane & 15;     // col within 16
    const int hd = wc >> 1, ch = wc & 1;

    float arj[4];
    #pragma unroll
    for (int j = 0; j < 4; ++j) arj[j] = ar[ch * 64 + j * 16 + cl];

    // per-row score partial over this wave's 64 cols
    float sp[4][4];
    #pragma unroll
    for (int i = 0; i < 4; ++i)
        #pragma unroll
        for (int reg = 0; reg < 4; ++reg) {
            float s = 0.f;
            #pragma unroll
            for (int j = 0; j < 4; ++j) {
                float x = acc[i][j][reg];
                s = fmaf(x >= 0.f ? x : 0.01f * x, arj[j], s);
            }
            float v = s;
            v += __shfl_xor(v, 1, 64);
            v += __shfl_xor(v, 2, 64);
            v += __shfl_xor(v, 4, 64);
            v += __shfl_xor(v, 8, 64);
            sp[i][reg] = v;
        }
    if (cl == 0) {
        #pragma unroll
        for (int i = 0; i < 4; ++i)
            #pragma unroll
            for (int reg = 0; reg < 4; ++reg)
                sPart[wr][hd][ch][i * 16 + g4 * 4 + reg] = sp[i][reg];
    }
    __syncthreads();

    // softmax over the 64 rows of (seq=wr, head=hd); all waves of pair compute, ch==0 writes
    {
        float s = sPart[wr][hd][0][lane] + sPart[wr][hd][1][lane];
        float mx = wave_max(s);
        float e = expf(s - mx);
        float sum = wave_sum(e);
        if (ch == 0) pbuf[wr][hd][lane] = e / sum;
    }
    __syncthreads();

    // ctx for this wave's 64 cols
    float pv[4][4];
    #pragma unroll
    for (int i = 0; i < 4; ++i)
        #pragma unroll
        for (int reg = 0; reg < 4; ++reg)
            pv[i][reg] = pbuf[wr][hd][i * 16 + g4 * 4 + reg];
    #pragma unroll
    for (int j = 0; j < 4; ++j) {
        float c = 0.f;
        #pragma unroll
        for (int i = 0; i < 4; ++i)
            #pragma unroll
            for (int reg = 0; reg < 4; ++reg)
                c = fmaf(pv[i][reg], acc[i][j][reg], c);
        c += __shfl_xor(c, 16, 64);
        c += __shfl_xor(c, 32, 64);
        if (g4 == 0)
            hsa[(size_t)(blockIdx.x * 2 + wr) * 256 + wc * 64 + j * 16 + cl] = c;
    }
}

// ================= fp32 tiled GEMM (small M) =================
template<bool BT>
__global__ __launch_bounds__(256) void gemm_kernel(
    const float* __restrict__ A, const float* __restrict__ B,
    const float* __restrict__ bias, const float* __restrict__ rowscale,
    float* __restrict__ C,
    int M, int N, int K, int lda, int ldb, int ldc, int coff, int act)
{
    __shared__ float As[32][64 + 4];
    __shared__ float Bs[32][64 + 4];
    const int tid = threadIdx.x;
    const int m0 = blockIdx.y * 64;
    const int n0 = blockIdx.x * 64;
    const int ty = tid >> 4, tx = tid & 15;
    float acc[4][4] = {};
    for (int k0 = 0; k0 < K; k0 += 32) {
        #pragma unroll
        for (int r = 0; r < 2; ++r) {
            int f4 = tid + r * 256;
            int arw = f4 >> 3, af = (f4 & 7) << 2;
            float4 v = make_float4(0.f, 0.f, 0.f, 0.f);
            int grow = m0 + arw;
            if (grow < M) {
                v = *(const float4*)(A + (size_t)grow * lda + k0 + af);
                if (rowscale) { float s = rowscale[grow]; v.x *= s; v.y *= s; v.z *= s; v.w *= s; }
            }
            As[af + 0][arw] = v.x; As[af + 1][arw] = v.y; As[af + 2][arw] = v.z; As[af + 3][arw] = v.w;
        }
        #pragma unroll
        for (int r = 0; r < 2; ++r) {
            int f4 = tid + r * 256;
            int col = f4 >> 3, kf = (f4 & 7) << 2;
            float4 v = make_float4(0.f, 0.f, 0.f, 0.f);
            if (n0 + col < N) v = *(const float4*)(B + (size_t)(n0 + col) * ldb + k0 + kf);
            Bs[kf + 0][col] = v.x; Bs[kf + 1][col] = v.y; Bs[kf + 2][col] = v.z; Bs[kf + 3][col] = v.w;
        }
        __syncthreads();
        #pragma unroll
        for (int kk = 0; kk < 32; ++kk) {
            float4 a4 = *(const float4*)&As[kk][ty << 2];
            float4 b4 = *(const float4*)&Bs[kk][tx << 2];
            float a[4] = {a4.x, a4.y, a4.z, a4.w};
            float b[4] = {b4.x, b4.y, b4.z, b4.w};
            #pragma unroll
            for (int i = 0; i < 4; ++i)
                #pragma unroll
                for (int j = 0; j < 4; ++j)
                    acc[i][j] = fmaf(a[i], b[j], acc[i][j]);
        }
        __syncthreads();
    }
    #pragma unroll
    for (int i = 0; i < 4; ++i) {
        int row = m0 + (ty << 2) + i;
        if (row >= M) continue;
        #pragma unroll
        for (int j = 0; j < 4; ++j) {
            int col = n0 + (tx << 2) + j;
            if (col >= N) continue;
            float v = acc[i][j];
            if (bias) v += bias[col];
            if (act == 1) v = fmaxf(v, 0.f);
            else if (act == 2) v = (v > 0.f) ? v : expm1f(v);
            C[(size_t)row * ldc + coff + col] = v;
        }
    }
}

// ================= converts =================
__global__ __launch_bounds__(256) void conv_flat_kernel(const float* __restrict__ in, u16* __restrict__ out, int n) {
    int i = (blockIdx.x * 256 + threadIdx.x) * 4;
    if (i >= n) return;
    float4 v = *(const float4*)(in + i);
    u32 p0 = (u32)f2b(v.x) | ((u32)f2b(v.y) << 16);
    u32 p1 = (u32)f2b(v.z) | ((u32)f2b(v.w) << 16);
    *(uint2*)(out + i) = make_uint2(p0, p1);
}
__global__ __launch_bounds__(256) void conv_gcnw_kernel(const float* __restrict__ w, u16* __restrict__ out) {
    int idx = blockIdx.x * 256 + threadIdx.x;   // 0..65535
    int l = blockIdx.y;
    int k = idx >> 8, n = idx & 255;
    out[(size_t)l * 65536 + n * 256 + k] = f2b(w[(size_t)l * 65536 + k * 256 + n]);
}

// ================= CSR build =================
#define EDGE_CAP 128
__global__ __launch_bounds__(256) void bucket_fill_kernel(
    const int* __restrict__ src, const int* __restrict__ dst,
    int* __restrict__ ebuf, int* __restrict__ cursor, int* __restrict__ cnt_out, int ne)
{
    int e = blockIdx.x * 256 + threadIdx.x;
    if (e >= ne) return;
    int s = src[e], d = dst[e];
    atomicAdd(&cnt_out[s], 1);
    int pos = atomicAdd(&cursor[d], 1);
    if (pos < EDGE_CAP) ebuf[(size_t)d * EDGE_CAP + pos] = s;
}
__global__ __launch_bounds__(256) void deg_fin_kernel(const int* __restrict__ cnt, float* __restrict__ dinv, int n) {
    int i = blockIdx.x * 256 + threadIdx.x;
    if (i < n) dinv[i] = rsqrtf(fmaxf((float)cnt[i], 1.0f));
}

// ================= CSR aggregate (bf16 in, fp32+bf16 out), 4x unrolled =================
__global__ __launch_bounds__(256) void csr_agg_kernel(
    const u16* __restrict__ x, const int* __restrict__ ebuf,
    const int* __restrict__ deg, float* __restrict__ outf, u16* __restrict__ outb, int nnodes)
{
    int n = blockIdx.x * 4 + (threadIdx.x >> 6);
    if (n >= nnodes) return;
    int lane = threadIdx.x & 63;
    int d = deg[n];
    float dinv = rsqrtf(fmaxf((float)d, 1.0f));
    if (d > EDGE_CAP) d = EDGE_CAP;
    const int* eb = ebuf + (size_t)n * EDGE_CAP;
    const int co = lane << 2;
    float a0 = 0.f, a1 = 0.f, a2 = 0.f, a3 = 0.f;
    int k = 0;
    for (; k + 4 <= d; k += 4) {
        int4 s4 = *(const int4*)(eb + k);
        uint2 va = *(const uint2*)(x + (size_t)s4.x * 256 + co);
        uint2 vb = *(const uint2*)(x + (size_t)s4.y * 256 + co);
        uint2 vc = *(const uint2*)(x + (size_t)s4.z * 256 + co);
        uint2 vd = *(const uint2*)(x + (size_t)s4.w * 256 + co);
        a0 += b2f_lo(va.x) + b2f_lo(vb.x) + b2f_lo(vc.x) + b2f_lo(vd.x);
        a1 += b2f_hi(va.x) + b2f_hi(vb.x) + b2f_hi(vc.x) + b2f_hi(vd.x);
        a2 += b2f_lo(va.y) + b2f_lo(vb.y) + b2f_lo(vc.y) + b2f_lo(vd.y);
        a3 += b2f_hi(va.y) + b2f_hi(vb.y) + b2f_hi(vc.y) + b2f_hi(vd.y);
    }
    for (; k < d; ++k) {
        int s = eb[k];
        uint2 v = *(const uint2*)(x + (size_t)s * 256 + co);
        a0 += b2f_lo(v.x); a1 += b2f_hi(v.x);
        a2 += b2f_lo(v.y); a3 += b2f_hi(v.y);
    }
    a0 = fmaxf(a0 * dinv, 0.f); a1 = fmaxf(a1 * dinv, 0.f);
    a2 = fmaxf(a2 * dinv, 0.f); a3 = fmaxf(a3 * dinv, 0.f);
    *(float4*)(outf + (size_t)n * 256 + co) = make_float4(a0, a1, a2, a3);
    u32 p0 = (u32)f2b(a0) | ((u32)f2b(a1) << 16);
    u32 p1 = (u32)f2b(a2) | ((u32)f2b(a3) << 16);
    *(uint2*)(outb + (size_t)n * 256 + co) = make_uint2(p0, p1);
}

// ================= gather rows (fp32 + bf16 out) =================
__global__ __launch_bounds__(256) void gather_kernel(
    const float* __restrict__ gh, const int* __restrict__ seqs,
    float* __restrict__ h, u16* __restrict__ hb, int nrows)
{
    int idx = blockIdx.x * 256 + threadIdx.x;
    int row = idx >> 6, c4 = (idx & 63) << 2;
    if (row >= nrows) return;
    int node = seqs[row];
    float4 v = *(const float4*)(gh + (size_t)node * 256 + c4);
    *(float4*)(h + (size_t)row * 256 + c4) = v;
    u32 p0 = (u32)f2b(v.x) | ((u32)f2b(v.y) << 16);
    u32 p1 = (u32)f2b(v.z) | ((u32)f2b(v.w) << 16);
    *(uint2*)(hb + (size_t)row * 256 + c4) = make_uint2(p0, p1);
}

// ================= h = LN(h + broadcast u) (fp32 + bf16 out) =================
__global__ __launch_bounds__(256) void add_ln_kernel(
    float* __restrict__ h, u16* __restrict__ hb, const float* __restrict__ u,
    const float* __restrict__ g, const float* __restrict__ beta, int nrows)
{
    int row = blockIdx.x * 4 + (threadIdx.x >> 6);
    int lane = threadIdx.x & 63;
    if (row >= nrows) return;
    int b = row >> 6;
    float4 hv = *(float4*)(h + (size_t)row * 256 + (lane << 2));
    float4 uv = *(const float4*)(u + (size_t)b * 256 + (lane << 2));
    float y0 = hv.x + uv.x, y1 = hv.y + uv.y, y2 = hv.z + uv.z, y3 = hv.w + uv.w;
    float s = y0 + y1 + y2 + y3;
    float q = y0 * y0 + y1 * y1 + y2 * y2 + y3 * y3;
    s = wave_sum(s); q = wave_sum(q);
    float mean = s * (1.f / 256.f);
    float var = q * (1.f / 256.f) - mean * mean;
    float inv = rsqrtf(var + 1e-5f);
    float4 gv = *(const float4*)(g + (lane << 2));
    float4 bv = *(const float4*)(beta + (lane << 2));
    float o0 = (y0 - mean) * inv * gv.x + bv.x;
    float o1 = (y1 - mean) * inv * gv.y + bv.y;
    float o2 = (y2 - mean) * inv * gv.z + bv.z;
    float o3 = (y3 - mean) * inv * gv.w + bv.w;
    *(float4*)(h + (size_t)row * 256 + (lane << 2)) = make_float4(o0, o1, o2, o3);
    u32 p0 = (u32)f2b(o0) | ((u32)f2b(o1) << 16);
    u32 p1 = (u32)f2b(o2) | ((u32)f2b(o3) << 16);
    *(uint2*)(hb + (size_t)row * 256 + (lane << 2)) = make_uint2(p0, p1);
}

// ================= final =================
__global__ __launch_bounds__(256) void final_kernel(
    const float* __restrict__ m2, const float* __restrict__ w3,
    const float* __restrict__ b3, float* __restrict__ out, int nrows)
{
    int row = blockIdx.x * 4 + (threadIdx.x >> 6);
    int lane = threadIdx.x & 63;
    if (row >= nrows) return;
    float s = m2[(size_t)row * 128 + lane] * w3[lane]
            + m2[(size_t)row * 128 + 64 + lane] * w3[64 + lane];
    s = wave_sum(s);
    if (lane == 0) out[row] = 1.f / (1.f + expf(-(s + b3[0])));
}

static inline int cdiv(int a, int b) { return (a + b - 1) / b; }

extern "C" void kernel_launch(void* const* d_in, const int* in_sizes, int n_in,
                              void* d_out, int out_size, void* d_ws, size_t ws_size,
                              hipStream_t stream)
{
    const float* feat0   = (const float*)d_in[0];
    const float* feat1   = (const float*)d_in[1];
    const float* fc_w0   = (const float*)d_in[2];
    const float* fc_b0   = (const float*)d_in[3];
    const float* fc_w1   = (const float*)d_in[4];
    const float* fc_b1   = (const float*)d_in[5];
    const float* gcn_w   = (const float*)d_in[6];
    const int*   edge_src= (const int*)d_in[7];
    const int*   edge_dst= (const int*)d_in[8];
    const int*   dg_seqs = (const int*)d_in[9];
    const int*   pt_seqs = (const int*)d_in[10];
    // 11 type_emb, 12 node_type: dead; 13 gt_wl, 15 gt_al: dead (softmax cancellation)
    const float* gt_wr   = (const float*)d_in[14];
    const float* gt_ar   = (const float*)d_in[16];
    const float* gt_wf   = (const float*)d_in[17];
    const float* ln_g    = (const float*)d_in[18];
    const float* ln_b    = (const float*)d_in[19];
    const float* proj_d_w= (const float*)d_in[20];
    const float* proj_d_b= (const float*)d_in[21];
    const float* proj_p_w= (const float*)d_in[22];
    const float* proj_p_b= (const float*)d_in[23];
    const float* ml_w1   = (const float*)d_in[24];
    const float* ml_b1   = (const float*)d_in[25];
    const float* ml_w2   = (const float*)d_in[26];
    const float* ml_b2   = (const float*)d_in[27];
    const float* ml_w3   = (const float*)d_in[28];
    const float* ml_b3   = (const float*)d_in[29];
    float* out = (float*)d_out;

    // ---- workspace layout (f32 units) ----
    float* base  = (float*)d_ws;
    float* gh    = base;                     // 10,240,000 f32
    float* h     = gh + 10240000;            // 16,777,216 f32
    float* hbR   = h + 16777216;             // 8,388,608  (h_b bf16)
    float* ghbR  = hbR + 8388608;            // 5,120,000  (gh_b bf16)
    float* tmpbR = ghbR + 5120000;           // 5,120,000  (tmp_b bf16, GCN phase)
    float* ebR   = tmpbR + 5120000;          // 5,200,000  (ebuf+cursor+cnt ints)
    float* dego  = ebR + 5200000;            // 40,000
    float* hsa   = dego + 40000;             // 262,144
    float* u     = hsa + 262144;             // 262,144
    float* t1    = u + 262144;               // 262,144
    float* mx    = t1 + 262144;              // 524,288
    float* m1    = mx + 524288;              // 262,144
    float* m2    = m1 + 262144;              // 131,072
    float* wbR   = m2 + 131072;              // bf16 weights

    u16* h_b     = (u16*)hbR;
    u16* gh_b    = (u16*)ghbR;
    u16* tmp_b   = (u16*)tmpbR;
    int* ebuf    = (int*)ebR;                // 40000*128
    int* cursor  = ebuf + (size_t)40000 * EDGE_CAP;
    int* cnt_out = cursor + 40000;
    u16* wr_b    = (u16*)wbR;                // 524,288 bf16
    u16* fcw_b   = wr_b + 524288;            // 262,144 bf16
    u16* gcnw_b  = fcw_b + 262144;           // 131,072 bf16 (transposed)

    // ---- weight converts ----
    conv_flat_kernel<<<cdiv(524288 / 4, 256), 256, 0, stream>>>(gt_wr, wr_b, 524288);
    conv_flat_kernel<<<cdiv(131072 / 4, 256), 256, 0, stream>>>(fc_w0, fcw_b, 131072);
    conv_flat_kernel<<<cdiv(131072 / 4, 256), 256, 0, stream>>>(fc_w1, fcw_b + 131072, 131072);
    conv_gcnw_kernel<<<dim3(256, 2), 256, 0, stream>>>(gcn_w, gcnw_b);

    // ---- FC projections (fp32 A staged->bf16 in-kernel) -> gh_b ----
    mfma_gemm_kernel<true><<<dim3(2, cdiv(20000, 128)), 256, 0, stream>>>(
        feat0, fcw_b, fc_b0, nullptr, gh_b, 20000, 256, 512);
    mfma_gemm_kernel<true><<<dim3(2, cdiv(20000, 128)), 256, 0, stream>>>(
        feat1, fcw_b + 131072, fc_b1, nullptr, gh_b + (size_t)20000 * 256, 20000, 256, 512);

    // ---- CSR build (once) ----
    hipMemsetAsync(cursor, 0, 80000 * sizeof(int), stream);
    bucket_fill_kernel<<<2500, 256, 0, stream>>>(edge_src, edge_dst, ebuf, cursor, cnt_out, 640000);
    deg_fin_kernel<<<cdiv(40000, 256), 256, 0, stream>>>(cnt_out, dego, 40000);

    // ---- 2x GCN ----
    for (int l = 0; l < 2; ++l) {
        mfma_gemm_kernel<false><<<dim3(2, cdiv(40000, 128)), 256, 0, stream>>>(
            gh_b, gcnw_b + (size_t)l * 65536, nullptr, dego, tmp_b, 40000, 256, 256);
        csr_agg_kernel<<<10000, 256, 0, stream>>>(tmp_b, ebuf, cursor, gh, gh_b, 40000);
    }

    // ---- graph transformer per node type ----
    const int* seqs[2] = {dg_seqs, pt_seqs};
    const float* pw[2] = {proj_d_w, proj_p_w};
    const float* pb[2] = {proj_d_b, proj_p_b};
    for (int t = 0; t < 2; ++t) {
        gather_kernel<<<16384, 256, 0, stream>>>(gh, seqs[t], h, h_b, 65536);
        for (int l = 0; l < 4; ++l) {
            int i = t * 4 + l;
            fused_fr_attn_kernel<<<512, 512, 0, stream>>>(
                h_b, wr_b + (size_t)i * 65536, gt_ar + (size_t)i * 128, hsa);
            gemm_kernel<true><<<dim3(4, 16), 256, 0, stream>>>(
                hsa, gt_wf + (size_t)i * 65536, nullptr, nullptr, u, 1024, 256, 256, 256, 256, 256, 0, 0);
            add_ln_kernel<<<16384, 256, 0, stream>>>(h, h_b, u, ln_g + i * 256, ln_b + i * 256, 65536);
        }
        gemm_kernel<true><<<dim3(4, 16), 256, 0, stream>>>(
            h, pw[t], pb[t], nullptr, t1, 1024, 256, 256, 64 * 256, 256, 256, 0, 2);
        gemm_kernel<true><<<dim3(4, 16), 256, 0, stream>>>(
            t1, pw[t] + 65536, pb[t] + 256, nullptr, mx, 1024, 256, 256, 256, 256, 512, t * 256, 0);
    }

    // ---- predict MLP ----
    gemm_kernel<true><<<dim3(4, 16), 256, 0, stream>>>(
        mx, ml_w1, ml_b1, nullptr, m1, 1024, 256, 512, 512, 512, 256, 0, 1);
    gemm_kernel<true><<<dim3(2, 16), 256, 0, stream>>>(
        m1, ml_w2, ml_b2, nullptr, m2, 1024, 128, 256, 256, 256, 128, 0, 1);
    final_kernel<<<256, 256, 0, stream>>>(m2, ml_w3, ml_b3, out, 1024);
}

// Round 5
// 1108.633 us; speedup vs baseline: 5.8484x; 1.1142x over previous
//
#include <hip/hip_runtime.h>
#include <hip/hip_bf16.h>
#include <math.h>

typedef unsigned int u32;
typedef unsigned short u16;
typedef __attribute__((ext_vector_type(8))) short bf16x8;
typedef __attribute__((ext_vector_type(4))) float f32x4;

__device__ __forceinline__ float b2f(u16 u) { union { u32 i; float f; } c; c.i = ((u32)u) << 16; return c.f; }
__device__ __forceinline__ u16 f2b(float f) { __hip_bfloat16 h = __float2bfloat16(f); u16 r; __builtin_memcpy(&r, &h, 2); return r; }
__device__ __forceinline__ float b2f_lo(u32 w) { union { u32 i; float f; } c; c.i = w << 16; return c.f; }
__device__ __forceinline__ float b2f_hi(u32 w) { union { u32 i; float f; } c; c.i = w & 0xffff0000u; return c.f; }

__device__ __forceinline__ float wave_sum(float v) {
    #pragma unroll
    for (int off = 32; off > 0; off >>= 1) v += __shfl_xor(v, off, 64);
    return v;
}
__device__ __forceinline__ float wave_max(float v) {
    #pragma unroll
    for (int off = 32; off > 0; off >>= 1) v = fmaxf(v, __shfl_xor(v, off, 64));
    return v;
}

// ================= generic bf16 MFMA GEMM (128x128 tile, 8 waves of 32x64) ====
// C[M,N] = (A[M,K] @ B[N,K]^T) (+bias[col]) (*rowscale[row]) -> bf16 out
// AF32: A is fp32 (converted to bf16 during staging); else A is bf16.
template<bool AF32>
__global__ __launch_bounds__(512) void mfma_gemm_kernel(
    const void* __restrict__ Av, const u16* __restrict__ B,
    const float* __restrict__ bias, const float* __restrict__ rowscale,
    u16* __restrict__ Cb, int M, int N, int K)
{
    __shared__ u16 lds[2 * 128 * 64];   // A bytes [0,16384), B bytes [16384,32768)
    const int tid = threadIdx.x;
    const int wid = tid >> 6, lane = tid & 63;
    const int wr = wid >> 1, wc = wid & 1;   // 4 row-strips x 2 col-strips
    const int m0 = blockIdx.y * 128, n0 = blockIdx.x * 128;

    f32x4 acc[2][4] = {};

    const int rsub = lane >> 3;              // 0..7
    const int cbyte = (lane & 7) << 4;       // 0..112
    const int swz_st = cbyte ^ (rsub << 4);

    for (int k0 = 0; k0 < K; k0 += 64) {
        #pragma unroll
        for (int cc = 0; cc < 4; ++cc) {
            int c = wid * 4 + cc;                  // 0..31
            int buf = c >> 4;                      // 0=A, 1=B
            int row_in = ((c & 15) << 3) + rsub;   // 0..127
            int lim = buf ? N : M;
            int row_g = (buf ? n0 : m0) + row_in;
            if (row_g >= lim) row_g = lim - 1;
            if (buf == 0 && AF32) {
                const float* src = (const float*)Av + (size_t)row_g * K + k0 + (cbyte >> 1);
                float4 v0 = *(const float4*)src;
                float4 v1 = *(const float4*)(src + 4);
                uint4 pk;
                pk.x = (u32)f2b(v0.x) | ((u32)f2b(v0.y) << 16);
                pk.y = (u32)f2b(v0.z) | ((u32)f2b(v0.w) << 16);
                pk.z = (u32)f2b(v1.x) | ((u32)f2b(v1.y) << 16);
                pk.w = (u32)f2b(v1.z) | ((u32)f2b(v1.w) << 16);
                *(uint4*)((char*)lds + row_in * 128 + swz_st) = pk;
            } else {
                const u16* srcb = (buf ? B : (const u16*)Av) + (size_t)row_g * K + k0 + (cbyte >> 1);
                f32x4 v = *(const f32x4*)srcb;
                *(f32x4*)((char*)lds + buf * 16384 + row_in * 128 + swz_st) = v;
            }
        }
        __syncthreads();
        #pragma unroll
        for (int ks = 0; ks < 2; ++ks) {
            const int off = (ks * 64 + ((lane >> 4) << 4)) ^ ((lane & 7) << 4);
            const int ra = lane & 15;
            bf16x8 af[2], bfr[4];
            #pragma unroll
            for (int i = 0; i < 2; ++i)
                af[i] = *(bf16x8*)((char*)lds + (wr * 32 + i * 16 + ra) * 128 + off);
            #pragma unroll
            for (int j = 0; j < 4; ++j)
                bfr[j] = *(bf16x8*)((char*)lds + 16384 + (wc * 64 + j * 16 + ra) * 128 + off);
            #pragma unroll
            for (int i = 0; i < 2; ++i)
                #pragma unroll
                for (int j = 0; j < 4; ++j)
                    acc[i][j] = __builtin_amdgcn_mfma_f32_16x16x32_bf16(af[i], bfr[j], acc[i][j], 0, 0, 0);
        }
        __syncthreads();
    }

    const int cr = lane >> 4, ccol = lane & 15;
    #pragma unroll
    for (int i = 0; i < 2; ++i) {
        #pragma unroll
        for (int j = 0; j < 4; ++j) {
            int colg = n0 + wc * 64 + j * 16 + ccol;
            if (colg >= N) continue;
            float badd = bias ? bias[colg] : 0.f;
            #pragma unroll
            for (int reg = 0; reg < 4; ++reg) {
                int rowg = m0 + wr * 32 + i * 16 + cr * 4 + reg;
                if (rowg >= M) continue;
                float v = acc[i][j][reg] + badd;
                if (rowscale) v *= rowscale[rowg];
                Cb[(size_t)rowg * N + colg] = f2b(v);
            }
        }
    }
}

// ================= fused [LN +] fr-GEMM + attention ==========================
// Block = 128 rows (2 seqs), 512 threads / 8 waves (2 row x 4 col).
// HASLN: h = LN(hprev + u[seq]) (per-row, in-kernel), written to hout
//        (ROW0ONLY: only rows with (row&63)==0). Then fr = h @ wr^T via MFMA
//        (full 128x256 bf16 A-tile resident in LDS), then per-(seq,head)
//        softmax over the 64 rows (score is query-independent) and ctx -> hsa.
template<bool HASLN, bool ROW0ONLY>
__global__ __launch_bounds__(512) void attn_layer_kernel(
    const float* __restrict__ hprev, const float* __restrict__ uvec,
    const float* __restrict__ lng, const float* __restrict__ lnb,
    float* __restrict__ hout,
    const u16* __restrict__ wrb, const float* __restrict__ ar,
    float* __restrict__ hsa)
{
    __shared__ u16 ldsA[4 * 128 * 64];   // 64 KB: 4 k-chunks x [128 rows][64 k]
    __shared__ u16 ldsB[256 * 64];       // 32 KB: one k-chunk of wr (256 rows)
    __shared__ float redS[128][4];
    __shared__ float redQ[128][4];
    __shared__ float sPart[2][2][2][64];
    __shared__ float pbuf[2][2][64];

    const int tid = threadIdx.x;
    const int m0 = blockIdx.x * 128;

    // ---------- phase 0: (LN +) convert h tile into swizzled bf16 A-LDS ----
    {
        const int r = tid >> 2, q = tid & 3;   // row 0..127, col-quarter 0..3
        const int grow = m0 + r;
        const int c0 = q * 64;
        const float* hp = hprev + (size_t)grow * 256 + c0;
        float4 y[16];
        if (HASLN) {
            const float* up = uvec + (size_t)(grow >> 6) * 256 + c0;
            float s = 0.f, qq = 0.f;
            #pragma unroll
            for (int v = 0; v < 16; ++v) {
                float4 hv = *(const float4*)(hp + v * 4);
                float4 uv = *(const float4*)(up + v * 4);
                float4 yv = make_float4(hv.x + uv.x, hv.y + uv.y, hv.z + uv.z, hv.w + uv.w);
                y[v] = yv;
                s += yv.x + yv.y + yv.z + yv.w;
                qq += yv.x * yv.x + yv.y * yv.y + yv.z * yv.z + yv.w * yv.w;
            }
            redS[r][q] = s; redQ[r][q] = qq;
            __syncthreads();
            float st = redS[r][0] + redS[r][1] + redS[r][2] + redS[r][3];
            float qt = redQ[r][0] + redQ[r][1] + redQ[r][2] + redQ[r][3];
            float mean = st * (1.f / 256.f);
            float var = qt * (1.f / 256.f) - mean * mean;
            float inv = rsqrtf(var + 1e-5f);
            bool wout = !ROW0ONLY || ((grow & 63) == 0);
            #pragma unroll
            for (int v = 0; v < 16; ++v) {
                float4 gv = *(const float4*)(lng + c0 + v * 4);
                float4 bv = *(const float4*)(lnb + c0 + v * 4);
                float4 yv = y[v];
                yv.x = (yv.x - mean) * inv * gv.x + bv.x;
                yv.y = (yv.y - mean) * inv * gv.y + bv.y;
                yv.z = (yv.z - mean) * inv * gv.z + bv.z;
                yv.w = (yv.w - mean) * inv * gv.w + bv.w;
                y[v] = yv;
                if (wout) *(float4*)(hout + (size_t)grow * 256 + c0 + v * 4) = yv;
            }
        } else {
            #pragma unroll
            for (int v = 0; v < 16; ++v) y[v] = *(const float4*)(hp + v * 4);
        }
        #pragma unroll
        for (int g = 0; g < 8; ++g) {
            float4 a = y[2 * g], b = y[2 * g + 1];
            uint4 pk;
            pk.x = (u32)f2b(a.x) | ((u32)f2b(a.y) << 16);
            pk.y = (u32)f2b(a.z) | ((u32)f2b(a.w) << 16);
            pk.z = (u32)f2b(b.x) | ((u32)f2b(b.y) << 16);
            pk.w = (u32)f2b(b.z) | ((u32)f2b(b.w) << 16);
            *(uint4*)((char*)ldsA + q * 16384 + r * 128 + ((g << 4) ^ ((r & 7) << 4))) = pk;
        }
    }
    __syncthreads();

    // ---------- GEMM: fr = h @ wr^T, accumulators hold the full fr tile ----
    const int wid = tid >> 6, lane = tid & 63;
    const int wr = wid >> 2, wc = wid & 3;   // 2 row-halves x 4 col-quarters
    f32x4 acc[4][4] = {};

    for (int c = 0; c < 4; ++c) {
        #pragma unroll
        for (int s = 0; s < 4; ++s) {
            int gi = tid + s * 512;
            int row_in = gi >> 3, g = gi & 7;
            uint4 v = *(const uint4*)(wrb + (size_t)row_in * 256 + c * 64 + g * 8);
            *(uint4*)((char*)ldsB + row_in * 128 + ((g << 4) ^ ((row_in & 7) << 4))) = v;
        }
        __syncthreads();
        #pragma unroll
        for (int ks = 0; ks < 2; ++ks) {
            const int off = (ks * 64 + ((lane >> 4) << 4)) ^ ((lane & 7) << 4);
            const int ra = lane & 15;
            bf16x8 af[4], bfr[4];
            #pragma unroll
            for (int i = 0; i < 4; ++i)
                af[i] = *(bf16x8*)((char*)ldsA + c * 16384 + (wr * 64 + i * 16 + ra) * 128 + off);
            #pragma unroll
            for (int j = 0; j < 4; ++j)
                bfr[j] = *(bf16x8*)((char*)ldsB + (wc * 64 + j * 16 + ra) * 128 + off);
            #pragma unroll
            for (int i = 0; i < 4; ++i)
                #pragma unroll
                for (int j = 0; j < 4; ++j)
                    acc[i][j] = __builtin_amdgcn_mfma_f32_16x16x32_bf16(af[i], bfr[j], acc[i][j], 0, 0, 0);
        }
        __syncthreads();
    }

    // ---------- attention epilogue (score independent of query row) --------
    // acc[i][j][reg] = fr[row = wr*64 + i*16 + g4*4 + reg][col = wc*64 + j*16 + cl]
    const int g4 = lane >> 4;
    const int cl = lane & 15;
    const int hd = wc >> 1, ch = wc & 1;

    float arj[4];
    #pragma unroll
    for (int j = 0; j < 4; ++j) arj[j] = ar[ch * 64 + j * 16 + cl];

    float sp[4][4];
    #pragma unroll
    for (int i = 0; i < 4; ++i)
        #pragma unroll
        for (int reg = 0; reg < 4; ++reg) {
            float s = 0.f;
            #pragma unroll
            for (int j = 0; j < 4; ++j) {
                float x = acc[i][j][reg];
                s = fmaf(x >= 0.f ? x : 0.01f * x, arj[j], s);
            }
            float v = s;
            v += __shfl_xor(v, 1, 64);
            v += __shfl_xor(v, 2, 64);
            v += __shfl_xor(v, 4, 64);
            v += __shfl_xor(v, 8, 64);
            sp[i][reg] = v;
        }
    if (cl == 0) {
        #pragma unroll
        for (int i = 0; i < 4; ++i)
            #pragma unroll
            for (int reg = 0; reg < 4; ++reg)
                sPart[wr][hd][ch][i * 16 + g4 * 4 + reg] = sp[i][reg];
    }
    __syncthreads();

    {
        float s = sPart[wr][hd][0][lane] + sPart[wr][hd][1][lane];
        float mx = wave_max(s);
        float e = expf(s - mx);
        float sum = wave_sum(e);
        if (ch == 0) pbuf[wr][hd][lane] = e / sum;
    }
    __syncthreads();

    float pv[4][4];
    #pragma unroll
    for (int i = 0; i < 4; ++i)
        #pragma unroll
        for (int reg = 0; reg < 4; ++reg)
            pv[i][reg] = pbuf[wr][hd][i * 16 + g4 * 4 + reg];
    #pragma unroll
    for (int j = 0; j < 4; ++j) {
        float c = 0.f;
        #pragma unroll
        for (int i = 0; i < 4; ++i)
            #pragma unroll
            for (int reg = 0; reg < 4; ++reg)
                c = fmaf(pv[i][reg], acc[i][j][reg], c);
        c += __shfl_xor(c, 16, 64);
        c += __shfl_xor(c, 32, 64);
        if (g4 == 0)
            hsa[(size_t)(blockIdx.x * 2 + wr) * 256 + wc * 64 + j * 16 + cl] = c;
    }
}

// ================= fp32 tiled GEMM (small M) =================
template<bool BT>
__global__ __launch_bounds__(256) void gemm_kernel(
    const float* __restrict__ A, const float* __restrict__ B,
    const float* __restrict__ bias, const float* __restrict__ rowscale,
    float* __restrict__ C,
    int M, int N, int K, int lda, int ldb, int ldc, int coff, int act)
{
    __shared__ float As[32][64 + 4];
    __shared__ float Bs[32][64 + 4];
    const int tid = threadIdx.x;
    const int m0 = blockIdx.y * 64;
    const int n0 = blockIdx.x * 64;
    const int ty = tid >> 4, tx = tid & 15;
    float acc[4][4] = {};
    for (int k0 = 0; k0 < K; k0 += 32) {
        #pragma unroll
        for (int r = 0; r < 2; ++r) {
            int f4 = tid + r * 256;
            int arw = f4 >> 3, af = (f4 & 7) << 2;
            float4 v = make_float4(0.f, 0.f, 0.f, 0.f);
            int grow = m0 + arw;
            if (grow < M) {
                v = *(const float4*)(A + (size_t)grow * lda + k0 + af);
                if (rowscale) { float s = rowscale[grow]; v.x *= s; v.y *= s; v.z *= s; v.w *= s; }
            }
            As[af + 0][arw] = v.x; As[af + 1][arw] = v.y; As[af + 2][arw] = v.z; As[af + 3][arw] = v.w;
        }
        #pragma unroll
        for (int r = 0; r < 2; ++r) {
            int f4 = tid + r * 256;
            int col = f4 >> 3, kf = (f4 & 7) << 2;
            float4 v = make_float4(0.f, 0.f, 0.f, 0.f);
            if (n0 + col < N) v = *(const float4*)(B + (size_t)(n0 + col) * ldb + k0 + kf);
            Bs[kf + 0][col] = v.x; Bs[kf + 1][col] = v.y; Bs[kf + 2][col] = v.z; Bs[kf + 3][col] = v.w;
        }
        __syncthreads();
        #pragma unroll
        for (int kk = 0; kk < 32; ++kk) {
            float4 a4 = *(const float4*)&As[kk][ty << 2];
            float4 b4 = *(const float4*)&Bs[kk][tx << 2];
            float a[4] = {a4.x, a4.y, a4.z, a4.w};
            float b[4] = {b4.x, b4.y, b4.z, b4.w};
            #pragma unroll
            for (int i = 0; i < 4; ++i)
                #pragma unroll
                for (int j = 0; j < 4; ++j)
                    acc[i][j] = fmaf(a[i], b[j], acc[i][j]);
        }
        __syncthreads();
    }
    #pragma unroll
    for (int i = 0; i < 4; ++i) {
        int row = m0 + (ty << 2) + i;
        if (row >= M) continue;
        #pragma unroll
        for (int j = 0; j < 4; ++j) {
            int col = n0 + (tx << 2) + j;
            if (col >= N) continue;
            float v = acc[i][j];
            if (bias) v += bias[col];
            if (act == 1) v = fmaxf(v, 0.f);
            else if (act == 2) v = (v > 0.f) ? v : expm1f(v);
            C[(size_t)row * ldc + coff + col] = v;
        }
    }
}

// ================= converts =================
__global__ __launch_bounds__(256) void conv_flat_kernel(const float* __restrict__ in, u16* __restrict__ out, int n) {
    int i = (blockIdx.x * 256 + threadIdx.x) * 4;
    if (i >= n) return;
    float4 v = *(const float4*)(in + i);
    u32 p0 = (u32)f2b(v.x) | ((u32)f2b(v.y) << 16);
    u32 p1 = (u32)f2b(v.z) | ((u32)f2b(v.w) << 16);
    *(uint2*)(out + i) = make_uint2(p0, p1);
}
__global__ __launch_bounds__(256) void conv_gcnw_kernel(const float* __restrict__ w, u16* __restrict__ out) {
    int idx = blockIdx.x * 256 + threadIdx.x;   // 0..65535
    int l = blockIdx.y;
    int k = idx >> 8, n = idx & 255;
    out[(size_t)l * 65536 + n * 256 + k] = f2b(w[(size_t)l * 65536 + k * 256 + n]);
}

// ================= CSR build =================
#define EDGE_CAP 128
__global__ __launch_bounds__(256) void bucket_fill_kernel(
    const int* __restrict__ src, const int* __restrict__ dst,
    int* __restrict__ ebuf, int* __restrict__ cursor, int* __restrict__ cnt_out, int ne)
{
    int e = blockIdx.x * 256 + threadIdx.x;
    if (e >= ne) return;
    int s = src[e], d = dst[e];
    atomicAdd(&cnt_out[s], 1);
    int pos = atomicAdd(&cursor[d], 1);
    if (pos < EDGE_CAP) ebuf[(size_t)d * EDGE_CAP + pos] = s;
}
__global__ __launch_bounds__(256) void deg_fin_kernel(const int* __restrict__ cnt, float* __restrict__ dinv, int n) {
    int i = blockIdx.x * 256 + threadIdx.x;
    if (i < n) dinv[i] = rsqrtf(fmaxf((float)cnt[i], 1.0f));
}

// ================= CSR aggregate (bf16 in, fp32+bf16 out), 4x unrolled =======
__global__ __launch_bounds__(256) void csr_agg_kernel(
    const u16* __restrict__ x, const int* __restrict__ ebuf,
    const int* __restrict__ deg, float* __restrict__ outf, u16* __restrict__ outb, int nnodes)
{
    int n = blockIdx.x * 4 + (threadIdx.x >> 6);
    if (n >= nnodes) return;
    int lane = threadIdx.x & 63;
    int d = deg[n];
    float dinv = rsqrtf(fmaxf((float)d, 1.0f));
    if (d > EDGE_CAP) d = EDGE_CAP;
    const int* eb = ebuf + (size_t)n * EDGE_CAP;
    const int co = lane << 2;
    float a0 = 0.f, a1 = 0.f, a2 = 0.f, a3 = 0.f;
    int k = 0;
    for (; k + 4 <= d; k += 4) {
        int4 s4 = *(const int4*)(eb + k);
        uint2 va = *(const uint2*)(x + (size_t)s4.x * 256 + co);
        uint2 vb = *(const uint2*)(x + (size_t)s4.y * 256 + co);
        uint2 vc = *(const uint2*)(x + (size_t)s4.z * 256 + co);
        uint2 vd = *(const uint2*)(x + (size_t)s4.w * 256 + co);
        a0 += b2f_lo(va.x) + b2f_lo(vb.x) + b2f_lo(vc.x) + b2f_lo(vd.x);
        a1 += b2f_hi(va.x) + b2f_hi(vb.x) + b2f_hi(vc.x) + b2f_hi(vd.x);
        a2 += b2f_lo(va.y) + b2f_lo(vb.y) + b2f_lo(vc.y) + b2f_lo(vd.y);
        a3 += b2f_hi(va.y) + b2f_hi(vb.y) + b2f_hi(vc.y) + b2f_hi(vd.y);
    }
    for (; k < d; ++k) {
        int s = eb[k];
        uint2 v = *(const uint2*)(x + (size_t)s * 256 + co);
        a0 += b2f_lo(v.x); a1 += b2f_hi(v.x);
        a2 += b2f_lo(v.y); a3 += b2f_hi(v.y);
    }
    a0 = fmaxf(a0 * dinv, 0.f); a1 = fmaxf(a1 * dinv, 0.f);
    a2 = fmaxf(a2 * dinv, 0.f); a3 = fmaxf(a3 * dinv, 0.f);
    *(float4*)(outf + (size_t)n * 256 + co) = make_float4(a0, a1, a2, a3);
    u32 p0 = (u32)f2b(a0) | ((u32)f2b(a1) << 16);
    u32 p1 = (u32)f2b(a2) | ((u32)f2b(a3) << 16);
    *(uint2*)(outb + (size_t)n * 256 + co) = make_uint2(p0, p1);
}

// ================= gather rows (f32 only) =================
__global__ __launch_bounds__(256) void gather_kernel(
    const float* __restrict__ gh, const int* __restrict__ seqs,
    float* __restrict__ h, int nrows)
{
    int idx = blockIdx.x * 256 + threadIdx.x;
    int row = idx >> 6, c4 = (idx & 63) << 2;
    if (row >= nrows) return;
    int node = seqs[row];
    *(float4*)(h + (size_t)row * 256 + c4) = *(const float4*)(gh + (size_t)node * 256 + c4);
}

// ================= final LN at sequence position 0 =================
__global__ __launch_bounds__(256) void ln_row0_kernel(
    const float* __restrict__ h3, const float* __restrict__ u4,
    const float* __restrict__ g, const float* __restrict__ beta,
    float* __restrict__ embT)
{
    int b = blockIdx.x * 4 + (threadIdx.x >> 6);
    int lane = threadIdx.x & 63;
    if (b >= 1024) return;
    float4 hv = *(const float4*)(h3 + (size_t)b * 64 * 256 + (lane << 2));
    float4 uv = *(const float4*)(u4 + (size_t)b * 256 + (lane << 2));
    float y0 = hv.x + uv.x, y1 = hv.y + uv.y, y2 = hv.z + uv.z, y3 = hv.w + uv.w;
    float s = y0 + y1 + y2 + y3;
    float q = y0 * y0 + y1 * y1 + y2 * y2 + y3 * y3;
    s = wave_sum(s); q = wave_sum(q);
    float mean = s * (1.f / 256.f);
    float var = q * (1.f / 256.f) - mean * mean;
    float inv = rsqrtf(var + 1e-5f);
    float4 gv = *(const float4*)(g + (lane << 2));
    float4 bv = *(const float4*)(beta + (lane << 2));
    float4 o;
    o.x = (y0 - mean) * inv * gv.x + bv.x;
    o.y = (y1 - mean) * inv * gv.y + bv.y;
    o.z = (y2 - mean) * inv * gv.z + bv.z;
    o.w = (y3 - mean) * inv * gv.w + bv.w;
    *(float4*)(embT + (size_t)b * 256 + (lane << 2)) = o;
}

// ================= final =================
__global__ __launch_bounds__(256) void final_kernel(
    const float* __restrict__ m2, const float* __restrict__ w3,
    const float* __restrict__ b3, float* __restrict__ out, int nrows)
{
    int row = blockIdx.x * 4 + (threadIdx.x >> 6);
    int lane = threadIdx.x & 63;
    if (row >= nrows) return;
    float s = m2[(size_t)row * 128 + lane] * w3[lane]
            + m2[(size_t)row * 128 + 64 + lane] * w3[64 + lane];
    s = wave_sum(s);
    if (lane == 0) out[row] = 1.f / (1.f + expf(-(s + b3[0])));
}

static inline int cdiv(int a, int b) { return (a + b - 1) / b; }

extern "C" void kernel_launch(void* const* d_in, const int* in_sizes, int n_in,
                              void* d_out, int out_size, void* d_ws, size_t ws_size,
                              hipStream_t stream)
{
    const float* feat0   = (const float*)d_in[0];
    const float* feat1   = (const float*)d_in[1];
    const float* fc_w0   = (const float*)d_in[2];
    const float* fc_b0   = (const float*)d_in[3];
    const float* fc_w1   = (const float*)d_in[4];
    const float* fc_b1   = (const float*)d_in[5];
    const float* gcn_w   = (const float*)d_in[6];
    const int*   edge_src= (const int*)d_in[7];
    const int*   edge_dst= (const int*)d_in[8];
    const int*   dg_seqs = (const int*)d_in[9];
    const int*   pt_seqs = (const int*)d_in[10];
    // 11 type_emb, 12 node_type: dead; 13 gt_wl, 15 gt_al: dead (softmax cancellation)
    const float* gt_wr   = (const float*)d_in[14];
    const float* gt_ar   = (const float*)d_in[16];
    const float* gt_wf   = (const float*)d_in[17];
    const float* ln_g    = (const float*)d_in[18];
    const float* ln_b    = (const float*)d_in[19];
    const float* proj_d_w= (const float*)d_in[20];
    const float* proj_d_b= (const float*)d_in[21];
    const float* proj_p_w= (const float*)d_in[22];
    const float* proj_p_b= (const float*)d_in[23];
    const float* ml_w1   = (const float*)d_in[24];
    const float* ml_b1   = (const float*)d_in[25];
    const float* ml_w2   = (const float*)d_in[26];
    const float* ml_b2   = (const float*)d_in[27];
    const float* ml_w3   = (const float*)d_in[28];
    const float* ml_b3   = (const float*)d_in[29];
    float* out = (float*)d_out;

    // ---- workspace layout (f32 units) ----
    float* base  = (float*)d_ws;
    float* gh    = base;                     // 10,240,000
    float* hA    = gh + 10240000;            // 16,777,216
    float* hB    = hA + 16777216;            // 16,777,216
    float* dego  = hB + 16777216;            // 40,000
    float* hsa   = dego + 40000;             // 262,144
    float* u     = hsa + 262144;             // 262,144
    float* embT  = u + 262144;               // 262,144
    float* t1    = embT + 262144;            // 262,144
    float* mx    = t1 + 262144;              // 524,288
    float* m1    = mx + 524288;              // 262,144
    float* m2    = m1 + 262144;              // 131,072
    float* wbR   = m2 + 131072;              // bf16 weights region

    // GCN-phase aliases inside hA (dead before gather writes hA)
    u16* tmp_b   = (u16*)hA;                          // 10,240,000 bf16
    int* ebuf    = (int*)(hA + 5120000);              // 5,120,000 int
    int* cursor  = ebuf + (size_t)40000 * EDGE_CAP;   // 40,000
    int* cnt_out = cursor + 40000;                    // 40,000
    u16* gh_b    = (u16*)(hA + 10320000);             // 10,240,000 bf16

    u16* wr_b    = (u16*)wbR;                // 524,288 bf16
    u16* fcw_b   = wr_b + 524288;            // 262,144 bf16
    u16* gcnw_b  = fcw_b + 262144;           // 131,072 bf16 (transposed)

    // ---- weight converts ----
    conv_flat_kernel<<<cdiv(524288 / 4, 256), 256, 0, stream>>>(gt_wr, wr_b, 524288);
    conv_flat_kernel<<<cdiv(131072 / 4, 256), 256, 0, stream>>>(fc_w0, fcw_b, 131072);
    conv_flat_kernel<<<cdiv(131072 / 4, 256), 256, 0, stream>>>(fc_w1, fcw_b + 131072, 131072);
    conv_gcnw_kernel<<<dim3(256, 2), 256, 0, stream>>>(gcn_w, gcnw_b);

    // ---- FC projections (fp32 A converted in staging) -> gh_b ----
    mfma_gemm_kernel<true><<<dim3(2, cdiv(20000, 128)), 512, 0, stream>>>(
        feat0, fcw_b, fc_b0, nullptr, gh_b, 20000, 256, 512);
    mfma_gemm_kernel<true><<<dim3(2, cdiv(20000, 128)), 512, 0, stream>>>(
        feat1, fcw_b + 131072, fc_b1, nullptr, gh_b + (size_t)20000 * 256, 20000, 256, 512);

    // ---- CSR build (once) ----
    hipMemsetAsync(cursor, 0, 80000 * sizeof(int), stream);
    bucket_fill_kernel<<<2500, 256, 0, stream>>>(edge_src, edge_dst, ebuf, cursor, cnt_out, 640000);
    deg_fin_kernel<<<cdiv(40000, 256), 256, 0, stream>>>(cnt_out, dego, 40000);

    // ---- 2x GCN ----
    for (int l = 0; l < 2; ++l) {
        mfma_gemm_kernel<false><<<dim3(2, cdiv(40000, 128)), 512, 0, stream>>>(
            gh_b, gcnw_b + (size_t)l * 65536, nullptr, dego, tmp_b, 40000, 256, 256);
        csr_agg_kernel<<<10000, 256, 0, stream>>>(tmp_b, ebuf, cursor, gh, gh_b, 40000);
    }

    // ---- graph transformer per node type (LN folded into next layer) ----
    const int* seqs[2] = {dg_seqs, pt_seqs};
    const float* pw[2] = {proj_d_w, proj_p_w};
    const float* pb[2] = {proj_d_b, proj_p_b};
    for (int t = 0; t < 2; ++t) {
        int i = t * 4;
        gather_kernel<<<16384, 256, 0, stream>>>(gh, seqs[t], hA, 65536);
        // layer 1: no LN
        attn_layer_kernel<false, false><<<512, 512, 0, stream>>>(
            hA, nullptr, nullptr, nullptr, nullptr,
            wr_b + (size_t)i * 65536, gt_ar + (size_t)i * 128, hsa);
        gemm_kernel<true><<<dim3(4, 16), 256, 0, stream>>>(
            hsa, gt_wf + (size_t)i * 65536, nullptr, nullptr, u, 1024, 256, 256, 256, 256, 256, 0, 0);
        // layer 2: h1 = LN_0(h0+u1) in-kernel -> hB
        attn_layer_kernel<true, false><<<512, 512, 0, stream>>>(
            hA, u, ln_g + (size_t)i * 256, ln_b + (size_t)i * 256, hB,
            wr_b + (size_t)(i + 1) * 65536, gt_ar + (size_t)(i + 1) * 128, hsa);
        gemm_kernel<true><<<dim3(4, 16), 256, 0, stream>>>(
            hsa, gt_wf + (size_t)(i + 1) * 65536, nullptr, nullptr, u, 1024, 256, 256, 256, 256, 256, 0, 0);
        // layer 3: h2 = LN_1(h1+u2) -> hA
        attn_layer_kernel<true, false><<<512, 512, 0, stream>>>(
            hB, u, ln_g + (size_t)(i + 1) * 256, ln_b + (size_t)(i + 1) * 256, hA,
            wr_b + (size_t)(i + 2) * 65536, gt_ar + (size_t)(i + 2) * 128, hsa);
        gemm_kernel<true><<<dim3(4, 16), 256, 0, stream>>>(
            hsa, gt_wf + (size_t)(i + 2) * 65536, nullptr, nullptr, u, 1024, 256, 256, 256, 256, 256, 0, 0);
        // layer 4: h3 = LN_2(h2+u3) -> hB (row0 only)
        attn_layer_kernel<true, true><<<512, 512, 0, stream>>>(
            hA, u, ln_g + (size_t)(i + 2) * 256, ln_b + (size_t)(i + 2) * 256, hB,
            wr_b + (size_t)(i + 3) * 65536, gt_ar + (size_t)(i + 3) * 128, hsa);
        gemm_kernel<true><<<dim3(4, 16), 256, 0, stream>>>(
            hsa, gt_wf + (size_t)(i + 3) * 65536, nullptr, nullptr, u, 1024, 256, 256, 256, 256, 256, 0, 0);
        // final LN at position 0 -> embT, then proj head
        ln_row0_kernel<<<256, 256, 0, stream>>>(
            hB, u, ln_g + (size_t)(i + 3) * 256, ln_b + (size_t)(i + 3) * 256, embT);
        gemm_kernel<true><<<dim3(4, 16), 256, 0, stream>>>(
            embT, pw[t], pb[t], nullptr, t1, 1024, 256, 256, 256, 256, 256, 0, 2);
        gemm_kernel<true><<<dim3(4, 16), 256, 0, stream>>>(
            t1, pw[t] + 65536, pb[t] + 256, nullptr, mx, 1024, 256, 256, 256, 256, 512, t * 256, 0);
    }

    // ---- predict MLP ----
    gemm_kernel<true><<<dim3(4, 16), 256, 0, stream>>>(
        mx, ml_w1, ml_b1, nullptr, m1, 1024, 256, 512, 512, 512, 256, 0, 1);
    gemm_kernel<true><<<dim3(2, 16), 256, 0, stream>>>(
        m1, ml_w2, ml_b2, nullptr, m2, 1024, 128, 256, 256, 256, 128, 0, 1);
    final_kernel<<<256, 256, 0, stream>>>(m2, ml_w3, ml_b3, out, 1024);
}

// Round 6
// 949.292 us; speedup vs baseline: 6.8301x; 1.1679x over previous
//
#include <hip/hip_runtime.h>
#include <hip/hip_bf16.h>
#include <math.h>

typedef unsigned int u32;
typedef unsigned short u16;
typedef __attribute__((ext_vector_type(8))) short bf16x8;
typedef __attribute__((ext_vector_type(4))) float f32x4;

__device__ __forceinline__ float b2f(u16 u) { union { u32 i; float f; } c; c.i = ((u32)u) << 16; return c.f; }
__device__ __forceinline__ u16 f2b(float f) { __hip_bfloat16 h = __float2bfloat16(f); u16 r; __builtin_memcpy(&r, &h, 2); return r; }
__device__ __forceinline__ float b2f_lo(u32 w) { union { u32 i; float f; } c; c.i = w << 16; return c.f; }
__device__ __forceinline__ float b2f_hi(u32 w) { union { u32 i; float f; } c; c.i = w & 0xffff0000u; return c.f; }
__device__ __forceinline__ u32 pk2(float a, float b) { return (u32)f2b(a) | ((u32)f2b(b) << 16); }

__device__ __forceinline__ float wave_sum(float v) {
    #pragma unroll
    for (int off = 32; off > 0; off >>= 1) v += __shfl_xor(v, off, 64);
    return v;
}
__device__ __forceinline__ float wave_max(float v) {
    #pragma unroll
    for (int off = 32; off > 0; off >>= 1) v = fmaxf(v, __shfl_xor(v, off, 64));
    return v;
}

// ================= generic bf16 MFMA GEMM (128x128 tile, 8 waves of 32x64) ====
// C[M,N] = (A[M,K] @ B[N,K]^T) (+bias[col]) (*rowscale[row]) -> bf16 out
// blockIdx.z==1 switches to the alternate pointer set (merged dual GEMM).
template<bool AF32>
__global__ __launch_bounds__(512) void mfma_gemm_kernel(
    const void* __restrict__ Av, const u16* __restrict__ B,
    const float* __restrict__ bias, const float* __restrict__ rowscale,
    u16* __restrict__ Cb, int M, int N, int K,
    const void* __restrict__ Av1, const u16* __restrict__ B1,
    const float* __restrict__ bias1, u16* __restrict__ Cb1)
{
    if (blockIdx.z) { Av = Av1; B = B1; bias = bias1; Cb = Cb1; }
    __shared__ u16 lds[2 * 128 * 64];   // A bytes [0,16384), B bytes [16384,32768)
    const int tid = threadIdx.x;
    const int wid = tid >> 6, lane = tid & 63;
    const int wr = wid >> 1, wc = wid & 1;   // 4 row-strips x 2 col-strips
    const int m0 = blockIdx.y * 128, n0 = blockIdx.x * 128;

    f32x4 acc[2][4] = {};

    const int rsub = lane >> 3;              // 0..7
    const int cbyte = (lane & 7) << 4;       // 0..112
    const int swz_st = cbyte ^ (rsub << 4);

    for (int k0 = 0; k0 < K; k0 += 64) {
        #pragma unroll
        for (int cc = 0; cc < 4; ++cc) {
            int c = wid * 4 + cc;                  // 0..31
            int buf = c >> 4;                      // 0=A, 1=B
            int row_in = ((c & 15) << 3) + rsub;   // 0..127
            int lim = buf ? N : M;
            int row_g = (buf ? n0 : m0) + row_in;
            if (row_g >= lim) row_g = lim - 1;
            if (buf == 0 && AF32) {
                const float* src = (const float*)Av + (size_t)row_g * K + k0 + (cbyte >> 1);
                float4 v0 = *(const float4*)src;
                float4 v1 = *(const float4*)(src + 4);
                uint4 pk;
                pk.x = pk2(v0.x, v0.y); pk.y = pk2(v0.z, v0.w);
                pk.z = pk2(v1.x, v1.y); pk.w = pk2(v1.z, v1.w);
                *(uint4*)((char*)lds + row_in * 128 + swz_st) = pk;
            } else {
                const u16* srcb = (buf ? B : (const u16*)Av) + (size_t)row_g * K + k0 + (cbyte >> 1);
                f32x4 v = *(const f32x4*)srcb;
                *(f32x4*)((char*)lds + buf * 16384 + row_in * 128 + swz_st) = v;
            }
        }
        __syncthreads();
        #pragma unroll
        for (int ks = 0; ks < 2; ++ks) {
            const int off = (ks * 64 + ((lane >> 4) << 4)) ^ ((lane & 7) << 4);
            const int ra = lane & 15;
            bf16x8 af[2], bfr[4];
            #pragma unroll
            for (int i = 0; i < 2; ++i)
                af[i] = *(bf16x8*)((char*)lds + (wr * 32 + i * 16 + ra) * 128 + off);
            #pragma unroll
            for (int j = 0; j < 4; ++j)
                bfr[j] = *(bf16x8*)((char*)lds + 16384 + (wc * 64 + j * 16 + ra) * 128 + off);
            #pragma unroll
            for (int i = 0; i < 2; ++i)
                #pragma unroll
                for (int j = 0; j < 4; ++j)
                    acc[i][j] = __builtin_amdgcn_mfma_f32_16x16x32_bf16(af[i], bfr[j], acc[i][j], 0, 0, 0);
        }
        __syncthreads();
    }

    const int cr = lane >> 4, ccol = lane & 15;
    #pragma unroll
    for (int i = 0; i < 2; ++i) {
        #pragma unroll
        for (int j = 0; j < 4; ++j) {
            int colg = n0 + wc * 64 + j * 16 + ccol;
            if (colg >= N) continue;
            float badd = bias ? bias[colg] : 0.f;
            #pragma unroll
            for (int reg = 0; reg < 4; ++reg) {
                int rowg = m0 + wr * 32 + i * 16 + cr * 4 + reg;
                if (rowg >= M) continue;
                float v = acc[i][j][reg] + badd;
                if (rowscale) v *= rowscale[rowg];
                Cb[(size_t)rowg * N + colg] = f2b(v);
            }
        }
    }
}

// ================= mega-fused 4-layer graph transformer ======================
// Block = 1 sequence (64 rows), 256 threads / 4 waves. Residual h in registers
// (thread t: row r=t>>2, col-quarter q=t&3, y[16] float4). Per layer:
//   pack y -> bf16 swizzled LDS A (32KB); fr = h @ wr^T via MFMA with B-frags
//   loaded coalesced from frag-major wrN (global, L2-resident); additive-attn
//   softmax over the 64 rows (query-independent) -> ctx[256]; u = ctx @ wf^T
//   from packed-pair wfT2; h = LN(h + u). Layer 4: LN row 0 only -> embT.
__global__ __launch_bounds__(256) void fused_transformer_kernel(
    const float* __restrict__ gh, const int* __restrict__ seqs,
    const u16* __restrict__ wrN,   // [4][16 gn][8 kc][64 lane][8] bf16
    const u32* __restrict__ wfT2,  // [4][128 d2][256 n] packed bf16 pairs
    const float* __restrict__ ar,  // [4][128]
    const float* __restrict__ lng, const float* __restrict__ lnb,  // [4][256]
    float* __restrict__ embT)      // [1024,256]
{
    __shared__ u16 ldsA[64 * 256];       // 32KB: [c:4][row:64][128B swizzled]
    __shared__ float sPart[2][2][64];    // [head][col-half][row]
    __shared__ float pbuf[2][64];
    __shared__ float ctxS[256];
    __shared__ float uS[256];

    const int tid = threadIdx.x;
    const int s = blockIdx.x;
    const int r = tid >> 2, q = tid & 3;
    const int wid = tid >> 6, lane = tid & 63;
    const int hd = wid >> 1, ch = wid & 1;
    const int g4 = lane >> 4, cl = lane & 15;

    // ---- gather h0 rows from gh ----
    float4 y[16];
    {
        int node = seqs[s * 64 + r];
        const float* src = gh + (size_t)node * 256 + q * 64;
        #pragma unroll
        for (int v = 0; v < 16; ++v) y[v] = *(const float4*)(src + v * 4);
    }

    for (int l = 0; l < 4; ++l) {
        // ---- pack y -> swizzled bf16 A-LDS ----
        #pragma unroll
        for (int g = 0; g < 8; ++g) {
            float4 a = y[2 * g], b = y[2 * g + 1];
            uint4 pk;
            pk.x = pk2(a.x, a.y); pk.y = pk2(a.z, a.w);
            pk.z = pk2(b.x, b.y); pk.w = pk2(b.z, b.w);
            *(uint4*)((char*)ldsA + q * 8192 + r * 128 + ((g << 4) ^ ((r & 7) << 4))) = pk;
        }
        __syncthreads();

        // ---- fr = h @ wr^T : wave wid owns cols wid*64..+63, all 64 rows ----
        f32x4 acc[4][4] = {};
        {
            const u16* wrl = wrN + (size_t)l * 65536;
            const int ra = lane & 15;
            #pragma unroll
            for (int kc = 0; kc < 8; ++kc) {
                const int c = kc >> 1, ks = kc & 1;
                const int off = (ks * 64 + ((lane >> 4) << 4)) ^ ((lane & 7) << 4);
                bf16x8 af[4], bfr[4];
                #pragma unroll
                for (int i = 0; i < 4; ++i)
                    af[i] = *(bf16x8*)((char*)ldsA + c * 8192 + (i * 16 + ra) * 128 + off);
                #pragma unroll
                for (int j = 0; j < 4; ++j)
                    bfr[j] = *(const bf16x8*)(wrl + ((size_t)((wid * 4 + j) * 8 + kc) << 9) + lane * 8);
                #pragma unroll
                for (int i = 0; i < 4; ++i)
                    #pragma unroll
                    for (int j = 0; j < 4; ++j)
                        acc[i][j] = __builtin_amdgcn_mfma_f32_16x16x32_bf16(af[i], bfr[j], acc[i][j], 0, 0, 0);
            }
        }

        // ---- attention (score independent of query row) ----
        // acc[i][j][reg] = fr[row=i*16+g4*4+reg][col=wid*64+j*16+cl]
        {
            const float* arl = ar + l * 128;
            float arj[4];
            #pragma unroll
            for (int j = 0; j < 4; ++j) arj[j] = arl[ch * 64 + j * 16 + cl];
            #pragma unroll
            for (int i = 0; i < 4; ++i)
                #pragma unroll
                for (int reg = 0; reg < 4; ++reg) {
                    float sc = 0.f;
                    #pragma unroll
                    for (int j = 0; j < 4; ++j) {
                        float x = acc[i][j][reg];
                        sc = fmaf(x >= 0.f ? x : 0.01f * x, arj[j], sc);
                    }
                    sc += __shfl_xor(sc, 1, 64);
                    sc += __shfl_xor(sc, 2, 64);
                    sc += __shfl_xor(sc, 4, 64);
                    sc += __shfl_xor(sc, 8, 64);
                    if (cl == 0) sPart[hd][ch][i * 16 + g4 * 4 + reg] = sc;
                }
        }
        __syncthreads();
        {
            float sv = sPart[hd][0][lane] + sPart[hd][1][lane];
            float mx = wave_max(sv);
            float e = expf(sv - mx);
            float sm = wave_sum(e);
            if (ch == 0) pbuf[hd][lane] = e / sm;
        }
        __syncthreads();
        {
            float pv[4][4];
            #pragma unroll
            for (int i = 0; i < 4; ++i)
                #pragma unroll
                for (int reg = 0; reg < 4; ++reg)
                    pv[i][reg] = pbuf[hd][i * 16 + g4 * 4 + reg];
            #pragma unroll
            for (int j = 0; j < 4; ++j) {
                float c = 0.f;
                #pragma unroll
                for (int i = 0; i < 4; ++i)
                    #pragma unroll
                    for (int reg = 0; reg < 4; ++reg)
                        c = fmaf(pv[i][reg], acc[i][j][reg], c);
                c += __shfl_xor(c, 16, 64);
                c += __shfl_xor(c, 32, 64);
                if (g4 == 0) ctxS[wid * 64 + j * 16 + cl] = c;
            }
        }
        __syncthreads();

        // ---- u[n] = sum_d ctx[d] * wf[n][d] (packed-pair bf16, coalesced) ----
        {
            const u32* wp = wfT2 + (size_t)l * 32768 + tid;
            float ua = 0.f;
            #pragma unroll 8
            for (int d2 = 0; d2 < 128; ++d2) {
                u32 w2 = wp[(size_t)d2 * 256];
                ua = fmaf(ctxS[2 * d2], b2f_lo(w2), ua);
                ua = fmaf(ctxS[2 * d2 + 1], b2f_hi(w2), ua);
            }
            uS[tid] = ua;
        }
        __syncthreads();

        // ---- h = LN(h + u) ----
        {
            #pragma unroll
            for (int v = 0; v < 16; ++v) {
                float4 uv = *(const float4*)&uS[q * 64 + v * 4];
                y[v].x += uv.x; y[v].y += uv.y; y[v].z += uv.z; y[v].w += uv.w;
            }
            float sm = 0.f, qq = 0.f;
            #pragma unroll
            for (int v = 0; v < 16; ++v) {
                sm += y[v].x + y[v].y + y[v].z + y[v].w;
                qq += y[v].x * y[v].x + y[v].y * y[v].y + y[v].z * y[v].z + y[v].w * y[v].w;
            }
            sm += __shfl_xor(sm, 1, 64); sm += __shfl_xor(sm, 2, 64);
            qq += __shfl_xor(qq, 1, 64); qq += __shfl_xor(qq, 2, 64);
            float mean = sm * (1.f / 256.f);
            float var = qq * (1.f / 256.f) - mean * mean;
            float inv = rsqrtf(var + 1e-5f);
            const float* gl = lng + l * 256 + q * 64;
            const float* bl = lnb + l * 256 + q * 64;
            if (l < 3) {
                #pragma unroll
                for (int v = 0; v < 16; ++v) {
                    float4 gv = *(const float4*)(gl + v * 4);
                    float4 bv = *(const float4*)(bl + v * 4);
                    y[v].x = (y[v].x - mean) * inv * gv.x + bv.x;
                    y[v].y = (y[v].y - mean) * inv * gv.y + bv.y;
                    y[v].z = (y[v].z - mean) * inv * gv.z + bv.z;
                    y[v].w = (y[v].w - mean) * inv * gv.w + bv.w;
                }
            } else if (r == 0) {
                #pragma unroll
                for (int v = 0; v < 16; ++v) {
                    float4 gv = *(const float4*)(gl + v * 4);
                    float4 bv = *(const float4*)(bl + v * 4);
                    float4 o;
                    o.x = (y[v].x - mean) * inv * gv.x + bv.x;
                    o.y = (y[v].y - mean) * inv * gv.y + bv.y;
                    o.z = (y[v].z - mean) * inv * gv.z + bv.z;
                    o.w = (y[v].w - mean) * inv * gv.w + bv.w;
                    *(float4*)(embT + (size_t)s * 256 + q * 64 + v * 4) = o;
                }
            }
        }
        __syncthreads();
    }
}

// ================= fp32 tiled GEMM (small M) =================
template<bool BT>
__global__ __launch_bounds__(256) void gemm_kernel(
    const float* __restrict__ A, const float* __restrict__ B,
    const float* __restrict__ bias, const float* __restrict__ rowscale,
    float* __restrict__ C,
    int M, int N, int K, int lda, int ldb, int ldc, int coff, int act)
{
    __shared__ float As[32][64 + 4];
    __shared__ float Bs[32][64 + 4];
    const int tid = threadIdx.x;
    const int m0 = blockIdx.y * 64;
    const int n0 = blockIdx.x * 64;
    const int ty = tid >> 4, tx = tid & 15;
    float acc[4][4] = {};
    for (int k0 = 0; k0 < K; k0 += 32) {
        #pragma unroll
        for (int r = 0; r < 2; ++r) {
            int f4 = tid + r * 256;
            int arw = f4 >> 3, af = (f4 & 7) << 2;
            float4 v = make_float4(0.f, 0.f, 0.f, 0.f);
            int grow = m0 + arw;
            if (grow < M) {
                v = *(const float4*)(A + (size_t)grow * lda + k0 + af);
                if (rowscale) { float s = rowscale[grow]; v.x *= s; v.y *= s; v.z *= s; v.w *= s; }
            }
            As[af + 0][arw] = v.x; As[af + 1][arw] = v.y; As[af + 2][arw] = v.z; As[af + 3][arw] = v.w;
        }
        #pragma unroll
        for (int r = 0; r < 2; ++r) {
            int f4 = tid + r * 256;
            int col = f4 >> 3, kf = (f4 & 7) << 2;
            float4 v = make_float4(0.f, 0.f, 0.f, 0.f);
            if (n0 + col < N) v = *(const float4*)(B + (size_t)(n0 + col) * ldb + k0 + kf);
            Bs[kf + 0][col] = v.x; Bs[kf + 1][col] = v.y; Bs[kf + 2][col] = v.z; Bs[kf + 3][col] = v.w;
        }
        __syncthreads();
        #pragma unroll
        for (int kk = 0; kk < 32; ++kk) {
            float4 a4 = *(const float4*)&As[kk][ty << 2];
            float4 b4 = *(const float4*)&Bs[kk][tx << 2];
            float a[4] = {a4.x, a4.y, a4.z, a4.w};
            float b[4] = {b4.x, b4.y, b4.z, b4.w};
            #pragma unroll
            for (int i = 0; i < 4; ++i)
                #pragma unroll
                for (int j = 0; j < 4; ++j)
                    acc[i][j] = fmaf(a[i], b[j], acc[i][j]);
        }
        __syncthreads();
    }
    #pragma unroll
    for (int i = 0; i < 4; ++i) {
        int row = m0 + (ty << 2) + i;
        if (row >= M) continue;
        #pragma unroll
        for (int j = 0; j < 4; ++j) {
            int col = n0 + (tx << 2) + j;
            if (col >= N) continue;
            float v = acc[i][j];
            if (bias) v += bias[col];
            if (act == 1) v = fmaxf(v, 0.f);
            else if (act == 2) v = (v > 0.f) ? v : expm1f(v);
            C[(size_t)row * ldc + coff + col] = v;
        }
    }
}

// ================= converts =================
__global__ __launch_bounds__(256) void conv_flat_kernel(const float* __restrict__ in, u16* __restrict__ out, int n) {
    int i = (blockIdx.x * 256 + threadIdx.x) * 4;
    if (i >= n) return;
    float4 v = *(const float4*)(in + i);
    *(uint2*)(out + i) = make_uint2(pk2(v.x, v.y), pk2(v.z, v.w));
}
__global__ __launch_bounds__(256) void conv_gcnw_kernel(const float* __restrict__ w, u16* __restrict__ out) {
    int idx = blockIdx.x * 256 + threadIdx.x;   // 0..65535
    int l = blockIdx.y;
    int k = idx >> 8, n = idx & 255;
    out[(size_t)l * 65536 + n * 256 + k] = f2b(w[(size_t)l * 65536 + k * 256 + n]);
}
// gt_wr [8][256 n][256 k] -> frag-major wrN: [(l*16+gn)*8+kc] frags of 64 lanes x 16B
__global__ __launch_bounds__(256) void conv_wrN_kernel(const float* __restrict__ w, u16* __restrict__ out) {
    int idx = blockIdx.x * 256 + threadIdx.x;    // 0..65535
    int lane = idx & 63;
    int kc = (idx >> 6) & 7;
    int gn = (idx >> 9) & 15;
    int l = idx >> 13;
    int row = gn * 16 + (lane & 15);
    int k0 = kc * 32 + (lane >> 4) * 8;
    const float* src = w + ((size_t)l * 256 + row) * 256 + k0;
    float4 v0 = *(const float4*)src;
    float4 v1 = *(const float4*)(src + 4);
    uint4 pk;
    pk.x = pk2(v0.x, v0.y); pk.y = pk2(v0.z, v0.w);
    pk.z = pk2(v1.x, v1.y); pk.w = pk2(v1.z, v1.w);
    *(uint4*)(out + (size_t)idx * 8) = pk;
}
// gt_wf [8][256 n][256 d] -> wfT2 u32 [8][128 d2][256 n] = pack(wf[n][2d2], wf[n][2d2+1])
__global__ __launch_bounds__(256) void conv_wfT2_kernel(const float* __restrict__ w, u32* __restrict__ out) {
    int idx = blockIdx.x * 256 + threadIdx.x;    // 0..262143
    int n = idx & 255;
    int d2 = (idx >> 8) & 127;
    int l = idx >> 15;
    const float* src = w + ((size_t)l * 256 + n) * 256 + 2 * d2;
    out[idx] = pk2(src[0], src[1]);
}

// ================= CSR build =================
#define EDGE_CAP 128
__global__ __launch_bounds__(256) void bucket_fill_kernel(
    const int* __restrict__ src, const int* __restrict__ dst,
    int* __restrict__ ebuf, int* __restrict__ cursor, int* __restrict__ cnt_out, int ne)
{
    int e = blockIdx.x * 256 + threadIdx.x;
    if (e >= ne) return;
    int s = src[e], d = dst[e];
    atomicAdd(&cnt_out[s], 1);
    int pos = atomicAdd(&cursor[d], 1);
    if (pos < EDGE_CAP) ebuf[(size_t)d * EDGE_CAP + pos] = s;
}
__global__ __launch_bounds__(256) void deg_fin_kernel(const int* __restrict__ cnt, float* __restrict__ dinv, int n) {
    int i = blockIdx.x * 256 + threadIdx.x;
    if (i < n) dinv[i] = rsqrtf(fmaxf((float)cnt[i], 1.0f));
}

// ================= CSR aggregate (bf16 in, fp32+bf16 out), 4x unrolled =======
__global__ __launch_bounds__(256) void csr_agg_kernel(
    const u16* __restrict__ x, const int* __restrict__ ebuf,
    const int* __restrict__ deg, float* __restrict__ outf, u16* __restrict__ outb, int nnodes)
{
    int n = blockIdx.x * 4 + (threadIdx.x >> 6);
    if (n >= nnodes) return;
    int lane = threadIdx.x & 63;
    int d = deg[n];
    float dinv = rsqrtf(fmaxf((float)d, 1.0f));
    if (d > EDGE_CAP) d = EDGE_CAP;
    const int* eb = ebuf + (size_t)n * EDGE_CAP;
    const int co = lane << 2;
    float a0 = 0.f, a1 = 0.f, a2 = 0.f, a3 = 0.f;
    int k = 0;
    for (; k + 4 <= d; k += 4) {
        int4 s4 = *(const int4*)(eb + k);
        uint2 va = *(const uint2*)(x + (size_t)s4.x * 256 + co);
        uint2 vb = *(const uint2*)(x + (size_t)s4.y * 256 + co);
        uint2 vc = *(const uint2*)(x + (size_t)s4.z * 256 + co);
        uint2 vd = *(const uint2*)(x + (size_t)s4.w * 256 + co);
        a0 += b2f_lo(va.x) + b2f_lo(vb.x) + b2f_lo(vc.x) + b2f_lo(vd.x);
        a1 += b2f_hi(va.x) + b2f_hi(vb.x) + b2f_hi(vc.x) + b2f_hi(vd.x);
        a2 += b2f_lo(va.y) + b2f_lo(vb.y) + b2f_lo(vc.y) + b2f_lo(vd.y);
        a3 += b2f_hi(va.y) + b2f_hi(vb.y) + b2f_hi(vc.y) + b2f_hi(vd.y);
    }
    for (; k < d; ++k) {
        int s = eb[k];
        uint2 v = *(const uint2*)(x + (size_t)s * 256 + co);
        a0 += b2f_lo(v.x); a1 += b2f_hi(v.x);
        a2 += b2f_lo(v.y); a3 += b2f_hi(v.y);
    }
    a0 = fmaxf(a0 * dinv, 0.f); a1 = fmaxf(a1 * dinv, 0.f);
    a2 = fmaxf(a2 * dinv, 0.f); a3 = fmaxf(a3 * dinv, 0.f);
    *(float4*)(outf + (size_t)n * 256 + co) = make_float4(a0, a1, a2, a3);
    *(uint2*)(outb + (size_t)n * 256 + co) = make_uint2(pk2(a0, a1), pk2(a2, a3));
}

// ================= final =================
__global__ __launch_bounds__(256) void final_kernel(
    const float* __restrict__ m2, const float* __restrict__ w3,
    const float* __restrict__ b3, float* __restrict__ out, int nrows)
{
    int row = blockIdx.x * 4 + (threadIdx.x >> 6);
    int lane = threadIdx.x & 63;
    if (row >= nrows) return;
    float s = m2[(size_t)row * 128 + lane] * w3[lane]
            + m2[(size_t)row * 128 + 64 + lane] * w3[64 + lane];
    s = wave_sum(s);
    if (lane == 0) out[row] = 1.f / (1.f + expf(-(s + b3[0])));
}

static inline int cdiv(int a, int b) { return (a + b - 1) / b; }

extern "C" void kernel_launch(void* const* d_in, const int* in_sizes, int n_in,
                              void* d_out, int out_size, void* d_ws, size_t ws_size,
                              hipStream_t stream)
{
    const float* feat0   = (const float*)d_in[0];
    const float* feat1   = (const float*)d_in[1];
    const float* fc_w0   = (const float*)d_in[2];
    const float* fc_b0   = (const float*)d_in[3];
    const float* fc_w1   = (const float*)d_in[4];
    const float* fc_b1   = (const float*)d_in[5];
    const float* gcn_w   = (const float*)d_in[6];
    const int*   edge_src= (const int*)d_in[7];
    const int*   edge_dst= (const int*)d_in[8];
    const int*   dg_seqs = (const int*)d_in[9];
    const int*   pt_seqs = (const int*)d_in[10];
    // 11 type_emb, 12 node_type: dead; 13 gt_wl, 15 gt_al: dead (softmax cancellation)
    const float* gt_wr   = (const float*)d_in[14];
    const float* gt_ar   = (const float*)d_in[16];
    const float* gt_wf   = (const float*)d_in[17];
    const float* ln_g    = (const float*)d_in[18];
    const float* ln_b    = (const float*)d_in[19];
    const float* proj_d_w= (const float*)d_in[20];
    const float* proj_d_b= (const float*)d_in[21];
    const float* proj_p_w= (const float*)d_in[22];
    const float* proj_p_b= (const float*)d_in[23];
    const float* ml_w1   = (const float*)d_in[24];
    const float* ml_b1   = (const float*)d_in[25];
    const float* ml_w2   = (const float*)d_in[26];
    const float* ml_b2   = (const float*)d_in[27];
    const float* ml_w3   = (const float*)d_in[28];
    const float* ml_b3   = (const float*)d_in[29];
    float* out = (float*)d_out;

    // ---- workspace layout (f32 units) ----
    float* base  = (float*)d_ws;
    float* gh    = base;                      // 10,240,000
    float* gcnR  = gh + 10240000;             // GCN-phase region (15,440,000)
    float* dego  = gcnR + 15440000;           // 40,000
    float* embT  = dego + 40000;              // 262,144
    float* t1    = embT + 262144;             // 262,144
    float* mx    = t1 + 262144;               // 524,288
    float* m1    = mx + 524288;               // 262,144
    float* m2    = m1 + 262144;               // 131,072
    float* wreg  = m2 + 131072;               // converted weights

    u16* tmp_b   = (u16*)gcnR;                        // 10,240,000 bf16
    int* ebuf    = (int*)(gcnR + 5120000);            // 5,120,000 int
    int* cursor  = ebuf + (size_t)40000 * EDGE_CAP;   // 40,000
    int* cnt_out = cursor + 40000;                    // 40,000
    u16* gh_b    = (u16*)(gcnR + 10320000);           // 10,240,000 bf16

    u16* fcw_b   = (u16*)wreg;                // 262,144 u16
    u16* gcnw_b  = fcw_b + 262144;            // 131,072 u16
    u16* wrN     = gcnw_b + 131072;           // 524,288 u16 (8 layers x 65,536)
    u32* wfT2    = (u32*)(wrN + 524288);      // 262,144 u32 (8 layers x 32,768)

    // ---- weight converts ----
    conv_flat_kernel<<<cdiv(131072 / 4, 256), 256, 0, stream>>>(fc_w0, fcw_b, 131072);
    conv_flat_kernel<<<cdiv(131072 / 4, 256), 256, 0, stream>>>(fc_w1, fcw_b + 131072, 131072);
    conv_gcnw_kernel<<<dim3(256, 2), 256, 0, stream>>>(gcn_w, gcnw_b);
    conv_wrN_kernel<<<256, 256, 0, stream>>>(gt_wr, wrN);
    conv_wfT2_kernel<<<1024, 256, 0, stream>>>(gt_wf, wfT2);

    // ---- FC projections (merged dual GEMM via blockIdx.z) -> gh_b ----
    mfma_gemm_kernel<true><<<dim3(2, cdiv(20000, 128), 2), 512, 0, stream>>>(
        feat0, fcw_b, fc_b0, nullptr, gh_b, 20000, 256, 512,
        feat1, fcw_b + 131072, fc_b1, gh_b + (size_t)20000 * 256);

    // ---- CSR build (once) ----
    hipMemsetAsync(cursor, 0, 80000 * sizeof(int), stream);
    bucket_fill_kernel<<<2500, 256, 0, stream>>>(edge_src, edge_dst, ebuf, cursor, cnt_out, 640000);
    deg_fin_kernel<<<cdiv(40000, 256), 256, 0, stream>>>(cnt_out, dego, 40000);

    // ---- 2x GCN ----
    for (int l = 0; l < 2; ++l) {
        mfma_gemm_kernel<false><<<dim3(2, cdiv(40000, 128), 1), 512, 0, stream>>>(
            gh_b, gcnw_b + (size_t)l * 65536, nullptr, dego, tmp_b, 40000, 256, 256,
            gh_b, gcnw_b, nullptr, tmp_b);
        csr_agg_kernel<<<10000, 256, 0, stream>>>(tmp_b, ebuf, cursor, gh, gh_b, 40000);
    }

    // ---- mega-fused graph transformer per node type ----
    const int* seqs[2] = {dg_seqs, pt_seqs};
    const float* pw[2] = {proj_d_w, proj_p_w};
    const float* pb[2] = {proj_d_b, proj_p_b};
    for (int t = 0; t < 2; ++t) {
        fused_transformer_kernel<<<1024, 256, 0, stream>>>(
            gh, seqs[t],
            wrN + (size_t)t * 4 * 65536, wfT2 + (size_t)t * 4 * 32768,
            gt_ar + (size_t)t * 512, ln_g + (size_t)t * 1024, ln_b + (size_t)t * 1024,
            embT);
        gemm_kernel<true><<<dim3(4, 16), 256, 0, stream>>>(
            embT, pw[t], pb[t], nullptr, t1, 1024, 256, 256, 256, 256, 256, 0, 2);
        gemm_kernel<true><<<dim3(4, 16), 256, 0, stream>>>(
            t1, pw[t] + 65536, pb[t] + 256, nullptr, mx, 1024, 256, 256, 256, 256, 512, t * 256, 0);
    }

    // ---- predict MLP ----
    gemm_kernel<true><<<dim3(4, 16), 256, 0, stream>>>(
        mx, ml_w1, ml_b1, nullptr, m1, 1024, 256, 512, 512, 512, 256, 0, 1);
    gemm_kernel<true><<<dim3(2, 16), 256, 0, stream>>>(
        m1, ml_w2, ml_b2, nullptr, m2, 1024, 128, 256, 256, 256, 128, 0, 1);
    final_kernel<<<256, 256, 0, stream>>>(m2, ml_w3, ml_b3, out, 1024);
}

// Round 7
// 708.701 us; speedup vs baseline: 9.1488x; 1.3395x over previous
//
#include <hip/hip_runtime.h>
#include <hip/hip_bf16.h>
#include <math.h>

typedef unsigned int u32;
typedef unsigned short u16;
typedef __attribute__((ext_vector_type(8))) short bf16x8;
typedef __attribute__((ext_vector_type(4))) float f32x4;

__device__ __forceinline__ float b2f(u16 u) { union { u32 i; float f; } c; c.i = ((u32)u) << 16; return c.f; }
__device__ __forceinline__ u16 f2b(float f) { __hip_bfloat16 h = __float2bfloat16(f); u16 r; __builtin_memcpy(&r, &h, 2); return r; }
__device__ __forceinline__ float b2f_lo(u32 w) { union { u32 i; float f; } c; c.i = w << 16; return c.f; }
__device__ __forceinline__ float b2f_hi(u32 w) { union { u32 i; float f; } c; c.i = w & 0xffff0000u; return c.f; }
__device__ __forceinline__ u32 pk2(float a, float b) { return (u32)f2b(a) | ((u32)f2b(b) << 16); }

__device__ __forceinline__ float wave_sum(float v) {
    #pragma unroll
    for (int off = 32; off > 0; off >>= 1) v += __shfl_xor(v, off, 64);
    return v;
}
__device__ __forceinline__ float wave_max(float v) {
    #pragma unroll
    for (int off = 32; off > 0; off >>= 1) v = fmaxf(v, __shfl_xor(v, off, 64));
    return v;
}

// ================= generic bf16 MFMA GEMM (128x128 tile, 8 waves of 32x64) ====
// C[M,N] = (A[M,K] @ B[N,K]^T) (+bias[col]) (*rowscale[row]) -> bf16 out
// blockIdx.z==1 switches to the alternate pointer set (merged dual GEMM).
template<bool AF32>
__global__ __launch_bounds__(512) void mfma_gemm_kernel(
    const void* __restrict__ Av, const u16* __restrict__ B,
    const float* __restrict__ bias, const float* __restrict__ rowscale,
    u16* __restrict__ Cb, int M, int N, int K,
    const void* __restrict__ Av1, const u16* __restrict__ B1,
    const float* __restrict__ bias1, u16* __restrict__ Cb1)
{
    if (blockIdx.z) { Av = Av1; B = B1; bias = bias1; Cb = Cb1; }
    __shared__ u16 lds[2 * 128 * 64];   // A bytes [0,16384), B bytes [16384,32768)
    const int tid = threadIdx.x;
    const int wid = tid >> 6, lane = tid & 63;
    const int wr = wid >> 1, wc = wid & 1;   // 4 row-strips x 2 col-strips
    const int m0 = blockIdx.y * 128, n0 = blockIdx.x * 128;

    f32x4 acc[2][4] = {};

    const int rsub = lane >> 3;              // 0..7
    const int cbyte = (lane & 7) << 4;       // 0..112
    const int swz_st = cbyte ^ (rsub << 4);

    for (int k0 = 0; k0 < K; k0 += 64) {
        #pragma unroll
        for (int cc = 0; cc < 4; ++cc) {
            int c = wid * 4 + cc;                  // 0..31
            int buf = c >> 4;                      // 0=A, 1=B
            int row_in = ((c & 15) << 3) + rsub;   // 0..127
            int lim = buf ? N : M;
            int row_g = (buf ? n0 : m0) + row_in;
            if (row_g >= lim) row_g = lim - 1;
            if (buf == 0 && AF32) {
                const float* src = (const float*)Av + (size_t)row_g * K + k0 + (cbyte >> 1);
                float4 v0 = *(const float4*)src;
                float4 v1 = *(const float4*)(src + 4);
                uint4 pk;
                pk.x = pk2(v0.x, v0.y); pk.y = pk2(v0.z, v0.w);
                pk.z = pk2(v1.x, v1.y); pk.w = pk2(v1.z, v1.w);
                *(uint4*)((char*)lds + row_in * 128 + swz_st) = pk;
            } else {
                const u16* srcb = (buf ? B : (const u16*)Av) + (size_t)row_g * K + k0 + (cbyte >> 1);
                f32x4 v = *(const f32x4*)srcb;
                *(f32x4*)((char*)lds + buf * 16384 + row_in * 128 + swz_st) = v;
            }
        }
        __syncthreads();
        #pragma unroll
        for (int ks = 0; ks < 2; ++ks) {
            const int off = (ks * 64 + ((lane >> 4) << 4)) ^ ((lane & 7) << 4);
            const int ra = lane & 15;
            bf16x8 af[2], bfr[4];
            #pragma unroll
            for (int i = 0; i < 2; ++i)
                af[i] = *(bf16x8*)((char*)lds + (wr * 32 + i * 16 + ra) * 128 + off);
            #pragma unroll
            for (int j = 0; j < 4; ++j)
                bfr[j] = *(bf16x8*)((char*)lds + 16384 + (wc * 64 + j * 16 + ra) * 128 + off);
            #pragma unroll
            for (int i = 0; i < 2; ++i)
                #pragma unroll
                for (int j = 0; j < 4; ++j)
                    acc[i][j] = __builtin_amdgcn_mfma_f32_16x16x32_bf16(af[i], bfr[j], acc[i][j], 0, 0, 0);
        }
        __syncthreads();
    }

    const int cr = lane >> 4, ccol = lane & 15;
    #pragma unroll
    for (int i = 0; i < 2; ++i) {
        #pragma unroll
        for (int j = 0; j < 4; ++j) {
            int colg = n0 + wc * 64 + j * 16 + ccol;
            if (colg >= N) continue;
            float badd = bias ? bias[colg] : 0.f;
            #pragma unroll
            for (int reg = 0; reg < 4; ++reg) {
                int rowg = m0 + wr * 32 + i * 16 + cr * 4 + reg;
                if (rowg >= M) continue;
                float v = acc[i][j][reg] + badd;
                if (rowscale) v *= rowscale[rowg];
                Cb[(size_t)rowg * N + colg] = f2b(v);
            }
        }
    }
}

// ================= mega-fused 4-layer graph transformer ======================
// Block = 1 sequence (64 rows), 512 threads / 8 waves, both types in one grid
// (t = blockIdx.x>>10). Residual h in registers (thread: row r=tid>>3,
// col-octant o8=tid&7, y[8] float4 = 32 f32). Per layer: pack y -> swizzled
// bf16 LDS A (32KB); fr = h @ wr^T (wave wid owns 32 cols, acc[4][2]); B-frags
// coalesced from frag-major wrN (L2-resident); additive-attn softmax over the
// 64 rows (query-independent) -> ctx; u = ctx @ wf^T from wfT2; h = LN(h+u).
// Layer 4: LN row 0 only -> embT[2048,256].
__global__ __launch_bounds__(512, 4) void fused_transformer_kernel(
    const float* __restrict__ gh, const int* __restrict__ dg_seqs,
    const int* __restrict__ pt_seqs,
    const u16* __restrict__ wrN,   // [8][16 gn][8 kc][64 lane][8] bf16
    const u32* __restrict__ wfT2,  // [8][128 d2][256 n] packed bf16 pairs
    const float* __restrict__ ar,  // [8][128]
    const float* __restrict__ lng, const float* __restrict__ lnb,  // [8][256]
    float* __restrict__ embT)      // [2048,256]
{
    __shared__ u16 ldsA[64 * 256];       // 32KB: [c:4][row:64][128B swizzled]
    __shared__ float sPart[8][64];       // per-wave score partials
    __shared__ float pbuf[2][64];
    __shared__ float ctxS[256];
    __shared__ float uS2[2][256];

    const int tid = threadIdx.x;
    const int bx = blockIdx.x;
    const int t = bx >> 10, s = bx & 1023;
    const int r = tid >> 3, o8 = tid & 7;        // row 0..63, col-octant 0..7
    const int wid = tid >> 6, lane = tid & 63;
    const int hd = wid >> 2;                     // head (waves 0-3 / 4-7)
    const int g4 = lane >> 4, cl = lane & 15;

    const int* seqs = t ? pt_seqs : dg_seqs;

    // ---- gather h0 (thread's 32 cols of its row) ----
    float4 y[8];
    {
        int node = seqs[s * 64 + r];
        const float* src = gh + (size_t)node * 256 + o8 * 32;
        #pragma unroll
        for (int v = 0; v < 8; ++v) y[v] = *(const float4*)(src + v * 4);
    }

    for (int l = 0; l < 4; ++l) {
        const int li = t * 4 + l;
        // ---- pack y -> swizzled bf16 A-LDS ----
        {
            const int c = o8 >> 1, gb = (o8 & 1) * 4;
            #pragma unroll
            for (int gg = 0; gg < 4; ++gg) {
                float4 a = y[2 * gg], b = y[2 * gg + 1];
                uint4 pk;
                pk.x = pk2(a.x, a.y); pk.y = pk2(a.z, a.w);
                pk.z = pk2(b.x, b.y); pk.w = pk2(b.z, b.w);
                int g = gb + gg;
                *(uint4*)((char*)ldsA + c * 8192 + r * 128 + ((g << 4) ^ ((r & 7) << 4))) = pk;
            }
        }
        __syncthreads();

        // ---- fr = h @ wr^T : wave wid -> cols wid*32..+31, rows 0..63 ----
        f32x4 acc[4][2] = {};
        {
            const u16* wrl = wrN + (size_t)li * 65536;
            const int ra = lane & 15;
            #pragma unroll
            for (int kc = 0; kc < 8; ++kc) {
                const int c = kc >> 1, ks = kc & 1;
                const int off = (ks * 64 + ((lane >> 4) << 4)) ^ ((lane & 7) << 4);
                bf16x8 af[4], bfr[2];
                #pragma unroll
                for (int i = 0; i < 4; ++i)
                    af[i] = *(bf16x8*)((char*)ldsA + c * 8192 + (i * 16 + ra) * 128 + off);
                #pragma unroll
                for (int j = 0; j < 2; ++j)
                    bfr[j] = *(const bf16x8*)(wrl + ((size_t)((wid * 2 + j) * 8 + kc) << 9) + lane * 8);
                #pragma unroll
                for (int i = 0; i < 4; ++i)
                    #pragma unroll
                    for (int j = 0; j < 2; ++j)
                        acc[i][j] = __builtin_amdgcn_mfma_f32_16x16x32_bf16(af[i], bfr[j], acc[i][j], 0, 0, 0);
            }
        }

        // ---- scores over this wave's 32 cols (d-within-head = (wid&3)*32+...) ----
        {
            const float* arl = ar + li * 128;
            float arj[2];
            #pragma unroll
            for (int j = 0; j < 2; ++j) arj[j] = arl[(wid & 3) * 32 + j * 16 + cl];
            #pragma unroll
            for (int i = 0; i < 4; ++i)
                #pragma unroll
                for (int reg = 0; reg < 4; ++reg) {
                    float sc;
                    {
                        float x0 = acc[i][0][reg], x1 = acc[i][1][reg];
                        sc = (x0 >= 0.f ? x0 : 0.01f * x0) * arj[0]
                           + (x1 >= 0.f ? x1 : 0.01f * x1) * arj[1];
                    }
                    sc += __shfl_xor(sc, 1, 64);
                    sc += __shfl_xor(sc, 2, 64);
                    sc += __shfl_xor(sc, 4, 64);
                    sc += __shfl_xor(sc, 8, 64);
                    if (cl == 0) sPart[wid][i * 16 + g4 * 4 + reg] = sc;
                }
        }
        __syncthreads();

        // ---- softmax per head over 64 rows ----
        {
            int base = hd * 4;
            float sv = sPart[base][lane] + sPart[base + 1][lane]
                     + sPart[base + 2][lane] + sPart[base + 3][lane];
            float mx = wave_max(sv);
            float e = expf(sv - mx);
            float sm = wave_sum(e);
            if ((wid & 3) == 0) pbuf[hd][lane] = e / sm;
        }
        __syncthreads();

        // ---- ctx over wave's 32 cols ----
        {
            float pv[4][4];
            #pragma unroll
            for (int i = 0; i < 4; ++i)
                #pragma unroll
                for (int reg = 0; reg < 4; ++reg)
                    pv[i][reg] = pbuf[hd][i * 16 + g4 * 4 + reg];
            #pragma unroll
            for (int j = 0; j < 2; ++j) {
                float c = 0.f;
                #pragma unroll
                for (int i = 0; i < 4; ++i)
                    #pragma unroll
                    for (int reg = 0; reg < 4; ++reg)
                        c = fmaf(pv[i][reg], acc[i][j][reg], c);
                c += __shfl_xor(c, 16, 64);
                c += __shfl_xor(c, 32, 64);
                if (g4 == 0) ctxS[wid * 32 + j * 16 + cl] = c;
            }
        }
        __syncthreads();

        // ---- u[n] = sum_d ctx[d]*wf[n][d], d split over 2 thread-halves ----
        {
            const int n = tid & 255, half = tid >> 8;
            const u32* wp = wfT2 + (size_t)li * 32768 + (size_t)half * 16384 + n;
            float ua = 0.f;
            #pragma unroll 8
            for (int d2 = 0; d2 < 64; ++d2) {
                u32 w2 = wp[(size_t)d2 * 256];
                ua = fmaf(ctxS[half * 128 + 2 * d2], b2f_lo(w2), ua);
                ua = fmaf(ctxS[half * 128 + 2 * d2 + 1], b2f_hi(w2), ua);
            }
            uS2[half][n] = ua;
        }
        __syncthreads();

        // ---- h = LN(h + u) (8 threads per row; shuffle xor 1,2,4) ----
        {
            #pragma unroll
            for (int v = 0; v < 8; ++v) {
                int c0 = o8 * 32 + v * 4;
                float4 u0 = *(const float4*)&uS2[0][c0];
                float4 u1 = *(const float4*)&uS2[1][c0];
                y[v].x += u0.x + u1.x; y[v].y += u0.y + u1.y;
                y[v].z += u0.z + u1.z; y[v].w += u0.w + u1.w;
            }
            float sm = 0.f, qq = 0.f;
            #pragma unroll
            for (int v = 0; v < 8; ++v) {
                sm += y[v].x + y[v].y + y[v].z + y[v].w;
                qq += y[v].x * y[v].x + y[v].y * y[v].y + y[v].z * y[v].z + y[v].w * y[v].w;
            }
            sm += __shfl_xor(sm, 1, 64); sm += __shfl_xor(sm, 2, 64); sm += __shfl_xor(sm, 4, 64);
            qq += __shfl_xor(qq, 1, 64); qq += __shfl_xor(qq, 2, 64); qq += __shfl_xor(qq, 4, 64);
            float mean = sm * (1.f / 256.f);
            float var = qq * (1.f / 256.f) - mean * mean;
            float inv = rsqrtf(var + 1e-5f);
            const float* gl = lng + li * 256 + o8 * 32;
            const float* bl = lnb + li * 256 + o8 * 32;
            if (l < 3) {
                #pragma unroll
                for (int v = 0; v < 8; ++v) {
                    float4 gv = *(const float4*)(gl + v * 4);
                    float4 bv = *(const float4*)(bl + v * 4);
                    y[v].x = (y[v].x - mean) * inv * gv.x + bv.x;
                    y[v].y = (y[v].y - mean) * inv * gv.y + bv.y;
                    y[v].z = (y[v].z - mean) * inv * gv.z + bv.z;
                    y[v].w = (y[v].w - mean) * inv * gv.w + bv.w;
                }
            } else if (r == 0) {
                float* dst = embT + (size_t)(t * 1024 + s) * 256 + o8 * 32;
                #pragma unroll
                for (int v = 0; v < 8; ++v) {
                    float4 gv = *(const float4*)(gl + v * 4);
                    float4 bv = *(const float4*)(bl + v * 4);
                    float4 o;
                    o.x = (y[v].x - mean) * inv * gv.x + bv.x;
                    o.y = (y[v].y - mean) * inv * gv.y + bv.y;
                    o.z = (y[v].z - mean) * inv * gv.z + bv.z;
                    o.w = (y[v].w - mean) * inv * gv.w + bv.w;
                    *(float4*)(dst + v * 4) = o;
                }
            }
        }
        __syncthreads();
    }
}

// ================= fp32 tiled GEMM (small M) =================
template<bool BT>
__global__ __launch_bounds__(256) void gemm_kernel(
    const float* __restrict__ A, const float* __restrict__ B,
    const float* __restrict__ bias, const float* __restrict__ rowscale,
    float* __restrict__ C,
    int M, int N, int K, int lda, int ldb, int ldc, int coff, int act)
{
    __shared__ float As[32][64 + 4];
    __shared__ float Bs[32][64 + 4];
    const int tid = threadIdx.x;
    const int m0 = blockIdx.y * 64;
    const int n0 = blockIdx.x * 64;
    const int ty = tid >> 4, tx = tid & 15;
    float acc[4][4] = {};
    for (int k0 = 0; k0 < K; k0 += 32) {
        #pragma unroll
        for (int r = 0; r < 2; ++r) {
            int f4 = tid + r * 256;
            int arw = f4 >> 3, af = (f4 & 7) << 2;
            float4 v = make_float4(0.f, 0.f, 0.f, 0.f);
            int grow = m0 + arw;
            if (grow < M) {
                v = *(const float4*)(A + (size_t)grow * lda + k0 + af);
                if (rowscale) { float s = rowscale[grow]; v.x *= s; v.y *= s; v.z *= s; v.w *= s; }
            }
            As[af + 0][arw] = v.x; As[af + 1][arw] = v.y; As[af + 2][arw] = v.z; As[af + 3][arw] = v.w;
        }
        #pragma unroll
        for (int r = 0; r < 2; ++r) {
            int f4 = tid + r * 256;
            int col = f4 >> 3, kf = (f4 & 7) << 2;
            float4 v = make_float4(0.f, 0.f, 0.f, 0.f);
            if (n0 + col < N) v = *(const float4*)(B + (size_t)(n0 + col) * ldb + k0 + kf);
            Bs[kf + 0][col] = v.x; Bs[kf + 1][col] = v.y; Bs[kf + 2][col] = v.z; Bs[kf + 3][col] = v.w;
        }
        __syncthreads();
        #pragma unroll
        for (int kk = 0; kk < 32; ++kk) {
            float4 a4 = *(const float4*)&As[kk][ty << 2];
            float4 b4 = *(const float4*)&Bs[kk][tx << 2];
            float a[4] = {a4.x, a4.y, a4.z, a4.w};
            float b[4] = {b4.x, b4.y, b4.z, b4.w};
            #pragma unroll
            for (int i = 0; i < 4; ++i)
                #pragma unroll
                for (int j = 0; j < 4; ++j)
                    acc[i][j] = fmaf(a[i], b[j], acc[i][j]);
        }
        __syncthreads();
    }
    #pragma unroll
    for (int i = 0; i < 4; ++i) {
        int row = m0 + (ty << 2) + i;
        if (row >= M) continue;
        #pragma unroll
        for (int j = 0; j < 4; ++j) {
            int col = n0 + (tx << 2) + j;
            if (col >= N) continue;
            float v = acc[i][j];
            if (bias) v += bias[col];
            if (act == 1) v = fmaxf(v, 0.f);
            else if (act == 2) v = (v > 0.f) ? v : expm1f(v);
            C[(size_t)row * ldc + coff + col] = v;
        }
    }
}

// ================= converts =================
__global__ __launch_bounds__(256) void conv_flat_kernel(const float* __restrict__ in, u16* __restrict__ out, int n) {
    int i = (blockIdx.x * 256 + threadIdx.x) * 4;
    if (i >= n) return;
    float4 v = *(const float4*)(in + i);
    *(uint2*)(out + i) = make_uint2(pk2(v.x, v.y), pk2(v.z, v.w));
}
__global__ __launch_bounds__(256) void conv_gcnw_kernel(const float* __restrict__ w, u16* __restrict__ out) {
    int idx = blockIdx.x * 256 + threadIdx.x;   // 0..65535
    int l = blockIdx.y;
    int k = idx >> 8, n = idx & 255;
    out[(size_t)l * 65536 + n * 256 + k] = f2b(w[(size_t)l * 65536 + k * 256 + n]);
}
// gt_wr [8][256 n][256 k] -> frag-major wrN: [(l*16+gn)*8+kc] frags of 64 lanes x 16B
__global__ __launch_bounds__(256) void conv_wrN_kernel(const float* __restrict__ w, u16* __restrict__ out) {
    int idx = blockIdx.x * 256 + threadIdx.x;    // 0..65535
    int lane = idx & 63;
    int kc = (idx >> 6) & 7;
    int gn = (idx >> 9) & 15;
    int l = idx >> 13;
    int row = gn * 16 + (lane & 15);
    int k0 = kc * 32 + (lane >> 4) * 8;
    const float* src = w + ((size_t)l * 256 + row) * 256 + k0;
    float4 v0 = *(const float4*)src;
    float4 v1 = *(const float4*)(src + 4);
    uint4 pk;
    pk.x = pk2(v0.x, v0.y); pk.y = pk2(v0.z, v0.w);
    pk.z = pk2(v1.x, v1.y); pk.w = pk2(v1.z, v1.w);
    *(uint4*)(out + (size_t)idx * 8) = pk;
}
// gt_wf [8][256 n][256 d] -> wfT2 u32 [8][128 d2][256 n] = pack(wf[n][2d2], wf[n][2d2+1])
__global__ __launch_bounds__(256) void conv_wfT2_kernel(const float* __restrict__ w, u32* __restrict__ out) {
    int idx = blockIdx.x * 256 + threadIdx.x;    // 0..262143
    int n = idx & 255;
    int d2 = (idx >> 8) & 127;
    int l = idx >> 15;
    const float* src = w + ((size_t)l * 256 + n) * 256 + 2 * d2;
    out[idx] = pk2(src[0], src[1]);
}

// ================= CSR build =================
#define EDGE_CAP 128
__global__ __launch_bounds__(256) void bucket_fill_kernel(
    const int* __restrict__ src, const int* __restrict__ dst,
    int* __restrict__ ebuf, int* __restrict__ cursor, int* __restrict__ cnt_out, int ne)
{
    int e = blockIdx.x * 256 + threadIdx.x;
    if (e >= ne) return;
    int s = src[e], d = dst[e];
    atomicAdd(&cnt_out[s], 1);
    int pos = atomicAdd(&cursor[d], 1);
    if (pos < EDGE_CAP) ebuf[(size_t)d * EDGE_CAP + pos] = s;
}
__global__ __launch_bounds__(256) void deg_fin_kernel(const int* __restrict__ cnt, float* __restrict__ dinv, int n) {
    int i = blockIdx.x * 256 + threadIdx.x;
    if (i < n) dinv[i] = rsqrtf(fmaxf((float)cnt[i], 1.0f));
}

// ================= CSR aggregate (bf16 in, fp32+bf16 out), 4x unrolled =======
__global__ __launch_bounds__(256) void csr_agg_kernel(
    const u16* __restrict__ x, const int* __restrict__ ebuf,
    const int* __restrict__ deg, float* __restrict__ outf, u16* __restrict__ outb, int nnodes)
{
    int n = blockIdx.x * 4 + (threadIdx.x >> 6);
    if (n >= nnodes) return;
    int lane = threadIdx.x & 63;
    int d = deg[n];
    float dinv = rsqrtf(fmaxf((float)d, 1.0f));
    if (d > EDGE_CAP) d = EDGE_CAP;
    const int* eb = ebuf + (size_t)n * EDGE_CAP;
    const int co = lane << 2;
    float a0 = 0.f, a1 = 0.f, a2 = 0.f, a3 = 0.f;
    int k = 0;
    for (; k + 4 <= d; k += 4) {
        int4 s4 = *(const int4*)(eb + k);
        uint2 va = *(const uint2*)(x + (size_t)s4.x * 256 + co);
        uint2 vb = *(const uint2*)(x + (size_t)s4.y * 256 + co);
        uint2 vc = *(const uint2*)(x + (size_t)s4.z * 256 + co);
        uint2 vd = *(const uint2*)(x + (size_t)s4.w * 256 + co);
        a0 += b2f_lo(va.x) + b2f_lo(vb.x) + b2f_lo(vc.x) + b2f_lo(vd.x);
        a1 += b2f_hi(va.x) + b2f_hi(vb.x) + b2f_hi(vc.x) + b2f_hi(vd.x);
        a2 += b2f_lo(va.y) + b2f_lo(vb.y) + b2f_lo(vc.y) + b2f_lo(vd.y);
        a3 += b2f_hi(va.y) + b2f_hi(vb.y) + b2f_hi(vc.y) + b2f_hi(vd.y);
    }
    for (; k < d; ++k) {
        int s = eb[k];
        uint2 v = *(const uint2*)(x + (size_t)s * 256 + co);
        a0 += b2f_lo(v.x); a1 += b2f_hi(v.x);
        a2 += b2f_lo(v.y); a3 += b2f_hi(v.y);
    }
    a0 = fmaxf(a0 * dinv, 0.f); a1 = fmaxf(a1 * dinv, 0.f);
    a2 = fmaxf(a2 * dinv, 0.f); a3 = fmaxf(a3 * dinv, 0.f);
    *(float4*)(outf + (size_t)n * 256 + co) = make_float4(a0, a1, a2, a3);
    *(uint2*)(outb + (size_t)n * 256 + co) = make_uint2(pk2(a0, a1), pk2(a2, a3));
}

// ================= final =================
__global__ __launch_bounds__(256) void final_kernel(
    const float* __restrict__ m2, const float* __restrict__ w3,
    const float* __restrict__ b3, float* __restrict__ out, int nrows)
{
    int row = blockIdx.x * 4 + (threadIdx.x >> 6);
    int lane = threadIdx.x & 63;
    if (row >= nrows) return;
    float s = m2[(size_t)row * 128 + lane] * w3[lane]
            + m2[(size_t)row * 128 + 64 + lane] * w3[64 + lane];
    s = wave_sum(s);
    if (lane == 0) out[row] = 1.f / (1.f + expf(-(s + b3[0])));
}

static inline int cdiv(int a, int b) { return (a + b - 1) / b; }

extern "C" void kernel_launch(void* const* d_in, const int* in_sizes, int n_in,
                              void* d_out, int out_size, void* d_ws, size_t ws_size,
                              hipStream_t stream)
{
    const float* feat0   = (const float*)d_in[0];
    const float* feat1   = (const float*)d_in[1];
    const float* fc_w0   = (const float*)d_in[2];
    const float* fc_b0   = (const float*)d_in[3];
    const float* fc_w1   = (const float*)d_in[4];
    const float* fc_b1   = (const float*)d_in[5];
    const float* gcn_w   = (const float*)d_in[6];
    const int*   edge_src= (const int*)d_in[7];
    const int*   edge_dst= (const int*)d_in[8];
    const int*   dg_seqs = (const int*)d_in[9];
    const int*   pt_seqs = (const int*)d_in[10];
    // 11 type_emb, 12 node_type: dead; 13 gt_wl, 15 gt_al: dead (softmax cancellation)
    const float* gt_wr   = (const float*)d_in[14];
    const float* gt_ar   = (const float*)d_in[16];
    const float* gt_wf   = (const float*)d_in[17];
    const float* ln_g    = (const float*)d_in[18];
    const float* ln_b    = (const float*)d_in[19];
    const float* proj_d_w= (const float*)d_in[20];
    const float* proj_d_b= (const float*)d_in[21];
    const float* proj_p_w= (const float*)d_in[22];
    const float* proj_p_b= (const float*)d_in[23];
    const float* ml_w1   = (const float*)d_in[24];
    const float* ml_b1   = (const float*)d_in[25];
    const float* ml_w2   = (const float*)d_in[26];
    const float* ml_b2   = (const float*)d_in[27];
    const float* ml_w3   = (const float*)d_in[28];
    const float* ml_b3   = (const float*)d_in[29];
    float* out = (float*)d_out;

    // ---- workspace layout (f32 units) ----
    float* base  = (float*)d_ws;
    float* gh    = base;                      // 10,240,000
    float* gcnR  = gh + 10240000;             // GCN-phase region (15,440,000)
    float* dego  = gcnR + 15440000;           // 40,000
    float* embT  = dego + 40000;              // 524,288 (both types)
    float* t1    = embT + 524288;             // 262,144
    float* mx    = t1 + 262144;               // 524,288
    float* m1    = mx + 524288;               // 262,144
    float* m2    = m1 + 262144;               // 131,072
    float* wreg  = m2 + 131072;               // converted weights

    u16* tmp_b   = (u16*)gcnR;                        // 10,240,000 bf16
    int* ebuf    = (int*)(gcnR + 5120000);            // 5,120,000 int
    int* cursor  = ebuf + (size_t)40000 * EDGE_CAP;   // 40,000
    int* cnt_out = cursor + 40000;                    // 40,000
    u16* gh_b    = (u16*)(gcnR + 10320000);           // 10,240,000 bf16

    u16* fcw_b   = (u16*)wreg;                // 262,144 u16
    u16* gcnw_b  = fcw_b + 262144;            // 131,072 u16
    u16* wrN     = gcnw_b + 131072;           // 524,288 u16 (8 layers x 65,536)
    u32* wfT2    = (u32*)(wrN + 524288);      // 262,144 u32 (8 layers x 32,768)

    // ---- weight converts ----
    conv_flat_kernel<<<cdiv(131072 / 4, 256), 256, 0, stream>>>(fc_w0, fcw_b, 131072);
    conv_flat_kernel<<<cdiv(131072 / 4, 256), 256, 0, stream>>>(fc_w1, fcw_b + 131072, 131072);
    conv_gcnw_kernel<<<dim3(256, 2), 256, 0, stream>>>(gcn_w, gcnw_b);
    conv_wrN_kernel<<<256, 256, 0, stream>>>(gt_wr, wrN);
    conv_wfT2_kernel<<<1024, 256, 0, stream>>>(gt_wf, wfT2);

    // ---- FC projections (merged dual GEMM via blockIdx.z) -> gh_b ----
    mfma_gemm_kernel<true><<<dim3(2, cdiv(20000, 128), 2), 512, 0, stream>>>(
        feat0, fcw_b, fc_b0, nullptr, gh_b, 20000, 256, 512,
        feat1, fcw_b + 131072, fc_b1, gh_b + (size_t)20000 * 256);

    // ---- CSR build (once) ----
    hipMemsetAsync(cursor, 0, 80000 * sizeof(int), stream);
    bucket_fill_kernel<<<2500, 256, 0, stream>>>(edge_src, edge_dst, ebuf, cursor, cnt_out, 640000);
    deg_fin_kernel<<<cdiv(40000, 256), 256, 0, stream>>>(cnt_out, dego, 40000);

    // ---- 2x GCN ----
    for (int l = 0; l < 2; ++l) {
        mfma_gemm_kernel<false><<<dim3(2, cdiv(40000, 128), 1), 512, 0, stream>>>(
            gh_b, gcnw_b + (size_t)l * 65536, nullptr, dego, tmp_b, 40000, 256, 256,
            gh_b, gcnw_b, nullptr, tmp_b);
        csr_agg_kernel<<<10000, 256, 0, stream>>>(tmp_b, ebuf, cursor, gh, gh_b, 40000);
    }

    // ---- mega-fused graph transformer, both types in one dispatch ----
    fused_transformer_kernel<<<2048, 512, 0, stream>>>(
        gh, dg_seqs, pt_seqs, wrN, wfT2, gt_ar, ln_g, ln_b, embT);

    // ---- proj heads ----
    const float* pw[2] = {proj_d_w, proj_p_w};
    const float* pb[2] = {proj_d_b, proj_p_b};
    for (int t = 0; t < 2; ++t) {
        gemm_kernel<true><<<dim3(4, 16), 256, 0, stream>>>(
            embT + (size_t)t * 262144, pw[t], pb[t], nullptr, t1, 1024, 256, 256, 256, 256, 256, 0, 2);
        gemm_kernel<true><<<dim3(4, 16), 256, 0, stream>>>(
            t1, pw[t] + 65536, pb[t] + 256, nullptr, mx, 1024, 256, 256, 256, 256, 512, t * 256, 0);
    }

    // ---- predict MLP ----
    gemm_kernel<true><<<dim3(4, 16), 256, 0, stream>>>(
        mx, ml_w1, ml_b1, nullptr, m1, 1024, 256, 512, 512, 512, 256, 0, 1);
    gemm_kernel<true><<<dim3(2, 16), 256, 0, stream>>>(
        m1, ml_w2, ml_b2, nullptr, m2, 1024, 128, 256, 256, 256, 128, 0, 1);
    final_kernel<<<256, 256, 0, stream>>>(m2, ml_w3, ml_b3, out, 1024);
}

// Round 8
// 695.502 us; speedup vs baseline: 9.3224x; 1.0190x over previous
//
#include <hip/hip_runtime.h>
#include <hip/hip_bf16.h>
#include <math.h>

typedef unsigned int u32;
typedef unsigned short u16;
typedef __attribute__((ext_vector_type(8))) short bf16x8;
typedef __attribute__((ext_vector_type(4))) float f32x4;

__device__ __forceinline__ float b2f(u16 u) { union { u32 i; float f; } c; c.i = ((u32)u) << 16; return c.f; }
__device__ __forceinline__ u16 f2b(float f) { __hip_bfloat16 h = __float2bfloat16(f); u16 r; __builtin_memcpy(&r, &h, 2); return r; }
__device__ __forceinline__ float b2f_lo(u32 w) { union { u32 i; float f; } c; c.i = w << 16; return c.f; }
__device__ __forceinline__ float b2f_hi(u32 w) { union { u32 i; float f; } c; c.i = w & 0xffff0000u; return c.f; }
__device__ __forceinline__ u32 pk2(float a, float b) { return (u32)f2b(a) | ((u32)f2b(b) << 16); }

__device__ __forceinline__ float wave_sum(float v) {
    #pragma unroll
    for (int off = 32; off > 0; off >>= 1) v += __shfl_xor(v, off, 64);
    return v;
}
__device__ __forceinline__ float wave_max(float v) {
    #pragma unroll
    for (int off = 32; off > 0; off >>= 1) v = fmaxf(v, __shfl_xor(v, off, 64));
    return v;
}

// ================= bf16 MFMA GEMM (64x128 tile, 4 waves of 32x64) ============
// C[M,N] = (A[M,K] @ B[N,K]^T) (+bias[col]) (*rowscale[row]) -> bf16 out
// blockIdx.z==1 switches to the alternate pointer set (merged dual GEMM).
template<bool AF32>
__global__ __launch_bounds__(256) void mfma_gemm_kernel(
    const void* __restrict__ Av, const u16* __restrict__ B,
    const float* __restrict__ bias, const float* __restrict__ rowscale,
    u16* __restrict__ Cb, int M, int N, int K,
    const void* __restrict__ Av1, const u16* __restrict__ B1,
    const float* __restrict__ bias1, u16* __restrict__ Cb1)
{
    if (blockIdx.z) { Av = Av1; B = B1; bias = bias1; Cb = Cb1; }
    __shared__ u16 lds[(64 + 128) * 64];   // A bytes [0,8192), B bytes [8192,24576)
    const int tid = threadIdx.x;
    const int wid = tid >> 6, lane = tid & 63;
    const int wr = wid >> 1, wc = wid & 1;   // 2 row-strips x 2 col-strips
    const int m0 = blockIdx.y * 64, n0 = blockIdx.x * 128;

    f32x4 acc[2][4] = {};

    for (int k0 = 0; k0 < K; k0 += 64) {
        // ---- stage A: 64 rows x 8 granules = 512, 2/thread
        #pragma unroll
        for (int s = 0; s < 2; ++s) {
            int idx = tid + s * 256;
            int row = idx >> 3, g = idx & 7;
            int row_g = m0 + row; if (row_g >= M) row_g = M - 1;
            int swz = ((g << 4) ^ ((row & 7) << 4));
            if (AF32) {
                const float* src = (const float*)Av + (size_t)row_g * K + k0 + g * 8;
                float4 v0 = *(const float4*)src;
                float4 v1 = *(const float4*)(src + 4);
                uint4 pk;
                pk.x = pk2(v0.x, v0.y); pk.y = pk2(v0.z, v0.w);
                pk.z = pk2(v1.x, v1.y); pk.w = pk2(v1.z, v1.w);
                *(uint4*)((char*)lds + row * 128 + swz) = pk;
            } else {
                f32x4 v = *(const f32x4*)((const u16*)Av + (size_t)row_g * K + k0 + g * 8);
                *(f32x4*)((char*)lds + row * 128 + swz) = v;
            }
        }
        // ---- stage B: 128 rows x 8 granules = 1024, 4/thread
        #pragma unroll
        for (int s = 0; s < 4; ++s) {
            int idx = tid + s * 256;
            int row = idx >> 3, g = idx & 7;
            int row_g = n0 + row; if (row_g >= N) row_g = N - 1;
            f32x4 v = *(const f32x4*)(B + (size_t)row_g * K + k0 + g * 8);
            *(f32x4*)((char*)lds + 8192 + row * 128 + ((g << 4) ^ ((row & 7) << 4))) = v;
        }
        __syncthreads();
        #pragma unroll
        for (int ks = 0; ks < 2; ++ks) {
            const int off = (ks * 64 + ((lane >> 4) << 4)) ^ ((lane & 7) << 4);
            const int ra = lane & 15;
            bf16x8 af[2], bfr[4];
            #pragma unroll
            for (int i = 0; i < 2; ++i)
                af[i] = *(bf16x8*)((char*)lds + (wr * 32 + i * 16 + ra) * 128 + off);
            #pragma unroll
            for (int j = 0; j < 4; ++j)
                bfr[j] = *(bf16x8*)((char*)lds + 8192 + (wc * 64 + j * 16 + ra) * 128 + off);
            #pragma unroll
            for (int i = 0; i < 2; ++i)
                #pragma unroll
                for (int j = 0; j < 4; ++j)
                    acc[i][j] = __builtin_amdgcn_mfma_f32_16x16x32_bf16(af[i], bfr[j], acc[i][j], 0, 0, 0);
        }
        __syncthreads();
    }

    const int cr = lane >> 4, ccol = lane & 15;
    #pragma unroll
    for (int i = 0; i < 2; ++i) {
        #pragma unroll
        for (int j = 0; j < 4; ++j) {
            int colg = n0 + wc * 64 + j * 16 + ccol;
            if (colg >= N) continue;
            float badd = bias ? bias[colg] : 0.f;
            #pragma unroll
            for (int reg = 0; reg < 4; ++reg) {
                int rowg = m0 + wr * 32 + i * 16 + cr * 4 + reg;
                if (rowg >= M) continue;
                float v = acc[i][j][reg] + badd;
                if (rowscale) v *= rowscale[rowg];
                Cb[(size_t)rowg * N + colg] = f2b(v);
            }
        }
    }
}

// ================= mega-fused 4-layer graph transformer ======================
// Block = 1 sequence (64 rows), 512 threads / 8 waves, both types in one grid.
// Small attn buffers OVERLAY dead ldsA (A-tile is dead after the fr-GEMM reads;
// extra barrier separates). LDS total = 32KB -> 4 blocks/CU (thread-capped).
__global__ __launch_bounds__(512, 4) void fused_transformer_kernel(
    const float* __restrict__ gh, const int* __restrict__ dg_seqs,
    const int* __restrict__ pt_seqs,
    const u16* __restrict__ wrN,   // [8][16 gn][8 kc][64 lane][8] bf16
    const u32* __restrict__ wfT2,  // [8][128 d2][256 n] packed bf16 pairs
    const float* __restrict__ ar,  // [8][128]
    const float* __restrict__ lng, const float* __restrict__ lnb,  // [8][256]
    float* __restrict__ embT)      // [2048,256]
{
    __shared__ u16 ldsA[64 * 256];       // 32KB: [c:4][row:64][128B swizzled]
    float* sPartO = (float*)ldsA;        // overlay: [8][64]   bytes [0,2048)
    float* pbufO  = sPartO + 512;        //          [2][64]   [2048,2560)
    float* ctxO   = pbufO + 128;         //          [256]     [2560,3584)
    float* uO     = ctxO + 256;          //          [2][256]  [3584,5632)

    const int tid = threadIdx.x;
    const int bx = blockIdx.x;
    const int t = bx >> 10, s = bx & 1023;
    const int r = tid >> 3, o8 = tid & 7;        // row 0..63, col-octant 0..7
    const int wid = tid >> 6, lane = tid & 63;
    const int hd = wid >> 2;                     // head (waves 0-3 / 4-7)
    const int g4 = lane >> 4, cl = lane & 15;

    const int* seqs = t ? pt_seqs : dg_seqs;

    // ---- gather h0 (thread's 32 cols of its row) ----
    float4 y[8];
    {
        int node = seqs[s * 64 + r];
        const float* src = gh + (size_t)node * 256 + o8 * 32;
        #pragma unroll
        for (int v = 0; v < 8; ++v) y[v] = *(const float4*)(src + v * 4);
    }

    for (int l = 0; l < 4; ++l) {
        const int li = t * 4 + l;
        // ---- pack y -> swizzled bf16 A-LDS ----
        {
            const int c = o8 >> 1, gb = (o8 & 1) * 4;
            #pragma unroll
            for (int gg = 0; gg < 4; ++gg) {
                float4 a = y[2 * gg], b = y[2 * gg + 1];
                uint4 pk;
                pk.x = pk2(a.x, a.y); pk.y = pk2(a.z, a.w);
                pk.z = pk2(b.x, b.y); pk.w = pk2(b.z, b.w);
                int g = gb + gg;
                *(uint4*)((char*)ldsA + c * 8192 + r * 128 + ((g << 4) ^ ((r & 7) << 4))) = pk;
            }
        }
        __syncthreads();

        // ---- fr = h @ wr^T : wave wid -> cols wid*32..+31, rows 0..63 ----
        f32x4 acc[4][2] = {};
        {
            const u16* wrl = wrN + (size_t)li * 65536;
            const int ra = lane & 15;
            #pragma unroll
            for (int kc = 0; kc < 8; ++kc) {
                const int c = kc >> 1, ks = kc & 1;
                const int off = (ks * 64 + ((lane >> 4) << 4)) ^ ((lane & 7) << 4);
                bf16x8 af[4], bfr[2];
                #pragma unroll
                for (int i = 0; i < 4; ++i)
                    af[i] = *(bf16x8*)((char*)ldsA + c * 8192 + (i * 16 + ra) * 128 + off);
                #pragma unroll
                for (int j = 0; j < 2; ++j)
                    bfr[j] = *(const bf16x8*)(wrl + ((size_t)((wid * 2 + j) * 8 + kc) << 9) + lane * 8);
                #pragma unroll
                for (int i = 0; i < 4; ++i)
                    #pragma unroll
                    for (int j = 0; j < 2; ++j)
                        acc[i][j] = __builtin_amdgcn_mfma_f32_16x16x32_bf16(af[i], bfr[j], acc[i][j], 0, 0, 0);
            }
        }
        __syncthreads();   // ldsA reads done -> overlay region may be written

        // ---- scores over this wave's 32 cols ----
        {
            const float* arl = ar + li * 128;
            float arj[2];
            #pragma unroll
            for (int j = 0; j < 2; ++j) arj[j] = arl[(wid & 3) * 32 + j * 16 + cl];
            #pragma unroll
            for (int i = 0; i < 4; ++i)
                #pragma unroll
                for (int reg = 0; reg < 4; ++reg) {
                    float sc;
                    {
                        float x0 = acc[i][0][reg], x1 = acc[i][1][reg];
                        sc = (x0 >= 0.f ? x0 : 0.01f * x0) * arj[0]
                           + (x1 >= 0.f ? x1 : 0.01f * x1) * arj[1];
                    }
                    sc += __shfl_xor(sc, 1, 64);
                    sc += __shfl_xor(sc, 2, 64);
                    sc += __shfl_xor(sc, 4, 64);
                    sc += __shfl_xor(sc, 8, 64);
                    if (cl == 0) sPartO[wid * 64 + i * 16 + g4 * 4 + reg] = sc;
                }
        }
        __syncthreads();

        // ---- softmax per head over 64 rows ----
        {
            int base = hd * 4 * 64;
            float sv = sPartO[base + lane] + sPartO[base + 64 + lane]
                     + sPartO[base + 128 + lane] + sPartO[base + 192 + lane];
            float mx = wave_max(sv);
            float e = expf(sv - mx);
            float sm = wave_sum(e);
            if ((wid & 3) == 0) pbufO[hd * 64 + lane] = e / sm;
        }
        __syncthreads();

        // ---- ctx over wave's 32 cols ----
        {
            float pv[4][4];
            #pragma unroll
            for (int i = 0; i < 4; ++i)
                #pragma unroll
                for (int reg = 0; reg < 4; ++reg)
                    pv[i][reg] = pbufO[hd * 64 + i * 16 + g4 * 4 + reg];
            #pragma unroll
            for (int j = 0; j < 2; ++j) {
                float c = 0.f;
                #pragma unroll
                for (int i = 0; i < 4; ++i)
                    #pragma unroll
                    for (int reg = 0; reg < 4; ++reg)
                        c = fmaf(pv[i][reg], acc[i][j][reg], c);
                c += __shfl_xor(c, 16, 64);
                c += __shfl_xor(c, 32, 64);
                if (g4 == 0) ctxO[wid * 32 + j * 16 + cl] = c;
            }
        }
        __syncthreads();

        // ---- u[n] = sum_d ctx[d]*wf[n][d]; 4 accumulators, deep load flight --
        {
            const int n = tid & 255, half = tid >> 8;
            const u32* wp = wfT2 + (size_t)li * 32768 + (size_t)half * 16384 + n;
            const float* cx = ctxO + half * 128;
            float ua0 = 0.f, ua1 = 0.f, ua2 = 0.f, ua3 = 0.f;
            #pragma unroll 4
            for (int d2 = 0; d2 < 64; d2 += 4) {
                u32 w0 = wp[(size_t)(d2 + 0) * 256];
                u32 w1 = wp[(size_t)(d2 + 1) * 256];
                u32 w2 = wp[(size_t)(d2 + 2) * 256];
                u32 w3 = wp[(size_t)(d2 + 3) * 256];
                ua0 = fmaf(cx[2 * d2 + 0], b2f_lo(w0), ua0);
                ua0 = fmaf(cx[2 * d2 + 1], b2f_hi(w0), ua0);
                ua1 = fmaf(cx[2 * d2 + 2], b2f_lo(w1), ua1);
                ua1 = fmaf(cx[2 * d2 + 3], b2f_hi(w1), ua1);
                ua2 = fmaf(cx[2 * d2 + 4], b2f_lo(w2), ua2);
                ua2 = fmaf(cx[2 * d2 + 5], b2f_hi(w2), ua2);
                ua3 = fmaf(cx[2 * d2 + 6], b2f_lo(w3), ua3);
                ua3 = fmaf(cx[2 * d2 + 7], b2f_hi(w3), ua3);
            }
            uO[half * 256 + n] = (ua0 + ua1) + (ua2 + ua3);
        }
        __syncthreads();

        // ---- h = LN(h + u) (8 threads per row; shuffle xor 1,2,4) ----
        {
            #pragma unroll
            for (int v = 0; v < 8; ++v) {
                int c0 = o8 * 32 + v * 4;
                float4 u0 = *(const float4*)&uO[c0];
                float4 u1 = *(const float4*)&uO[256 + c0];
                y[v].x += u0.x + u1.x; y[v].y += u0.y + u1.y;
                y[v].z += u0.z + u1.z; y[v].w += u0.w + u1.w;
            }
            float sm = 0.f, qq = 0.f;
            #pragma unroll
            for (int v = 0; v < 8; ++v) {
                sm += y[v].x + y[v].y + y[v].z + y[v].w;
                qq += y[v].x * y[v].x + y[v].y * y[v].y + y[v].z * y[v].z + y[v].w * y[v].w;
            }
            sm += __shfl_xor(sm, 1, 64); sm += __shfl_xor(sm, 2, 64); sm += __shfl_xor(sm, 4, 64);
            qq += __shfl_xor(qq, 1, 64); qq += __shfl_xor(qq, 2, 64); qq += __shfl_xor(qq, 4, 64);
            float mean = sm * (1.f / 256.f);
            float var = qq * (1.f / 256.f) - mean * mean;
            float inv = rsqrtf(var + 1e-5f);
            const float* gl = lng + li * 256 + o8 * 32;
            const float* bl = lnb + li * 256 + o8 * 32;
            if (l < 3) {
                #pragma unroll
                for (int v = 0; v < 8; ++v) {
                    float4 gv = *(const float4*)(gl + v * 4);
                    float4 bv = *(const float4*)(bl + v * 4);
                    y[v].x = (y[v].x - mean) * inv * gv.x + bv.x;
                    y[v].y = (y[v].y - mean) * inv * gv.y + bv.y;
                    y[v].z = (y[v].z - mean) * inv * gv.z + bv.z;
                    y[v].w = (y[v].w - mean) * inv * gv.w + bv.w;
                }
            } else if (r == 0) {
                float* dst = embT + (size_t)(t * 1024 + s) * 256 + o8 * 32;
                #pragma unroll
                for (int v = 0; v < 8; ++v) {
                    float4 gv = *(const float4*)(gl + v * 4);
                    float4 bv = *(const float4*)(bl + v * 4);
                    float4 o;
                    o.x = (y[v].x - mean) * inv * gv.x + bv.x;
                    o.y = (y[v].y - mean) * inv * gv.y + bv.y;
                    o.z = (y[v].z - mean) * inv * gv.z + bv.z;
                    o.w = (y[v].w - mean) * inv * gv.w + bv.w;
                    *(float4*)(dst + v * 4) = o;
                }
            }
        }
        __syncthreads();
    }
}

// ================= fp32 tiled GEMM (small M), dual-set via blockIdx.z ========
template<bool BT>
__global__ __launch_bounds__(256) void gemm_kernel(
    const float* __restrict__ A, const float* __restrict__ B,
    const float* __restrict__ bias, const float* __restrict__ rowscale,
    float* __restrict__ C,
    int M, int N, int K, int lda, int ldb, int ldc, int coff, int act,
    const float* __restrict__ A1, const float* __restrict__ B1,
    const float* __restrict__ bias1, float* __restrict__ C1, int coff1)
{
    if (blockIdx.z) { A = A1; B = B1; bias = bias1; C = C1; coff = coff1; }
    __shared__ float As[32][64 + 4];
    __shared__ float Bs[32][64 + 4];
    const int tid = threadIdx.x;
    const int m0 = blockIdx.y * 64;
    const int n0 = blockIdx.x * 64;
    const int ty = tid >> 4, tx = tid & 15;
    float acc[4][4] = {};
    for (int k0 = 0; k0 < K; k0 += 32) {
        #pragma unroll
        for (int r = 0; r < 2; ++r) {
            int f4 = tid + r * 256;
            int arw = f4 >> 3, af = (f4 & 7) << 2;
            float4 v = make_float4(0.f, 0.f, 0.f, 0.f);
            int grow = m0 + arw;
            if (grow < M) {
                v = *(const float4*)(A + (size_t)grow * lda + k0 + af);
                if (rowscale) { float s = rowscale[grow]; v.x *= s; v.y *= s; v.z *= s; v.w *= s; }
            }
            As[af + 0][arw] = v.x; As[af + 1][arw] = v.y; As[af + 2][arw] = v.z; As[af + 3][arw] = v.w;
        }
        #pragma unroll
        for (int r = 0; r < 2; ++r) {
            int f4 = tid + r * 256;
            int col = f4 >> 3, kf = (f4 & 7) << 2;
            float4 v = make_float4(0.f, 0.f, 0.f, 0.f);
            if (n0 + col < N) v = *(const float4*)(B + (size_t)(n0 + col) * ldb + k0 + kf);
            Bs[kf + 0][col] = v.x; Bs[kf + 1][col] = v.y; Bs[kf + 2][col] = v.z; Bs[kf + 3][col] = v.w;
        }
        __syncthreads();
        #pragma unroll
        for (int kk = 0; kk < 32; ++kk) {
            float4 a4 = *(const float4*)&As[kk][ty << 2];
            float4 b4 = *(const float4*)&Bs[kk][tx << 2];
            float a[4] = {a4.x, a4.y, a4.z, a4.w};
            float b[4] = {b4.x, b4.y, b4.z, b4.w};
            #pragma unroll
            for (int i = 0; i < 4; ++i)
                #pragma unroll
                for (int j = 0; j < 4; ++j)
                    acc[i][j] = fmaf(a[i], b[j], acc[i][j]);
        }
        __syncthreads();
    }
    #pragma unroll
    for (int i = 0; i < 4; ++i) {
        int row = m0 + (ty << 2) + i;
        if (row >= M) continue;
        #pragma unroll
        for (int j = 0; j < 4; ++j) {
            int col = n0 + (tx << 2) + j;
            if (col >= N) continue;
            float v = acc[i][j];
            if (bias) v += bias[col];
            if (act == 1) v = fmaxf(v, 0.f);
            else if (act == 2) v = (v > 0.f) ? v : expm1f(v);
            C[(size_t)row * ldc + coff + col] = v;
        }
    }
}

// ================= converts =================
__global__ __launch_bounds__(256) void conv_flat_kernel(const float* __restrict__ in, u16* __restrict__ out, int n) {
    int i = (blockIdx.x * 256 + threadIdx.x) * 4;
    if (i >= n) return;
    float4 v = *(const float4*)(in + i);
    *(uint2*)(out + i) = make_uint2(pk2(v.x, v.y), pk2(v.z, v.w));
}
__global__ __launch_bounds__(256) void conv_gcnw_kernel(const float* __restrict__ w, u16* __restrict__ out) {
    int idx = blockIdx.x * 256 + threadIdx.x;   // 0..65535
    int l = blockIdx.y;
    int k = idx >> 8, n = idx & 255;
    out[(size_t)l * 65536 + n * 256 + k] = f2b(w[(size_t)l * 65536 + k * 256 + n]);
}
// gt_wr [8][256 n][256 k] -> frag-major wrN: [(l*16+gn)*8+kc] frags of 64 lanes x 16B
__global__ __launch_bounds__(256) void conv_wrN_kernel(const float* __restrict__ w, u16* __restrict__ out) {
    int idx = blockIdx.x * 256 + threadIdx.x;    // 0..65535
    int lane = idx & 63;
    int kc = (idx >> 6) & 7;
    int gn = (idx >> 9) & 15;
    int l = idx >> 13;
    int row = gn * 16 + (lane & 15);
    int k0 = kc * 32 + (lane >> 4) * 8;
    const float* src = w + ((size_t)l * 256 + row) * 256 + k0;
    float4 v0 = *(const float4*)src;
    float4 v1 = *(const float4*)(src + 4);
    uint4 pk;
    pk.x = pk2(v0.x, v0.y); pk.y = pk2(v0.z, v0.w);
    pk.z = pk2(v1.x, v1.y); pk.w = pk2(v1.z, v1.w);
    *(uint4*)(out + (size_t)idx * 8) = pk;
}
// gt_wf [8][256 n][256 d] -> wfT2 u32 [8][128 d2][256 n]
__global__ __launch_bounds__(256) void conv_wfT2_kernel(const float* __restrict__ w, u32* __restrict__ out) {
    int idx = blockIdx.x * 256 + threadIdx.x;    // 0..262143
    int n = idx & 255;
    int d2 = (idx >> 8) & 127;
    int l = idx >> 15;
    const float* src = w + ((size_t)l * 256 + n) * 256 + 2 * d2;
    out[idx] = pk2(src[0], src[1]);
}

// ================= CSR build (4 edges/thread, pipelined atomics) =============
#define EDGE_CAP 128
__global__ __launch_bounds__(256) void bucket_fill_kernel(
    const int* __restrict__ src, const int* __restrict__ dst,
    int* __restrict__ ebuf, int* __restrict__ cursor, int* __restrict__ cnt_out, int ne)
{
    int e0 = (blockIdx.x * 256 + threadIdx.x) * 4;
    if (e0 >= ne) return;
    int4 s4 = *(const int4*)(src + e0);
    int4 d4 = *(const int4*)(dst + e0);
    atomicAdd(&cnt_out[s4.x], 1);
    atomicAdd(&cnt_out[s4.y], 1);
    atomicAdd(&cnt_out[s4.z], 1);
    atomicAdd(&cnt_out[s4.w], 1);
    int p0 = atomicAdd(&cursor[d4.x], 1);
    int p1 = atomicAdd(&cursor[d4.y], 1);
    int p2 = atomicAdd(&cursor[d4.z], 1);
    int p3 = atomicAdd(&cursor[d4.w], 1);
    if (p0 < EDGE_CAP) ebuf[(size_t)d4.x * EDGE_CAP + p0] = s4.x;
    if (p1 < EDGE_CAP) ebuf[(size_t)d4.y * EDGE_CAP + p1] = s4.y;
    if (p2 < EDGE_CAP) ebuf[(size_t)d4.z * EDGE_CAP + p2] = s4.z;
    if (p3 < EDGE_CAP) ebuf[(size_t)d4.w * EDGE_CAP + p3] = s4.w;
}
__global__ __launch_bounds__(256) void deg_fin_kernel(const int* __restrict__ cnt, float* __restrict__ dinv, int n) {
    int i = blockIdx.x * 256 + threadIdx.x;
    if (i < n) dinv[i] = rsqrtf(fmaxf((float)cnt[i], 1.0f));
}

// ================= CSR aggregate (bf16 in, fp32+bf16 out), 4x unrolled =======
__global__ __launch_bounds__(256) void csr_agg_kernel(
    const u16* __restrict__ x, const int* __restrict__ ebuf,
    const int* __restrict__ deg, float* __restrict__ outf, u16* __restrict__ outb, int nnodes)
{
    int n = blockIdx.x * 4 + (threadIdx.x >> 6);
    if (n >= nnodes) return;
    int lane = threadIdx.x & 63;
    int d = deg[n];
    float dinv = rsqrtf(fmaxf((float)d, 1.0f));
    if (d > EDGE_CAP) d = EDGE_CAP;
    const int* eb = ebuf + (size_t)n * EDGE_CAP;
    const int co = lane << 2;
    float a0 = 0.f, a1 = 0.f, a2 = 0.f, a3 = 0.f;
    int k = 0;
    for (; k + 4 <= d; k += 4) {
        int4 s4 = *(const int4*)(eb + k);
        uint2 va = *(const uint2*)(x + (size_t)s4.x * 256 + co);
        uint2 vb = *(const uint2*)(x + (size_t)s4.y * 256 + co);
        uint2 vc = *(const uint2*)(x + (size_t)s4.z * 256 + co);
        uint2 vd = *(const uint2*)(x + (size_t)s4.w * 256 + co);
        a0 += b2f_lo(va.x) + b2f_lo(vb.x) + b2f_lo(vc.x) + b2f_lo(vd.x);
        a1 += b2f_hi(va.x) + b2f_hi(vb.x) + b2f_hi(vc.x) + b2f_hi(vd.x);
        a2 += b2f_lo(va.y) + b2f_lo(vb.y) + b2f_lo(vc.y) + b2f_lo(vd.y);
        a3 += b2f_hi(va.y) + b2f_hi(vb.y) + b2f_hi(vc.y) + b2f_hi(vd.y);
    }
    for (; k < d; ++k) {
        int s = eb[k];
        uint2 v = *(const uint2*)(x + (size_t)s * 256 + co);
        a0 += b2f_lo(v.x); a1 += b2f_hi(v.x);
        a2 += b2f_lo(v.y); a3 += b2f_hi(v.y);
    }
    a0 = fmaxf(a0 * dinv, 0.f); a1 = fmaxf(a1 * dinv, 0.f);
    a2 = fmaxf(a2 * dinv, 0.f); a3 = fmaxf(a3 * dinv, 0.f);
    *(float4*)(outf + (size_t)n * 256 + co) = make_float4(a0, a1, a2, a3);
    *(uint2*)(outb + (size_t)n * 256 + co) = make_uint2(pk2(a0, a1), pk2(a2, a3));
}

// ================= final =================
__global__ __launch_bounds__(256) void final_kernel(
    const float* __restrict__ m2, const float* __restrict__ w3,
    const float* __restrict__ b3, float* __restrict__ out, int nrows)
{
    int row = blockIdx.x * 4 + (threadIdx.x >> 6);
    int lane = threadIdx.x & 63;
    if (row >= nrows) return;
    float s = m2[(size_t)row * 128 + lane] * w3[lane]
            + m2[(size_t)row * 128 + 64 + lane] * w3[64 + lane];
    s = wave_sum(s);
    if (lane == 0) out[row] = 1.f / (1.f + expf(-(s + b3[0])));
}

static inline int cdiv(int a, int b) { return (a + b - 1) / b; }

extern "C" void kernel_launch(void* const* d_in, const int* in_sizes, int n_in,
                              void* d_out, int out_size, void* d_ws, size_t ws_size,
                              hipStream_t stream)
{
    const float* feat0   = (const float*)d_in[0];
    const float* feat1   = (const float*)d_in[1];
    const float* fc_w0   = (const float*)d_in[2];
    const float* fc_b0   = (const float*)d_in[3];
    const float* fc_w1   = (const float*)d_in[4];
    const float* fc_b1   = (const float*)d_in[5];
    const float* gcn_w   = (const float*)d_in[6];
    const int*   edge_src= (const int*)d_in[7];
    const int*   edge_dst= (const int*)d_in[8];
    const int*   dg_seqs = (const int*)d_in[9];
    const int*   pt_seqs = (const int*)d_in[10];
    // 11 type_emb, 12 node_type: dead; 13 gt_wl, 15 gt_al: dead (softmax cancellation)
    const float* gt_wr   = (const float*)d_in[14];
    const float* gt_ar   = (const float*)d_in[16];
    const float* gt_wf   = (const float*)d_in[17];
    const float* ln_g    = (const float*)d_in[18];
    const float* ln_b    = (const float*)d_in[19];
    const float* proj_d_w= (const float*)d_in[20];
    const float* proj_d_b= (const float*)d_in[21];
    const float* proj_p_w= (const float*)d_in[22];
    const float* proj_p_b= (const float*)d_in[23];
    const float* ml_w1   = (const float*)d_in[24];
    const float* ml_b1   = (const float*)d_in[25];
    const float* ml_w2   = (const float*)d_in[26];
    const float* ml_b2   = (const float*)d_in[27];
    const float* ml_w3   = (const float*)d_in[28];
    const float* ml_b3   = (const float*)d_in[29];
    float* out = (float*)d_out;

    // ---- workspace layout (f32 units) ----
    float* base  = (float*)d_ws;
    float* gh    = base;                      // 10,240,000
    float* gcnR  = gh + 10240000;             // GCN-phase region (15,440,000)
    float* dego  = gcnR + 15440000;           // 40,000
    float* embT  = dego + 40000;              // 524,288 (both types)
    float* t1    = embT + 524288;             // 524,288 (both types)
    float* mx    = t1 + 524288;               // 524,288
    float* m1    = mx + 524288;               // 262,144
    float* m2    = m1 + 262144;               // 131,072
    float* wreg  = m2 + 131072;               // converted weights

    u16* tmp_b   = (u16*)gcnR;                        // 10,240,000 bf16
    int* ebuf    = (int*)(gcnR + 5120000);            // 5,120,000 int
    int* cursor  = ebuf + (size_t)40000 * EDGE_CAP;   // 40,000
    int* cnt_out = cursor + 40000;                    // 40,000
    u16* gh_b    = (u16*)(gcnR + 10320000);           // 10,240,000 bf16

    u16* fcw_b   = (u16*)wreg;                // 262,144 u16
    u16* gcnw_b  = fcw_b + 262144;            // 131,072 u16
    u16* wrN     = gcnw_b + 131072;           // 524,288 u16 (8 layers x 65,536)
    u32* wfT2    = (u32*)(wrN + 524288);      // 262,144 u32 (8 layers x 32,768)

    // ---- weight converts ----
    conv_flat_kernel<<<cdiv(131072 / 4, 256), 256, 0, stream>>>(fc_w0, fcw_b, 131072);
    conv_flat_kernel<<<cdiv(131072 / 4, 256), 256, 0, stream>>>(fc_w1, fcw_b + 131072, 131072);
    conv_gcnw_kernel<<<dim3(256, 2), 256, 0, stream>>>(gcn_w, gcnw_b);
    conv_wrN_kernel<<<256, 256, 0, stream>>>(gt_wr, wrN);
    conv_wfT2_kernel<<<1024, 256, 0, stream>>>(gt_wf, wfT2);

    // ---- FC projections (merged dual GEMM via blockIdx.z) -> gh_b ----
    mfma_gemm_kernel<true><<<dim3(2, cdiv(20000, 64), 2), 256, 0, stream>>>(
        feat0, fcw_b, fc_b0, nullptr, gh_b, 20000, 256, 512,
        feat1, fcw_b + 131072, fc_b1, gh_b + (size_t)20000 * 256);

    // ---- CSR build (once) ----
    hipMemsetAsync(cursor, 0, 80000 * sizeof(int), stream);
    bucket_fill_kernel<<<625, 256, 0, stream>>>(edge_src, edge_dst, ebuf, cursor, cnt_out, 640000);
    deg_fin_kernel<<<cdiv(40000, 256), 256, 0, stream>>>(cnt_out, dego, 40000);

    // ---- 2x GCN ----
    for (int l = 0; l < 2; ++l) {
        mfma_gemm_kernel<false><<<dim3(2, cdiv(40000, 64), 1), 256, 0, stream>>>(
            gh_b, gcnw_b + (size_t)l * 65536, nullptr, dego, tmp_b, 40000, 256, 256,
            gh_b, gcnw_b, nullptr, tmp_b);
        csr_agg_kernel<<<10000, 256, 0, stream>>>(tmp_b, ebuf, cursor, gh, gh_b, 40000);
    }

    // ---- mega-fused graph transformer, both types in one dispatch ----
    fused_transformer_kernel<<<2048, 512, 0, stream>>>(
        gh, dg_seqs, pt_seqs, wrN, wfT2, gt_ar, ln_g, ln_b, embT);

    // ---- proj heads (both types per dispatch via blockIdx.z) ----
    gemm_kernel<true><<<dim3(4, 16, 2), 256, 0, stream>>>(
        embT, proj_d_w, proj_d_b, nullptr, t1, 1024, 256, 256, 256, 256, 256, 0, 2,
        embT + 262144, proj_p_w, proj_p_b, t1 + 262144, 0);
    gemm_kernel<true><<<dim3(4, 16, 2), 256, 0, stream>>>(
        t1, proj_d_w + 65536, proj_d_b + 256, nullptr, mx, 1024, 256, 256, 256, 256, 512, 0, 0,
        t1 + 262144, proj_p_w + 65536, proj_p_b + 256, mx, 256);

    // ---- predict MLP ----
    gemm_kernel<true><<<dim3(4, 16, 1), 256, 0, stream>>>(
        mx, ml_w1, ml_b1, nullptr, m1, 1024, 256, 512, 512, 512, 256, 0, 1,
        mx, ml_w1, ml_b1, m1, 0);
    gemm_kernel<true><<<dim3(2, 16, 1), 256, 0, stream>>>(
        m1, ml_w2, ml_b2, nullptr, m2, 1024, 128, 256, 256, 256, 128, 0, 1,
        m1, ml_w2, ml_b2, m2, 0);
    final_kernel<<<256, 256, 0, stream>>>(m2, ml_w3, ml_b3, out, 1024);
}

// Round 9
// 693.359 us; speedup vs baseline: 9.3512x; 1.0031x over previous
//
#include <hip/hip_runtime.h>
#include <hip/hip_bf16.h>
#include <math.h>

typedef unsigned int u32;
typedef unsigned short u16;
typedef __attribute__((ext_vector_type(8))) short bf16x8;
typedef __attribute__((ext_vector_type(4))) float f32x4;

__device__ __forceinline__ float b2f(u16 u) { union { u32 i; float f; } c; c.i = ((u32)u) << 16; return c.f; }
__device__ __forceinline__ u16 f2b(float f) { __hip_bfloat16 h = __float2bfloat16(f); u16 r; __builtin_memcpy(&r, &h, 2); return r; }
__device__ __forceinline__ float b2f_lo(u32 w) { union { u32 i; float f; } c; c.i = w << 16; return c.f; }
__device__ __forceinline__ float b2f_hi(u32 w) { union { u32 i; float f; } c; c.i = w & 0xffff0000u; return c.f; }
__device__ __forceinline__ u32 pk2(float a, float b) { return (u32)f2b(a) | ((u32)f2b(b) << 16); }

__device__ __forceinline__ float wave_sum(float v) {
    #pragma unroll
    for (int off = 32; off > 0; off >>= 1) v += __shfl_xor(v, off, 64);
    return v;
}

// ================= bf16 MFMA GEMM (64x128 tile, 4 waves of 32x64) ============
template<bool AF32>
__global__ __launch_bounds__(256) void mfma_gemm_kernel(
    const void* __restrict__ Av, const u16* __restrict__ B,
    const float* __restrict__ bias, const float* __restrict__ rowscale,
    u16* __restrict__ Cb, int M, int N, int K,
    const void* __restrict__ Av1, const u16* __restrict__ B1,
    const float* __restrict__ bias1, u16* __restrict__ Cb1)
{
    if (blockIdx.z) { Av = Av1; B = B1; bias = bias1; Cb = Cb1; }
    __shared__ u16 lds[(64 + 128) * 64];   // A bytes [0,8192), B bytes [8192,24576)
    const int tid = threadIdx.x;
    const int wid = tid >> 6, lane = tid & 63;
    const int wr = wid >> 1, wc = wid & 1;
    const int m0 = blockIdx.y * 64, n0 = blockIdx.x * 128;

    f32x4 acc[2][4] = {};

    for (int k0 = 0; k0 < K; k0 += 64) {
        #pragma unroll
        for (int s = 0; s < 2; ++s) {
            int idx = tid + s * 256;
            int row = idx >> 3, g = idx & 7;
            int row_g = m0 + row; if (row_g >= M) row_g = M - 1;
            int swz = ((g << 4) ^ ((row & 7) << 4));
            if (AF32) {
                const float* src = (const float*)Av + (size_t)row_g * K + k0 + g * 8;
                float4 v0 = *(const float4*)src;
                float4 v1 = *(const float4*)(src + 4);
                uint4 pk;
                pk.x = pk2(v0.x, v0.y); pk.y = pk2(v0.z, v0.w);
                pk.z = pk2(v1.x, v1.y); pk.w = pk2(v1.z, v1.w);
                *(uint4*)((char*)lds + row * 128 + swz) = pk;
            } else {
                f32x4 v = *(const f32x4*)((const u16*)Av + (size_t)row_g * K + k0 + g * 8);
                *(f32x4*)((char*)lds + row * 128 + swz) = v;
            }
        }
        #pragma unroll
        for (int s = 0; s < 4; ++s) {
            int idx = tid + s * 256;
            int row = idx >> 3, g = idx & 7;
            int row_g = n0 + row; if (row_g >= N) row_g = N - 1;
            f32x4 v = *(const f32x4*)(B + (size_t)row_g * K + k0 + g * 8);
            *(f32x4*)((char*)lds + 8192 + row * 128 + ((g << 4) ^ ((row & 7) << 4))) = v;
        }
        __syncthreads();
        #pragma unroll
        for (int ks = 0; ks < 2; ++ks) {
            const int off = (ks * 64 + ((lane >> 4) << 4)) ^ ((lane & 7) << 4);
            const int ra = lane & 15;
            bf16x8 af[2], bfr[4];
            #pragma unroll
            for (int i = 0; i < 2; ++i)
                af[i] = *(bf16x8*)((char*)lds + (wr * 32 + i * 16 + ra) * 128 + off);
            #pragma unroll
            for (int j = 0; j < 4; ++j)
                bfr[j] = *(bf16x8*)((char*)lds + 8192 + (wc * 64 + j * 16 + ra) * 128 + off);
            #pragma unroll
            for (int i = 0; i < 2; ++i)
                #pragma unroll
                for (int j = 0; j < 4; ++j)
                    acc[i][j] = __builtin_amdgcn_mfma_f32_16x16x32_bf16(af[i], bfr[j], acc[i][j], 0, 0, 0);
        }
        __syncthreads();
    }

    const int cr = lane >> 4, ccol = lane & 15;
    #pragma unroll
    for (int i = 0; i < 2; ++i) {
        #pragma unroll
        for (int j = 0; j < 4; ++j) {
            int colg = n0 + wc * 64 + j * 16 + ccol;
            if (colg >= N) continue;
            float badd = bias ? bias[colg] : 0.f;
            #pragma unroll
            for (int reg = 0; reg < 4; ++reg) {
                int rowg = m0 + wr * 32 + i * 16 + cr * 4 + reg;
                if (rowg >= M) continue;
                float v = acc[i][j][reg] + badd;
                if (rowscale) v *= rowscale[rowg];
                Cb[(size_t)rowg * N + colg] = f2b(v);
            }
        }
    }
}

// ================= mega-fused 4-layer graph transformer ======================
// Block = 1 sequence (64 rows), 512 threads / 8 waves, both types in one grid.
// 4 barriers/layer: pack | score-adds | ctx | u. p lives in registers (per-g4
// rows), softmax normalization via 4x ds_read_b128 + 2 shuffles + 16 expf.
__global__ __launch_bounds__(512, 4) void fused_transformer_kernel(
    const float* __restrict__ gh, const int* __restrict__ dg_seqs,
    const int* __restrict__ pt_seqs,
    const u16* __restrict__ wrN,   // [8][16 gn][8 kc][64 lane][8] bf16
    const u32* __restrict__ wfT2,  // [8][128 d2][256 n] packed bf16 pairs
    const float* __restrict__ ar,  // [8][128]
    const float* __restrict__ lng, const float* __restrict__ lnb,  // [8][256]
    float* __restrict__ embT)      // [2048,256]
{
    __shared__ u16 ldsA[64 * 256];       // 32KB: [c:4][row:64][128B swizzled]
    __shared__ float scoreH[2][64];      // per-head accumulated scores
    __shared__ float ctxS[256];
    __shared__ float uS[2][256];

    const int tid = threadIdx.x;
    const int bx = blockIdx.x;
    const int t = bx >> 10, s = bx & 1023;
    const int r = tid >> 3, o8 = tid & 7;        // row 0..63, col-octant 0..7
    const int wid = tid >> 6, lane = tid & 63;
    const int hd = wid >> 2;                     // head (waves 0-3 / 4-7)
    const int g4 = lane >> 4, cl = lane & 15;

    const int* seqs = t ? pt_seqs : dg_seqs;

    // ---- gather h0 (thread's 32 cols of its row) ----
    float4 y[8];
    {
        int node = seqs[s * 64 + r];
        const float* src = gh + (size_t)node * 256 + o8 * 32;
        #pragma unroll
        for (int v = 0; v < 8; ++v) y[v] = *(const float4*)(src + v * 4);
    }

    for (int l = 0; l < 4; ++l) {
        const int li = t * 4 + l;
        // ---- pack y -> swizzled bf16 A-LDS; zero scoreH ----
        {
            const int c = o8 >> 1, gb = (o8 & 1) * 4;
            #pragma unroll
            for (int gg = 0; gg < 4; ++gg) {
                float4 a = y[2 * gg], b = y[2 * gg + 1];
                uint4 pk;
                pk.x = pk2(a.x, a.y); pk.y = pk2(a.z, a.w);
                pk.z = pk2(b.x, b.y); pk.w = pk2(b.z, b.w);
                int g = gb + gg;
                *(uint4*)((char*)ldsA + c * 8192 + r * 128 + ((g << 4) ^ ((r & 7) << 4))) = pk;
            }
            if (tid < 128) ((float*)scoreH)[tid] = 0.f;
        }
        __syncthreads();   // B1

        // ---- fr = h @ wr^T : wave wid -> cols wid*32..+31, rows 0..63 ----
        f32x4 acc[4][2] = {};
        {
            const u16* wrl = wrN + (size_t)li * 65536;
            const int ra = lane & 15;
            #pragma unroll
            for (int kc = 0; kc < 8; ++kc) {
                const int c = kc >> 1, ks = kc & 1;
                const int off = (ks * 64 + ((lane >> 4) << 4)) ^ ((lane & 7) << 4);
                bf16x8 af[4], bfr[2];
                #pragma unroll
                for (int i = 0; i < 4; ++i)
                    af[i] = *(bf16x8*)((char*)ldsA + c * 8192 + (i * 16 + ra) * 128 + off);
                #pragma unroll
                for (int j = 0; j < 2; ++j)
                    bfr[j] = *(const bf16x8*)(wrl + ((size_t)((wid * 2 + j) * 8 + kc) << 9) + lane * 8);
                #pragma unroll
                for (int i = 0; i < 4; ++i)
                    #pragma unroll
                    for (int j = 0; j < 2; ++j)
                        acc[i][j] = __builtin_amdgcn_mfma_f32_16x16x32_bf16(af[i], bfr[j], acc[i][j], 0, 0, 0);
            }
        }

        // ---- scores over this wave's 32 cols -> atomic add into scoreH[hd] --
        {
            const float* arl = ar + li * 128;
            float arj[2];
            #pragma unroll
            for (int j = 0; j < 2; ++j) arj[j] = arl[(wid & 3) * 32 + j * 16 + cl];
            #pragma unroll
            for (int i = 0; i < 4; ++i)
                #pragma unroll
                for (int reg = 0; reg < 4; ++reg) {
                    float sc;
                    {
                        float x0 = acc[i][0][reg], x1 = acc[i][1][reg];
                        sc = (x0 >= 0.f ? x0 : 0.01f * x0) * arj[0]
                           + (x1 >= 0.f ? x1 : 0.01f * x1) * arj[1];
                    }
                    sc += __shfl_xor(sc, 1, 64);
                    sc += __shfl_xor(sc, 2, 64);
                    sc += __shfl_xor(sc, 4, 64);
                    sc += __shfl_xor(sc, 8, 64);
                    if (cl == 0) atomicAdd(&scoreH[hd][i * 16 + g4 * 4 + reg], sc);
                }
        }
        __syncthreads();   // B2

        // ---- softmax in-register: lane's 16 rows depend only on g4 ----
        float p[4][4];
        {
            const float* sc = scoreH[hd];
            #pragma unroll
            for (int i = 0; i < 4; ++i)
                *(float4*)p[i] = *(const float4*)(sc + i * 16 + g4 * 4);
            float mx = -1e30f;
            #pragma unroll
            for (int i = 0; i < 4; ++i)
                #pragma unroll
                for (int reg = 0; reg < 4; ++reg) mx = fmaxf(mx, p[i][reg]);
            mx = fmaxf(mx, __shfl_xor(mx, 16, 64));
            mx = fmaxf(mx, __shfl_xor(mx, 32, 64));
            float sme = 0.f;
            #pragma unroll
            for (int i = 0; i < 4; ++i)
                #pragma unroll
                for (int reg = 0; reg < 4; ++reg) {
                    p[i][reg] = expf(p[i][reg] - mx);
                    sme += p[i][reg];
                }
            sme += __shfl_xor(sme, 16, 64);
            sme += __shfl_xor(sme, 32, 64);
            float inv = 1.f / sme;
            #pragma unroll
            for (int i = 0; i < 4; ++i)
                #pragma unroll
                for (int reg = 0; reg < 4; ++reg) p[i][reg] *= inv;
        }

        // ---- ctx over wave's 32 cols ----
        {
            #pragma unroll
            for (int j = 0; j < 2; ++j) {
                float c = 0.f;
                #pragma unroll
                for (int i = 0; i < 4; ++i)
                    #pragma unroll
                    for (int reg = 0; reg < 4; ++reg)
                        c = fmaf(p[i][reg], acc[i][j][reg], c);
                c += __shfl_xor(c, 16, 64);
                c += __shfl_xor(c, 32, 64);
                if (g4 == 0) ctxS[wid * 32 + j * 16 + cl] = c;
            }
        }
        __syncthreads();   // B3

        // ---- u[n] = sum_d ctx[d]*wf[n][d]; 4 accumulators, deep load flight --
        {
            const int n = tid & 255, half = tid >> 8;
            const u32* wp = wfT2 + (size_t)li * 32768 + (size_t)half * 16384 + n;
            const float* cx = ctxS + half * 128;
            float ua0 = 0.f, ua1 = 0.f, ua2 = 0.f, ua3 = 0.f;
            #pragma unroll 4
            for (int d2 = 0; d2 < 64; d2 += 4) {
                u32 w0 = wp[(size_t)(d2 + 0) * 256];
                u32 w1 = wp[(size_t)(d2 + 1) * 256];
                u32 w2 = wp[(size_t)(d2 + 2) * 256];
                u32 w3 = wp[(size_t)(d2 + 3) * 256];
                ua0 = fmaf(cx[2 * d2 + 0], b2f_lo(w0), ua0);
                ua0 = fmaf(cx[2 * d2 + 1], b2f_hi(w0), ua0);
                ua1 = fmaf(cx[2 * d2 + 2], b2f_lo(w1), ua1);
                ua1 = fmaf(cx[2 * d2 + 3], b2f_hi(w1), ua1);
                ua2 = fmaf(cx[2 * d2 + 4], b2f_lo(w2), ua2);
                ua2 = fmaf(cx[2 * d2 + 5], b2f_hi(w2), ua2);
                ua3 = fmaf(cx[2 * d2 + 6], b2f_lo(w3), ua3);
                ua3 = fmaf(cx[2 * d2 + 7], b2f_hi(w3), ua3);
            }
            uS[half][n] = (ua0 + ua1) + (ua2 + ua3);
        }
        __syncthreads();   // B4

        // ---- h = LN(h + u) (8 threads per row; shuffle xor 1,2,4) ----
        {
            #pragma unroll
            for (int v = 0; v < 8; ++v) {
                int c0 = o8 * 32 + v * 4;
                float4 u0 = *(const float4*)&uS[0][c0];
                float4 u1 = *(const float4*)&uS[1][c0];
                y[v].x += u0.x + u1.x; y[v].y += u0.y + u1.y;
                y[v].z += u0.z + u1.z; y[v].w += u0.w + u1.w;
            }
            float sm = 0.f, qq = 0.f;
            #pragma unroll
            for (int v = 0; v < 8; ++v) {
                sm += y[v].x + y[v].y + y[v].z + y[v].w;
                qq += y[v].x * y[v].x + y[v].y * y[v].y + y[v].z * y[v].z + y[v].w * y[v].w;
            }
            sm += __shfl_xor(sm, 1, 64); sm += __shfl_xor(sm, 2, 64); sm += __shfl_xor(sm, 4, 64);
            qq += __shfl_xor(qq, 1, 64); qq += __shfl_xor(qq, 2, 64); qq += __shfl_xor(qq, 4, 64);
            float mean = sm * (1.f / 256.f);
            float var = qq * (1.f / 256.f) - mean * mean;
            float inv = rsqrtf(var + 1e-5f);
            const float* gl = lng + li * 256 + o8 * 32;
            const float* bl = lnb + li * 256 + o8 * 32;
            if (l < 3) {
                #pragma unroll
                for (int v = 0; v < 8; ++v) {
                    float4 gv = *(const float4*)(gl + v * 4);
                    float4 bv = *(const float4*)(bl + v * 4);
                    y[v].x = (y[v].x - mean) * inv * gv.x + bv.x;
                    y[v].y = (y[v].y - mean) * inv * gv.y + bv.y;
                    y[v].z = (y[v].z - mean) * inv * gv.z + bv.z;
                    y[v].w = (y[v].w - mean) * inv * gv.w + bv.w;
                }
            } else if (r == 0) {
                float* dst = embT + (size_t)(t * 1024 + s) * 256 + o8 * 32;
                #pragma unroll
                for (int v = 0; v < 8; ++v) {
                    float4 gv = *(const float4*)(gl + v * 4);
                    float4 bv = *(const float4*)(bl + v * 4);
                    float4 o;
                    o.x = (y[v].x - mean) * inv * gv.x + bv.x;
                    o.y = (y[v].y - mean) * inv * gv.y + bv.y;
                    o.z = (y[v].z - mean) * inv * gv.z + bv.z;
                    o.w = (y[v].w - mean) * inv * gv.w + bv.w;
                    *(float4*)(dst + v * 4) = o;
                }
            }
        }
        // no end barrier: next pack's ldsA writes are ordered by B2..B4;
        // scoreH zeroing is ordered by B4 (reads ended before B3).
    }
}

// ================= fp32 tiled GEMM (small M), dual-set via blockIdx.z ========
template<bool BT>
__global__ __launch_bounds__(256) void gemm_kernel(
    const float* __restrict__ A, const float* __restrict__ B,
    const float* __restrict__ bias, const float* __restrict__ rowscale,
    float* __restrict__ C,
    int M, int N, int K, int lda, int ldb, int ldc, int coff, int act,
    const float* __restrict__ A1, const float* __restrict__ B1,
    const float* __restrict__ bias1, float* __restrict__ C1, int coff1)
{
    if (blockIdx.z) { A = A1; B = B1; bias = bias1; C = C1; coff = coff1; }
    __shared__ float As[32][64 + 4];
    __shared__ float Bs[32][64 + 4];
    const int tid = threadIdx.x;
    const int m0 = blockIdx.y * 64;
    const int n0 = blockIdx.x * 64;
    const int ty = tid >> 4, tx = tid & 15;
    float acc[4][4] = {};
    for (int k0 = 0; k0 < K; k0 += 32) {
        #pragma unroll
        for (int r = 0; r < 2; ++r) {
            int f4 = tid + r * 256;
            int arw = f4 >> 3, af = (f4 & 7) << 2;
            float4 v = make_float4(0.f, 0.f, 0.f, 0.f);
            int grow = m0 + arw;
            if (grow < M) {
                v = *(const float4*)(A + (size_t)grow * lda + k0 + af);
                if (rowscale) { float s = rowscale[grow]; v.x *= s; v.y *= s; v.z *= s; v.w *= s; }
            }
            As[af + 0][arw] = v.x; As[af + 1][arw] = v.y; As[af + 2][arw] = v.z; As[af + 3][arw] = v.w;
        }
        #pragma unroll
        for (int r = 0; r < 2; ++r) {
            int f4 = tid + r * 256;
            int col = f4 >> 3, kf = (f4 & 7) << 2;
            float4 v = make_float4(0.f, 0.f, 0.f, 0.f);
            if (n0 + col < N) v = *(const float4*)(B + (size_t)(n0 + col) * ldb + k0 + kf);
            Bs[kf + 0][col] = v.x; Bs[kf + 1][col] = v.y; Bs[kf + 2][col] = v.z; Bs[kf + 3][col] = v.w;
        }
        __syncthreads();
        #pragma unroll
        for (int kk = 0; kk < 32; ++kk) {
            float4 a4 = *(const float4*)&As[kk][ty << 2];
            float4 b4 = *(const float4*)&Bs[kk][tx << 2];
            float a[4] = {a4.x, a4.y, a4.z, a4.w};
            float b[4] = {b4.x, b4.y, b4.z, b4.w};
            #pragma unroll
            for (int i = 0; i < 4; ++i)
                #pragma unroll
                for (int j = 0; j < 4; ++j)
                    acc[i][j] = fmaf(a[i], b[j], acc[i][j]);
        }
        __syncthreads();
    }
    #pragma unroll
    for (int i = 0; i < 4; ++i) {
        int row = m0 + (ty << 2) + i;
        if (row >= M) continue;
        #pragma unroll
        for (int j = 0; j < 4; ++j) {
            int col = n0 + (tx << 2) + j;
            if (col >= N) continue;
            float v = acc[i][j];
            if (bias) v += bias[col];
            if (act == 1) v = fmaxf(v, 0.f);
            else if (act == 2) v = (v > 0.f) ? v : expm1f(v);
            C[(size_t)row * ldc + coff + col] = v;
        }
    }
}

// ================= converts =================
__global__ __launch_bounds__(256) void conv_flat_kernel(const float* __restrict__ in, u16* __restrict__ out, int n) {
    int i = (blockIdx.x * 256 + threadIdx.x) * 4;
    if (i >= n) return;
    float4 v = *(const float4*)(in + i);
    *(uint2*)(out + i) = make_uint2(pk2(v.x, v.y), pk2(v.z, v.w));
}
__global__ __launch_bounds__(256) void conv_gcnw_kernel(const float* __restrict__ w, u16* __restrict__ out) {
    int idx = blockIdx.x * 256 + threadIdx.x;   // 0..65535
    int l = blockIdx.y;
    int k = idx >> 8, n = idx & 255;
    out[(size_t)l * 65536 + n * 256 + k] = f2b(w[(size_t)l * 65536 + k * 256 + n]);
}
// gt_wr [8][256 n][256 k] -> frag-major wrN
__global__ __launch_bounds__(256) void conv_wrN_kernel(const float* __restrict__ w, u16* __restrict__ out) {
    int idx = blockIdx.x * 256 + threadIdx.x;    // 0..65535
    int lane = idx & 63;
    int kc = (idx >> 6) & 7;
    int gn = (idx >> 9) & 15;
    int l = idx >> 13;
    int row = gn * 16 + (lane & 15);
    int k0 = kc * 32 + (lane >> 4) * 8;
    const float* src = w + ((size_t)l * 256 + row) * 256 + k0;
    float4 v0 = *(const float4*)src;
    float4 v1 = *(const float4*)(src + 4);
    uint4 pk;
    pk.x = pk2(v0.x, v0.y); pk.y = pk2(v0.z, v0.w);
    pk.z = pk2(v1.x, v1.y); pk.w = pk2(v1.z, v1.w);
    *(uint4*)(out + (size_t)idx * 8) = pk;
}
// gt_wf [8][256 n][256 d] -> wfT2 u32 [8][128 d2][256 n]
__global__ __launch_bounds__(256) void conv_wfT2_kernel(const float* __restrict__ w, u32* __restrict__ out) {
    int idx = blockIdx.x * 256 + threadIdx.x;    // 0..262143
    int n = idx & 255;
    int d2 = (idx >> 8) & 127;
    int l = idx >> 15;
    const float* src = w + ((size_t)l * 256 + n) * 256 + 2 * d2;
    out[idx] = pk2(src[0], src[1]);
}

// ================= CSR build (4 edges/thread, pipelined atomics) =============
#define EDGE_CAP 128
__global__ __launch_bounds__(256) void bucket_fill_kernel(
    const int* __restrict__ src, const int* __restrict__ dst,
    int* __restrict__ ebuf, int* __restrict__ cursor, int* __restrict__ cnt_out, int ne)
{
    int e0 = (blockIdx.x * 256 + threadIdx.x) * 4;
    if (e0 >= ne) return;
    int4 s4 = *(const int4*)(src + e0);
    int4 d4 = *(const int4*)(dst + e0);
    atomicAdd(&cnt_out[s4.x], 1);
    atomicAdd(&cnt_out[s4.y], 1);
    atomicAdd(&cnt_out[s4.z], 1);
    atomicAdd(&cnt_out[s4.w], 1);
    int p0 = atomicAdd(&cursor[d4.x], 1);
    int p1 = atomicAdd(&cursor[d4.y], 1);
    int p2 = atomicAdd(&cursor[d4.z], 1);
    int p3 = atomicAdd(&cursor[d4.w], 1);
    if (p0 < EDGE_CAP) ebuf[(size_t)d4.x * EDGE_CAP + p0] = s4.x;
    if (p1 < EDGE_CAP) ebuf[(size_t)d4.y * EDGE_CAP + p1] = s4.y;
    if (p2 < EDGE_CAP) ebuf[(size_t)d4.z * EDGE_CAP + p2] = s4.z;
    if (p3 < EDGE_CAP) ebuf[(size_t)d4.w * EDGE_CAP + p3] = s4.w;
}
__global__ __launch_bounds__(256) void deg_fin_kernel(const int* __restrict__ cnt, float* __restrict__ dinv, int n) {
    int i = blockIdx.x * 256 + threadIdx.x;
    if (i < n) dinv[i] = rsqrtf(fmaxf((float)cnt[i], 1.0f));
}

// ================= CSR aggregate (bf16 in, fp32+bf16 out), 4x unrolled =======
__global__ __launch_bounds__(256) void csr_agg_kernel(
    const u16* __restrict__ x, const int* __restrict__ ebuf,
    const int* __restrict__ deg, float* __restrict__ outf, u16* __restrict__ outb, int nnodes)
{
    int n = blockIdx.x * 4 + (threadIdx.x >> 6);
    if (n >= nnodes) return;
    int lane = threadIdx.x & 63;
    int d = deg[n];
    float dinv = rsqrtf(fmaxf((float)d, 1.0f));
    if (d > EDGE_CAP) d = EDGE_CAP;
    const int* eb = ebuf + (size_t)n * EDGE_CAP;
    const int co = lane << 2;
    float a0 = 0.f, a1 = 0.f, a2 = 0.f, a3 = 0.f;
    int k = 0;
    for (; k + 4 <= d; k += 4) {
        int4 s4 = *(const int4*)(eb + k);
        uint2 va = *(const uint2*)(x + (size_t)s4.x * 256 + co);
        uint2 vb = *(const uint2*)(x + (size_t)s4.y * 256 + co);
        uint2 vc = *(const uint2*)(x + (size_t)s4.z * 256 + co);
        uint2 vd = *(const uint2*)(x + (size_t)s4.w * 256 + co);
        a0 += b2f_lo(va.x) + b2f_lo(vb.x) + b2f_lo(vc.x) + b2f_lo(vd.x);
        a1 += b2f_hi(va.x) + b2f_hi(vb.x) + b2f_hi(vc.x) + b2f_hi(vd.x);
        a2 += b2f_lo(va.y) + b2f_lo(vb.y) + b2f_lo(vc.y) + b2f_lo(vd.y);
        a3 += b2f_hi(va.y) + b2f_hi(vb.y) + b2f_hi(vc.y) + b2f_hi(vd.y);
    }
    for (; k < d; ++k) {
        int s = eb[k];
        uint2 v = *(const uint2*)(x + (size_t)s * 256 + co);
        a0 += b2f_lo(v.x); a1 += b2f_hi(v.x);
        a2 += b2f_lo(v.y); a3 += b2f_hi(v.y);
    }
    a0 = fmaxf(a0 * dinv, 0.f); a1 = fmaxf(a1 * dinv, 0.f);
    a2 = fmaxf(a2 * dinv, 0.f); a3 = fmaxf(a3 * dinv, 0.f);
    *(float4*)(outf + (size_t)n * 256 + co) = make_float4(a0, a1, a2, a3);
    *(uint2*)(outb + (size_t)n * 256 + co) = make_uint2(pk2(a0, a1), pk2(a2, a3));
}

// ================= final =================
__global__ __launch_bounds__(256) void final_kernel(
    const float* __restrict__ m2, const float* __restrict__ w3,
    const float* __restrict__ b3, float* __restrict__ out, int nrows)
{
    int row = blockIdx.x * 4 + (threadIdx.x >> 6);
    int lane = threadIdx.x & 63;
    if (row >= nrows) return;
    float s = m2[(size_t)row * 128 + lane] * w3[lane]
            + m2[(size_t)row * 128 + 64 + lane] * w3[64 + lane];
    s = wave_sum(s);
    if (lane == 0) out[row] = 1.f / (1.f + expf(-(s + b3[0])));
}

static inline int cdiv(int a, int b) { return (a + b - 1) / b; }

extern "C" void kernel_launch(void* const* d_in, const int* in_sizes, int n_in,
                              void* d_out, int out_size, void* d_ws, size_t ws_size,
                              hipStream_t stream)
{
    const float* feat0   = (const float*)d_in[0];
    const float* feat1   = (const float*)d_in[1];
    const float* fc_w0   = (const float*)d_in[2];
    const float* fc_b0   = (const float*)d_in[3];
    const float* fc_w1   = (const float*)d_in[4];
    const float* fc_b1   = (const float*)d_in[5];
    const float* gcn_w   = (const float*)d_in[6];
    const int*   edge_src= (const int*)d_in[7];
    const int*   edge_dst= (const int*)d_in[8];
    const int*   dg_seqs = (const int*)d_in[9];
    const int*   pt_seqs = (const int*)d_in[10];
    // 11 type_emb, 12 node_type: dead; 13 gt_wl, 15 gt_al: dead (softmax cancellation)
    const float* gt_wr   = (const float*)d_in[14];
    const float* gt_ar   = (const float*)d_in[16];
    const float* gt_wf   = (const float*)d_in[17];
    const float* ln_g    = (const float*)d_in[18];
    const float* ln_b    = (const float*)d_in[19];
    const float* proj_d_w= (const float*)d_in[20];
    const float* proj_d_b= (const float*)d_in[21];
    const float* proj_p_w= (const float*)d_in[22];
    const float* proj_p_b= (const float*)d_in[23];
    const float* ml_w1   = (const float*)d_in[24];
    const float* ml_b1   = (const float*)d_in[25];
    const float* ml_w2   = (const float*)d_in[26];
    const float* ml_b2   = (const float*)d_in[27];
    const float* ml_w3   = (const float*)d_in[28];
    const float* ml_b3   = (const float*)d_in[29];
    float* out = (float*)d_out;

    // ---- workspace layout (f32 units) ----
    float* base  = (float*)d_ws;
    float* gh    = base;                      // 10,240,000
    float* gcnR  = gh + 10240000;             // GCN-phase region (15,440,000)
    float* dego  = gcnR + 15440000;           // 40,000
    float* embT  = dego + 40000;              // 524,288 (both types)
    float* t1    = embT + 524288;             // 524,288 (both types)
    float* mx    = t1 + 524288;               // 524,288
    float* m1    = mx + 524288;               // 262,144
    float* m2    = m1 + 262144;               // 131,072
    float* wreg  = m2 + 131072;               // converted weights

    u16* tmp_b   = (u16*)gcnR;                        // 10,240,000 bf16
    int* ebuf    = (int*)(gcnR + 5120000);            // 5,120,000 int
    int* cursor  = ebuf + (size_t)40000 * EDGE_CAP;   // 40,000
    int* cnt_out = cursor + 40000;                    // 40,000
    u16* gh_b    = (u16*)(gcnR + 10320000);           // 10,240,000 bf16

    u16* fcw_b   = (u16*)wreg;                // 262,144 u16
    u16* gcnw_b  = fcw_b + 262144;            // 131,072 u16
    u16* wrN     = gcnw_b + 131072;           // 524,288 u16 (8 layers x 65,536)
    u32* wfT2    = (u32*)(wrN + 524288);      // 262,144 u32 (8 layers x 32,768)

    // ---- weight converts ----
    conv_flat_kernel<<<cdiv(131072 / 4, 256), 256, 0, stream>>>(fc_w0, fcw_b, 131072);
    conv_flat_kernel<<<cdiv(131072 / 4, 256), 256, 0, stream>>>(fc_w1, fcw_b + 131072, 131072);
    conv_gcnw_kernel<<<dim3(256, 2), 256, 0, stream>>>(gcn_w, gcnw_b);
    conv_wrN_kernel<<<256, 256, 0, stream>>>(gt_wr, wrN);
    conv_wfT2_kernel<<<1024, 256, 0, stream>>>(gt_wf, wfT2);

    // ---- FC projections (merged dual GEMM via blockIdx.z) -> gh_b ----
    mfma_gemm_kernel<true><<<dim3(2, cdiv(20000, 64), 2), 256, 0, stream>>>(
        feat0, fcw_b, fc_b0, nullptr, gh_b, 20000, 256, 512,
        feat1, fcw_b + 131072, fc_b1, gh_b + (size_t)20000 * 256);

    // ---- CSR build (once) ----
    hipMemsetAsync(cursor, 0, 80000 * sizeof(int), stream);
    bucket_fill_kernel<<<625, 256, 0, stream>>>(edge_src, edge_dst, ebuf, cursor, cnt_out, 640000);
    deg_fin_kernel<<<cdiv(40000, 256), 256, 0, stream>>>(cnt_out, dego, 40000);

    // ---- 2x GCN ----
    for (int l = 0; l < 2; ++l) {
        mfma_gemm_kernel<false><<<dim3(2, cdiv(40000, 64), 1), 256, 0, stream>>>(
            gh_b, gcnw_b + (size_t)l * 65536, nullptr, dego, tmp_b, 40000, 256, 256,
            gh_b, gcnw_b, nullptr, tmp_b);
        csr_agg_kernel<<<10000, 256, 0, stream>>>(tmp_b, ebuf, cursor, gh, gh_b, 40000);
    }

    // ---- mega-fused graph transformer, both types in one dispatch ----
    fused_transformer_kernel<<<2048, 512, 0, stream>>>(
        gh, dg_seqs, pt_seqs, wrN, wfT2, gt_ar, ln_g, ln_b, embT);

    // ---- proj heads (both types per dispatch via blockIdx.z) ----
    gemm_kernel<true><<<dim3(4, 16, 2), 256, 0, stream>>>(
        embT, proj_d_w, proj_d_b, nullptr, t1, 1024, 256, 256, 256, 256, 256, 0, 2,
        embT + 262144, proj_p_w, proj_p_b, t1 + 262144, 0);
    gemm_kernel<true><<<dim3(4, 16, 2), 256, 0, stream>>>(
        t1, proj_d_w + 65536, proj_d_b + 256, nullptr, mx, 1024, 256, 256, 256, 256, 512, 0, 0,
        t1 + 262144, proj_p_w + 65536, proj_p_b + 256, mx, 256);

    // ---- predict MLP ----
    gemm_kernel<true><<<dim3(4, 16, 1), 256, 0, stream>>>(
        mx, ml_w1, ml_b1, nullptr, m1, 1024, 256, 512, 512, 512, 256, 0, 1,
        mx, ml_w1, ml_b1, m1, 0);
    gemm_kernel<true><<<dim3(2, 16, 1), 256, 0, stream>>>(
        m1, ml_w2, ml_b2, nullptr, m2, 1024, 128, 256, 256, 256, 128, 0, 1,
        m1, ml_w2, ml_b2, m2, 0);
    final_kernel<<<256, 256, 0, stream>>>(m2, ml_w3, ml_b3, out, 1024);
}

// Round 10
// 651.142 us; speedup vs baseline: 9.9575x; 1.0648x over previous
//
#include <hip/hip_runtime.h>
#include <hip/hip_bf16.h>
#include <math.h>

typedef unsigned int u32;
typedef unsigned short u16;
typedef __attribute__((ext_vector_type(8))) short bf16x8;
typedef __attribute__((ext_vector_type(4))) float f32x4;

__device__ __forceinline__ float b2f(u16 u) { union { u32 i; float f; } c; c.i = ((u32)u) << 16; return c.f; }
__device__ __forceinline__ u16 f2b(float f) { __hip_bfloat16 h = __float2bfloat16(f); u16 r; __builtin_memcpy(&r, &h, 2); return r; }
__device__ __forceinline__ float b2f_lo(u32 w) { union { u32 i; float f; } c; c.i = w << 16; return c.f; }
__device__ __forceinline__ float b2f_hi(u32 w) { union { u32 i; float f; } c; c.i = w & 0xffff0000u; return c.f; }
__device__ __forceinline__ u32 pk2(float a, float b) { return (u32)f2b(a) | ((u32)f2b(b) << 16); }

__device__ __forceinline__ float wave_sum(float v) {
    #pragma unroll
    for (int off = 32; off > 0; off >>= 1) v += __shfl_xor(v, off, 64);
    return v;
}

// ---- DPP reductions (VALU pipe, not LDS pipe) ----
template<int CTRL>
__device__ __forceinline__ float dpp_addf(float v) {
    int y = __builtin_amdgcn_update_dpp(0, __builtin_bit_cast(int, v), CTRL, 0xF, 0xF, true);
    return v + __builtin_bit_cast(float, y);
}
// sum across each 16-lane group; all lanes receive the result
__device__ __forceinline__ float sum16_dpp(float v) {
    v = dpp_addf<0xB1>(v);    // quad_perm [1,0,3,2]  (xor 1)
    v = dpp_addf<0x4E>(v);    // quad_perm [2,3,0,1]  (xor 2)
    v = dpp_addf<0x141>(v);   // row_half_mirror      (cross quads within 8)
    v = dpp_addf<0x140>(v);   // row_mirror           (cross 8-halves within 16)
    return v;
}
// sum across each 8-lane group; all lanes receive the result
__device__ __forceinline__ float sum8_dpp(float v) {
    v = dpp_addf<0xB1>(v);
    v = dpp_addf<0x4E>(v);
    v = dpp_addf<0x141>(v);
    return v;
}

// ================= bf16 MFMA GEMM (64x128 tile, 4 waves of 32x64) ============
template<bool AF32>
__global__ __launch_bounds__(256) void mfma_gemm_kernel(
    const void* __restrict__ Av, const u16* __restrict__ B,
    const float* __restrict__ bias, const float* __restrict__ rowscale,
    u16* __restrict__ Cb, int M, int N, int K,
    const void* __restrict__ Av1, const u16* __restrict__ B1,
    const float* __restrict__ bias1, u16* __restrict__ Cb1)
{
    if (blockIdx.z) { Av = Av1; B = B1; bias = bias1; Cb = Cb1; }
    __shared__ u16 lds[(64 + 128) * 64];   // A bytes [0,8192), B bytes [8192,24576)
    const int tid = threadIdx.x;
    const int wid = tid >> 6, lane = tid & 63;
    const int wr = wid >> 1, wc = wid & 1;
    const int m0 = blockIdx.y * 64, n0 = blockIdx.x * 128;

    f32x4 acc[2][4] = {};

    for (int k0 = 0; k0 < K; k0 += 64) {
        #pragma unroll
        for (int s = 0; s < 2; ++s) {
            int idx = tid + s * 256;
            int row = idx >> 3, g = idx & 7;
            int row_g = m0 + row; if (row_g >= M) row_g = M - 1;
            int swz = ((g << 4) ^ ((row & 7) << 4));
            if (AF32) {
                const float* src = (const float*)Av + (size_t)row_g * K + k0 + g * 8;
                float4 v0 = *(const float4*)src;
                float4 v1 = *(const float4*)(src + 4);
                uint4 pk;
                pk.x = pk2(v0.x, v0.y); pk.y = pk2(v0.z, v0.w);
                pk.z = pk2(v1.x, v1.y); pk.w = pk2(v1.z, v1.w);
                *(uint4*)((char*)lds + row * 128 + swz) = pk;
            } else {
                f32x4 v = *(const f32x4*)((const u16*)Av + (size_t)row_g * K + k0 + g * 8);
                *(f32x4*)((char*)lds + row * 128 + swz) = v;
            }
        }
        #pragma unroll
        for (int s = 0; s < 4; ++s) {
            int idx = tid + s * 256;
            int row = idx >> 3, g = idx & 7;
            int row_g = n0 + row; if (row_g >= N) row_g = N - 1;
            f32x4 v = *(const f32x4*)(B + (size_t)row_g * K + k0 + g * 8);
            *(f32x4*)((char*)lds + 8192 + row * 128 + ((g << 4) ^ ((row & 7) << 4))) = v;
        }
        __syncthreads();
        #pragma unroll
        for (int ks = 0; ks < 2; ++ks) {
            const int off = (ks * 64 + ((lane >> 4) << 4)) ^ ((lane & 7) << 4);
            const int ra = lane & 15;
            bf16x8 af[2], bfr[4];
            #pragma unroll
            for (int i = 0; i < 2; ++i)
                af[i] = *(bf16x8*)((char*)lds + (wr * 32 + i * 16 + ra) * 128 + off);
            #pragma unroll
            for (int j = 0; j < 4; ++j)
                bfr[j] = *(bf16x8*)((char*)lds + 8192 + (wc * 64 + j * 16 + ra) * 128 + off);
            #pragma unroll
            for (int i = 0; i < 2; ++i)
                #pragma unroll
                for (int j = 0; j < 4; ++j)
                    acc[i][j] = __builtin_amdgcn_mfma_f32_16x16x32_bf16(af[i], bfr[j], acc[i][j], 0, 0, 0);
        }
        __syncthreads();
    }

    const int cr = lane >> 4, ccol = lane & 15;
    #pragma unroll
    for (int i = 0; i < 2; ++i) {
        #pragma unroll
        for (int j = 0; j < 4; ++j) {
            int colg = n0 + wc * 64 + j * 16 + ccol;
            if (colg >= N) continue;
            float badd = bias ? bias[colg] : 0.f;
            #pragma unroll
            for (int reg = 0; reg < 4; ++reg) {
                int rowg = m0 + wr * 32 + i * 16 + cr * 4 + reg;
                if (rowg >= M) continue;
                float v = acc[i][j][reg] + badd;
                if (rowscale) v *= rowscale[rowg];
                Cb[(size_t)rowg * N + colg] = f2b(v);
            }
        }
    }
}

// ================= mega-fused 4-layer graph transformer ======================
// Block = 1 sequence (64 rows), 512 threads / 8 waves, both types in one grid.
// 4 barriers/layer. 16/8-lane reductions on the VALU DPP pipe.
__global__ __launch_bounds__(512, 4) void fused_transformer_kernel(
    const float* __restrict__ gh, const int* __restrict__ dg_seqs,
    const int* __restrict__ pt_seqs,
    const u16* __restrict__ wrN,   // [8][16 gn][8 kc][64 lane][8] bf16
    const u32* __restrict__ wfT2,  // [8][128 d2][256 n] packed bf16 pairs
    const float* __restrict__ ar,  // [8][128]
    const float* __restrict__ lng, const float* __restrict__ lnb,  // [8][256]
    float* __restrict__ embT)      // [2048,256]
{
    __shared__ u16 ldsA[64 * 256];       // 32KB: [c:4][row:64][128B swizzled]
    __shared__ float scoreH[2][64];      // per-head accumulated scores
    __shared__ float ctxS[256];
    __shared__ float uS[2][256];

    const int tid = threadIdx.x;
    const int bx = blockIdx.x;
    const int t = bx >> 10, s = bx & 1023;
    const int r = tid >> 3, o8 = tid & 7;        // row 0..63, col-octant 0..7
    const int wid = tid >> 6, lane = tid & 63;
    const int hd = wid >> 2;                     // head (waves 0-3 / 4-7)
    const int g4 = lane >> 4, cl = lane & 15;

    const int* seqs = t ? pt_seqs : dg_seqs;

    // ---- gather h0 (thread's 32 cols of its row) ----
    float4 y[8];
    {
        int node = seqs[s * 64 + r];
        const float* src = gh + (size_t)node * 256 + o8 * 32;
        #pragma unroll
        for (int v = 0; v < 8; ++v) y[v] = *(const float4*)(src + v * 4);
    }

    for (int l = 0; l < 4; ++l) {
        const int li = t * 4 + l;
        // ---- pack y -> swizzled bf16 A-LDS; zero scoreH ----
        {
            const int c = o8 >> 1, gb = (o8 & 1) * 4;
            #pragma unroll
            for (int gg = 0; gg < 4; ++gg) {
                float4 a = y[2 * gg], b = y[2 * gg + 1];
                uint4 pk;
                pk.x = pk2(a.x, a.y); pk.y = pk2(a.z, a.w);
                pk.z = pk2(b.x, b.y); pk.w = pk2(b.z, b.w);
                int g = gb + gg;
                *(uint4*)((char*)ldsA + c * 8192 + r * 128 + ((g << 4) ^ ((r & 7) << 4))) = pk;
            }
            if (tid < 128) ((float*)scoreH)[tid] = 0.f;
        }
        __syncthreads();   // B1

        // ---- fr = h @ wr^T : wave wid -> cols wid*32..+31, rows 0..63 ----
        f32x4 acc[4][2] = {};
        {
            const u16* wrl = wrN + (size_t)li * 65536;
            const int ra = lane & 15;
            #pragma unroll
            for (int kc = 0; kc < 8; ++kc) {
                const int c = kc >> 1, ks = kc & 1;
                const int off = (ks * 64 + ((lane >> 4) << 4)) ^ ((lane & 7) << 4);
                bf16x8 af[4], bfr[2];
                #pragma unroll
                for (int i = 0; i < 4; ++i)
                    af[i] = *(bf16x8*)((char*)ldsA + c * 8192 + (i * 16 + ra) * 128 + off);
                #pragma unroll
                for (int j = 0; j < 2; ++j)
                    bfr[j] = *(const bf16x8*)(wrl + ((size_t)((wid * 2 + j) * 8 + kc) << 9) + lane * 8);
                #pragma unroll
                for (int i = 0; i < 4; ++i)
                    #pragma unroll
                    for (int j = 0; j < 2; ++j)
                        acc[i][j] = __builtin_amdgcn_mfma_f32_16x16x32_bf16(af[i], bfr[j], acc[i][j], 0, 0, 0);
            }
        }

        // ---- scores over this wave's 32 cols -> DPP reduce -> atomicAdd ----
        {
            const float* arl = ar + li * 128;
            float arj[2];
            #pragma unroll
            for (int j = 0; j < 2; ++j) arj[j] = arl[(wid & 3) * 32 + j * 16 + cl];
            #pragma unroll
            for (int i = 0; i < 4; ++i)
                #pragma unroll
                for (int reg = 0; reg < 4; ++reg) {
                    float sc;
                    {
                        float x0 = acc[i][0][reg], x1 = acc[i][1][reg];
                        sc = (x0 >= 0.f ? x0 : 0.01f * x0) * arj[0]
                           + (x1 >= 0.f ? x1 : 0.01f * x1) * arj[1];
                    }
                    sc = sum16_dpp(sc);
                    if (cl == 0) atomicAdd(&scoreH[hd][i * 16 + g4 * 4 + reg], sc);
                }
        }
        __syncthreads();   // B2

        // ---- softmax in-register: lane's 16 rows depend only on g4 ----
        float p[4][4];
        {
            const float* sc = scoreH[hd];
            #pragma unroll
            for (int i = 0; i < 4; ++i)
                *(float4*)p[i] = *(const float4*)(sc + i * 16 + g4 * 4);
            float mx = -1e30f;
            #pragma unroll
            for (int i = 0; i < 4; ++i)
                #pragma unroll
                for (int reg = 0; reg < 4; ++reg) mx = fmaxf(mx, p[i][reg]);
            mx = fmaxf(mx, __shfl_xor(mx, 16, 64));
            mx = fmaxf(mx, __shfl_xor(mx, 32, 64));
            float sme = 0.f;
            #pragma unroll
            for (int i = 0; i < 4; ++i)
                #pragma unroll
                for (int reg = 0; reg < 4; ++reg) {
                    p[i][reg] = __expf(p[i][reg] - mx);
                    sme += p[i][reg];
                }
            sme += __shfl_xor(sme, 16, 64);
            sme += __shfl_xor(sme, 32, 64);
            float inv = 1.f / sme;
            #pragma unroll
            for (int i = 0; i < 4; ++i)
                #pragma unroll
                for (int reg = 0; reg < 4; ++reg) p[i][reg] *= inv;
        }

        // ---- ctx over wave's 32 cols ----
        {
            #pragma unroll
            for (int j = 0; j < 2; ++j) {
                float c = 0.f;
                #pragma unroll
                for (int i = 0; i < 4; ++i)
                    #pragma unroll
                    for (int reg = 0; reg < 4; ++reg)
                        c = fmaf(p[i][reg], acc[i][j][reg], c);
                c += __shfl_xor(c, 16, 64);
                c += __shfl_xor(c, 32, 64);
                if (g4 == 0) ctxS[wid * 32 + j * 16 + cl] = c;
            }
        }
        __syncthreads();   // B3

        // ---- u[n] = sum_d ctx[d]*wf[n][d]; 4 accumulators, deep load flight --
        {
            const int n = tid & 255, half = tid >> 8;
            const u32* wp = wfT2 + (size_t)li * 32768 + (size_t)half * 16384 + n;
            const float* cx = ctxS + half * 128;
            float ua0 = 0.f, ua1 = 0.f, ua2 = 0.f, ua3 = 0.f;
            #pragma unroll 4
            for (int d2 = 0; d2 < 64; d2 += 4) {
                u32 w0 = wp[(size_t)(d2 + 0) * 256];
                u32 w1 = wp[(size_t)(d2 + 1) * 256];
                u32 w2 = wp[(size_t)(d2 + 2) * 256];
                u32 w3 = wp[(size_t)(d2 + 3) * 256];
                ua0 = fmaf(cx[2 * d2 + 0], b2f_lo(w0), ua0);
                ua0 = fmaf(cx[2 * d2 + 1], b2f_hi(w0), ua0);
                ua1 = fmaf(cx[2 * d2 + 2], b2f_lo(w1), ua1);
                ua1 = fmaf(cx[2 * d2 + 3], b2f_hi(w1), ua1);
                ua2 = fmaf(cx[2 * d2 + 4], b2f_lo(w2), ua2);
                ua2 = fmaf(cx[2 * d2 + 5], b2f_hi(w2), ua2);
                ua3 = fmaf(cx[2 * d2 + 6], b2f_lo(w3), ua3);
                ua3 = fmaf(cx[2 * d2 + 7], b2f_hi(w3), ua3);
            }
            uS[half][n] = (ua0 + ua1) + (ua2 + ua3);
        }
        __syncthreads();   // B4

        // ---- h = LN(h + u) (8 threads per row; DPP sum over 8 lanes) ----
        {
            #pragma unroll
            for (int v = 0; v < 8; ++v) {
                int c0 = o8 * 32 + v * 4;
                float4 u0 = *(const float4*)&uS[0][c0];
                float4 u1 = *(const float4*)&uS[1][c0];
                y[v].x += u0.x + u1.x; y[v].y += u0.y + u1.y;
                y[v].z += u0.z + u1.z; y[v].w += u0.w + u1.w;
            }
            float sm = 0.f, qq = 0.f;
            #pragma unroll
            for (int v = 0; v < 8; ++v) {
                sm += y[v].x + y[v].y + y[v].z + y[v].w;
                qq += y[v].x * y[v].x + y[v].y * y[v].y + y[v].z * y[v].z + y[v].w * y[v].w;
            }
            sm = sum8_dpp(sm);
            qq = sum8_dpp(qq);
            float mean = sm * (1.f / 256.f);
            float var = qq * (1.f / 256.f) - mean * mean;
            float inv = rsqrtf(var + 1e-5f);
            const float* gl = lng + li * 256 + o8 * 32;
            const float* bl = lnb + li * 256 + o8 * 32;
            if (l < 3) {
                #pragma unroll
                for (int v = 0; v < 8; ++v) {
                    float4 gv = *(const float4*)(gl + v * 4);
                    float4 bv = *(const float4*)(bl + v * 4);
                    y[v].x = (y[v].x - mean) * inv * gv.x + bv.x;
                    y[v].y = (y[v].y - mean) * inv * gv.y + bv.y;
                    y[v].z = (y[v].z - mean) * inv * gv.z + bv.z;
                    y[v].w = (y[v].w - mean) * inv * gv.w + bv.w;
                }
            } else if (r == 0) {
                float* dst = embT + (size_t)(t * 1024 + s) * 256 + o8 * 32;
                #pragma unroll
                for (int v = 0; v < 8; ++v) {
                    float4 gv = *(const float4*)(gl + v * 4);
                    float4 bv = *(const float4*)(bl + v * 4);
                    float4 o;
                    o.x = (y[v].x - mean) * inv * gv.x + bv.x;
                    o.y = (y[v].y - mean) * inv * gv.y + bv.y;
                    o.z = (y[v].z - mean) * inv * gv.z + bv.z;
                    o.w = (y[v].w - mean) * inv * gv.w + bv.w;
                    *(float4*)(dst + v * 4) = o;
                }
            }
        }
        // no end barrier: ordering provided by B2..B4 (see round-8 analysis)
    }
}

// ================= fp32 tiled GEMM (small M), dual-set via blockIdx.z ========
template<bool BT>
__global__ __launch_bounds__(256) void gemm_kernel(
    const float* __restrict__ A, const float* __restrict__ B,
    const float* __restrict__ bias, const float* __restrict__ rowscale,
    float* __restrict__ C,
    int M, int N, int K, int lda, int ldb, int ldc, int coff, int act,
    const float* __restrict__ A1, const float* __restrict__ B1,
    const float* __restrict__ bias1, float* __restrict__ C1, int coff1)
{
    if (blockIdx.z) { A = A1; B = B1; bias = bias1; C = C1; coff = coff1; }
    __shared__ float As[32][64 + 4];
    __shared__ float Bs[32][64 + 4];
    const int tid = threadIdx.x;
    const int m0 = blockIdx.y * 64;
    const int n0 = blockIdx.x * 64;
    const int ty = tid >> 4, tx = tid & 15;
    float acc[4][4] = {};
    for (int k0 = 0; k0 < K; k0 += 32) {
        #pragma unroll
        for (int r = 0; r < 2; ++r) {
            int f4 = tid + r * 256;
            int arw = f4 >> 3, af = (f4 & 7) << 2;
            float4 v = make_float4(0.f, 0.f, 0.f, 0.f);
            int grow = m0 + arw;
            if (grow < M) {
                v = *(const float4*)(A + (size_t)grow * lda + k0 + af);
                if (rowscale) { float s = rowscale[grow]; v.x *= s; v.y *= s; v.z *= s; v.w *= s; }
            }
            As[af + 0][arw] = v.x; As[af + 1][arw] = v.y; As[af + 2][arw] = v.z; As[af + 3][arw] = v.w;
        }
        #pragma unroll
        for (int r = 0; r < 2; ++r) {
            int f4 = tid + r * 256;
            int col = f4 >> 3, kf = (f4 & 7) << 2;
            float4 v = make_float4(0.f, 0.f, 0.f, 0.f);
            if (n0 + col < N) v = *(const float4*)(B + (size_t)(n0 + col) * ldb + k0 + kf);
            Bs[kf + 0][col] = v.x; Bs[kf + 1][col] = v.y; Bs[kf + 2][col] = v.z; Bs[kf + 3][col] = v.w;
        }
        __syncthreads();
        #pragma unroll
        for (int kk = 0; kk < 32; ++kk) {
            float4 a4 = *(const float4*)&As[kk][ty << 2];
            float4 b4 = *(const float4*)&Bs[kk][tx << 2];
            float a[4] = {a4.x, a4.y, a4.z, a4.w};
            float b[4] = {b4.x, b4.y, b4.z, b4.w};
            #pragma unroll
            for (int i = 0; i < 4; ++i)
                #pragma unroll
                for (int j = 0; j < 4; ++j)
                    acc[i][j] = fmaf(a[i], b[j], acc[i][j]);
        }
        __syncthreads();
    }
    #pragma unroll
    for (int i = 0; i < 4; ++i) {
        int row = m0 + (ty << 2) + i;
        if (row >= M) continue;
        #pragma unroll
        for (int j = 0; j < 4; ++j) {
            int col = n0 + (tx << 2) + j;
            if (col >= N) continue;
            float v = acc[i][j];
            if (bias) v += bias[col];
            if (act == 1) v = fmaxf(v, 0.f);
            else if (act == 2) v = (v > 0.f) ? v : expm1f(v);
            C[(size_t)row * ldc + coff + col] = v;
        }
    }
}

// ================= converts =================
__global__ __launch_bounds__(256) void conv_flat_kernel(const float* __restrict__ in, u16* __restrict__ out, int n) {
    int i = (blockIdx.x * 256 + threadIdx.x) * 4;
    if (i >= n) return;
    float4 v = *(const float4*)(in + i);
    *(uint2*)(out + i) = make_uint2(pk2(v.x, v.y), pk2(v.z, v.w));
}
__global__ __launch_bounds__(256) void conv_gcnw_kernel(const float* __restrict__ w, u16* __restrict__ out) {
    int idx = blockIdx.x * 256 + threadIdx.x;   // 0..65535
    int l = blockIdx.y;
    int k = idx >> 8, n = idx & 255;
    out[(size_t)l * 65536 + n * 256 + k] = f2b(w[(size_t)l * 65536 + k * 256 + n]);
}
// gt_wr [8][256 n][256 k] -> frag-major wrN
__global__ __launch_bounds__(256) void conv_wrN_kernel(const float* __restrict__ w, u16* __restrict__ out) {
    int idx = blockIdx.x * 256 + threadIdx.x;    // 0..65535
    int lane = idx & 63;
    int kc = (idx >> 6) & 7;
    int gn = (idx >> 9) & 15;
    int l = idx >> 13;
    int row = gn * 16 + (lane & 15);
    int k0 = kc * 32 + (lane >> 4) * 8;
    const float* src = w + ((size_t)l * 256 + row) * 256 + k0;
    float4 v0 = *(const float4*)src;
    float4 v1 = *(const float4*)(src + 4);
    uint4 pk;
    pk.x = pk2(v0.x, v0.y); pk.y = pk2(v0.z, v0.w);
    pk.z = pk2(v1.x, v1.y); pk.w = pk2(v1.z, v1.w);
    *(uint4*)(out + (size_t)idx * 8) = pk;
}
// gt_wf [8][256 n][256 d] -> wfT2 u32 [8][128 d2][256 n]
__global__ __launch_bounds__(256) void conv_wfT2_kernel(const float* __restrict__ w, u32* __restrict__ out) {
    int idx = blockIdx.x * 256 + threadIdx.x;    // 0..262143
    int n = idx & 255;
    int d2 = (idx >> 8) & 127;
    int l = idx >> 15;
    const float* src = w + ((size_t)l * 256 + n) * 256 + 2 * d2;
    out[idx] = pk2(src[0], src[1]);
}

// ================= CSR build (4 edges/thread, pipelined atomics) =============
#define EDGE_CAP 128
__global__ __launch_bounds__(256) void bucket_fill_kernel(
    const int* __restrict__ src, const int* __restrict__ dst,
    int* __restrict__ ebuf, int* __restrict__ cursor, int* __restrict__ cnt_out, int ne)
{
    int e0 = (blockIdx.x * 256 + threadIdx.x) * 4;
    if (e0 >= ne) return;
    int4 s4 = *(const int4*)(src + e0);
    int4 d4 = *(const int4*)(dst + e0);
    atomicAdd(&cnt_out[s4.x], 1);
    atomicAdd(&cnt_out[s4.y], 1);
    atomicAdd(&cnt_out[s4.z], 1);
    atomicAdd(&cnt_out[s4.w], 1);
    int p0 = atomicAdd(&cursor[d4.x], 1);
    int p1 = atomicAdd(&cursor[d4.y], 1);
    int p2 = atomicAdd(&cursor[d4.z], 1);
    int p3 = atomicAdd(&cursor[d4.w], 1);
    if (p0 < EDGE_CAP) ebuf[(size_t)d4.x * EDGE_CAP + p0] = s4.x;
    if (p1 < EDGE_CAP) ebuf[(size_t)d4.y * EDGE_CAP + p1] = s4.y;
    if (p2 < EDGE_CAP) ebuf[(size_t)d4.z * EDGE_CAP + p2] = s4.z;
    if (p3 < EDGE_CAP) ebuf[(size_t)d4.w * EDGE_CAP + p3] = s4.w;
}
__global__ __launch_bounds__(256) void deg_fin_kernel(const int* __restrict__ cnt, float* __restrict__ dinv, int n) {
    int i = blockIdx.x * 256 + threadIdx.x;
    if (i < n) dinv[i] = rsqrtf(fmaxf((float)cnt[i], 1.0f));
}

// ================= CSR aggregate, skips dead outputs per layer ===============
template<bool WF, bool WB>
__global__ __launch_bounds__(256) void csr_agg_kernel(
    const u16* __restrict__ x, const int* __restrict__ ebuf,
    const int* __restrict__ deg, float* __restrict__ outf, u16* __restrict__ outb, int nnodes)
{
    int n = blockIdx.x * 4 + (threadIdx.x >> 6);
    if (n >= nnodes) return;
    int lane = threadIdx.x & 63;
    int d = deg[n];
    float dinv = rsqrtf(fmaxf((float)d, 1.0f));
    if (d > EDGE_CAP) d = EDGE_CAP;
    const int* eb = ebuf + (size_t)n * EDGE_CAP;
    const int co = lane << 2;
    float a0 = 0.f, a1 = 0.f, a2 = 0.f, a3 = 0.f;
    int k = 0;
    for (; k + 4 <= d; k += 4) {
        int4 s4 = *(const int4*)(eb + k);
        uint2 va = *(const uint2*)(x + (size_t)s4.x * 256 + co);
        uint2 vb = *(const uint2*)(x + (size_t)s4.y * 256 + co);
        uint2 vc = *(const uint2*)(x + (size_t)s4.z * 256 + co);
        uint2 vd = *(const uint2*)(x + (size_t)s4.w * 256 + co);
        a0 += b2f_lo(va.x) + b2f_lo(vb.x) + b2f_lo(vc.x) + b2f_lo(vd.x);
        a1 += b2f_hi(va.x) + b2f_hi(vb.x) + b2f_hi(vc.x) + b2f_hi(vd.x);
        a2 += b2f_lo(va.y) + b2f_lo(vb.y) + b2f_lo(vc.y) + b2f_lo(vd.y);
        a3 += b2f_hi(va.y) + b2f_hi(vb.y) + b2f_hi(vc.y) + b2f_hi(vd.y);
    }
    for (; k < d; ++k) {
        int s = eb[k];
        uint2 v = *(const uint2*)(x + (size_t)s * 256 + co);
        a0 += b2f_lo(v.x); a1 += b2f_hi(v.x);
        a2 += b2f_lo(v.y); a3 += b2f_hi(v.y);
    }
    a0 = fmaxf(a0 * dinv, 0.f); a1 = fmaxf(a1 * dinv, 0.f);
    a2 = fmaxf(a2 * dinv, 0.f); a3 = fmaxf(a3 * dinv, 0.f);
    if (WF) *(float4*)(outf + (size_t)n * 256 + co) = make_float4(a0, a1, a2, a3);
    if (WB) *(uint2*)(outb + (size_t)n * 256 + co) = make_uint2(pk2(a0, a1), pk2(a2, a3));
}

// ================= final =================
__global__ __launch_bounds__(256) void final_kernel(
    const float* __restrict__ m2, const float* __restrict__ w3,
    const float* __restrict__ b3, float* __restrict__ out, int nrows)
{
    int row = blockIdx.x * 4 + (threadIdx.x >> 6);
    int lane = threadIdx.x & 63;
    if (row >= nrows) return;
    float s = m2[(size_t)row * 128 + lane] * w3[lane]
            + m2[(size_t)row * 128 + 64 + lane] * w3[64 + lane];
    s = wave_sum(s);
    if (lane == 0) out[row] = 1.f / (1.f + expf(-(s + b3[0])));
}

static inline int cdiv(int a, int b) { return (a + b - 1) / b; }

extern "C" void kernel_launch(void* const* d_in, const int* in_sizes, int n_in,
                              void* d_out, int out_size, void* d_ws, size_t ws_size,
                              hipStream_t stream)
{
    const float* feat0   = (const float*)d_in[0];
    const float* feat1   = (const float*)d_in[1];
    const float* fc_w0   = (const float*)d_in[2];
    const float* fc_b0   = (const float*)d_in[3];
    const float* fc_w1   = (const float*)d_in[4];
    const float* fc_b1   = (const float*)d_in[5];
    const float* gcn_w   = (const float*)d_in[6];
    const int*   edge_src= (const int*)d_in[7];
    const int*   edge_dst= (const int*)d_in[8];
    const int*   dg_seqs = (const int*)d_in[9];
    const int*   pt_seqs = (const int*)d_in[10];
    // 11 type_emb, 12 node_type: dead; 13 gt_wl, 15 gt_al: dead (softmax cancellation)
    const float* gt_wr   = (const float*)d_in[14];
    const float* gt_ar   = (const float*)d_in[16];
    const float* gt_wf   = (const float*)d_in[17];
    const float* ln_g    = (const float*)d_in[18];
    const float* ln_b    = (const float*)d_in[19];
    const float* proj_d_w= (const float*)d_in[20];
    const float* proj_d_b= (const float*)d_in[21];
    const float* proj_p_w= (const float*)d_in[22];
    const float* proj_p_b= (const float*)d_in[23];
    const float* ml_w1   = (const float*)d_in[24];
    const float* ml_b1   = (const float*)d_in[25];
    const float* ml_w2   = (const float*)d_in[26];
    const float* ml_b2   = (const float*)d_in[27];
    const float* ml_w3   = (const float*)d_in[28];
    const float* ml_b3   = (const float*)d_in[29];
    float* out = (float*)d_out;

    // ---- workspace layout (f32 units) ----
    float* base  = (float*)d_ws;
    float* gh    = base;                      // 10,240,000
    float* gcnR  = gh + 10240000;             // GCN-phase region (15,440,000)
    float* dego  = gcnR + 15440000;           // 40,000
    float* embT  = dego + 40000;              // 524,288 (both types)
    float* t1    = embT + 524288;             // 524,288 (both types)
    float* mx    = t1 + 524288;               // 524,288
    float* m1    = mx + 524288;               // 262,144
    float* m2    = m1 + 262144;               // 131,072
    float* wreg  = m2 + 131072;               // converted weights

    u16* tmp_b   = (u16*)gcnR;                        // 10,240,000 bf16
    int* ebuf    = (int*)(gcnR + 5120000);            // 5,120,000 int
    int* cursor  = ebuf + (size_t)40000 * EDGE_CAP;   // 40,000
    int* cnt_out = cursor + 40000;                    // 40,000
    u16* gh_b    = (u16*)(gcnR + 10320000);           // 10,240,000 bf16

    u16* fcw_b   = (u16*)wreg;                // 262,144 u16
    u16* gcnw_b  = fcw_b + 262144;            // 131,072 u16
    u16* wrN     = gcnw_b + 131072;           // 524,288 u16 (8 layers x 65,536)
    u32* wfT2    = (u32*)(wrN + 524288);      // 262,144 u32 (8 layers x 32,768)

    // ---- weight converts ----
    conv_flat_kernel<<<cdiv(131072 / 4, 256), 256, 0, stream>>>(fc_w0, fcw_b, 131072);
    conv_flat_kernel<<<cdiv(131072 / 4, 256), 256, 0, stream>>>(fc_w1, fcw_b + 131072, 131072);
    conv_gcnw_kernel<<<dim3(256, 2), 256, 0, stream>>>(gcn_w, gcnw_b);
    conv_wrN_kernel<<<256, 256, 0, stream>>>(gt_wr, wrN);
    conv_wfT2_kernel<<<1024, 256, 0, stream>>>(gt_wf, wfT2);

    // ---- FC projections (merged dual GEMM via blockIdx.z) -> gh_b ----
    mfma_gemm_kernel<true><<<dim3(2, cdiv(20000, 64), 2), 256, 0, stream>>>(
        feat0, fcw_b, fc_b0, nullptr, gh_b, 20000, 256, 512,
        feat1, fcw_b + 131072, fc_b1, gh_b + (size_t)20000 * 256);

    // ---- CSR build (once) ----
    hipMemsetAsync(cursor, 0, 80000 * sizeof(int), stream);
    bucket_fill_kernel<<<625, 256, 0, stream>>>(edge_src, edge_dst, ebuf, cursor, cnt_out, 640000);
    deg_fin_kernel<<<cdiv(40000, 256), 256, 0, stream>>>(cnt_out, dego, 40000);

    // ---- 2x GCN (layer 0 writes bf16 only; layer 1 writes f32 only) ----
    mfma_gemm_kernel<false><<<dim3(2, cdiv(40000, 64), 1), 256, 0, stream>>>(
        gh_b, gcnw_b, nullptr, dego, tmp_b, 40000, 256, 256,
        gh_b, gcnw_b, nullptr, tmp_b);
    csr_agg_kernel<false, true><<<10000, 256, 0, stream>>>(tmp_b, ebuf, cursor, gh, gh_b, 40000);
    mfma_gemm_kernel<false><<<dim3(2, cdiv(40000, 64), 1), 256, 0, stream>>>(
        gh_b, gcnw_b + 65536, nullptr, dego, tmp_b, 40000, 256, 256,
        gh_b, gcnw_b, nullptr, tmp_b);
    csr_agg_kernel<true, false><<<10000, 256, 0, stream>>>(tmp_b, ebuf, cursor, gh, gh_b, 40000);

    // ---- mega-fused graph transformer, both types in one dispatch ----
    fused_transformer_kernel<<<2048, 512, 0, stream>>>(
        gh, dg_seqs, pt_seqs, wrN, wfT2, gt_ar, ln_g, ln_b, embT);

    // ---- proj heads (both types per dispatch via blockIdx.z) ----
    gemm_kernel<true><<<dim3(4, 16, 2), 256, 0, stream>>>(
        embT, proj_d_w, proj_d_b, nullptr, t1, 1024, 256, 256, 256, 256, 256, 0, 2,
        embT + 262144, proj_p_w, proj_p_b, t1 + 262144, 0);
    gemm_kernel<true><<<dim3(4, 16, 2), 256, 0, stream>>>(
        t1, proj_d_w + 65536, proj_d_b + 256, nullptr, mx, 1024, 256, 256, 256, 256, 512, 0, 0,
        t1 + 262144, proj_p_w + 65536, proj_p_b + 256, mx, 256);

    // ---- predict MLP ----
    gemm_kernel<true><<<dim3(4, 16, 1), 256, 0, stream>>>(
        mx, ml_w1, ml_b1, nullptr, m1, 1024, 256, 512, 512, 512, 256, 0, 1,
        mx, ml_w1, ml_b1, m1, 0);
    gemm_kernel<true><<<dim3(2, 16, 1), 256, 0, stream>>>(
        m1, ml_w2, ml_b2, nullptr, m2, 1024, 128, 256, 256, 256, 128, 0, 1,
        m1, ml_w2, ml_b2, m2, 0);
    final_kernel<<<256, 256, 0, stream>>>(m2, ml_w3, ml_b3, out, 1024);
}